// Round 11
// baseline (1366.993 us; speedup 1.0000x reference)
//
#include <hip/hip_runtime.h>
#include <stdint.h>

typedef unsigned short u16;
typedef __attribute__((ext_vector_type(8))) short short8;
typedef __attribute__((ext_vector_type(4))) float f32x4;
typedef __attribute__((ext_vector_type(16))) float f32x16;

#define GPTR(p) ((const __attribute__((address_space(1))) void*)(p))
#define SPTR(p) ((__attribute__((address_space(3))) void*)(p))
#define GLDS16(g, l) __builtin_amdgcn_global_load_lds(GPTR(g), SPTR(l), 16, 0, 0)

static __device__ __forceinline__ float bf2f(u16 u) {
  union { unsigned int i; float f; } c; c.i = ((unsigned int)u) << 16; return c.f;
}
static __device__ __forceinline__ u16 f2bf(float f) {
  union { float f; unsigned int u; } c; c.f = f;
  unsigned int r = 0x7fffu + ((c.u >> 16) & 1u);
  return (u16)((c.u + r) >> 16);
}
static __device__ __forceinline__ unsigned cvtpk(float a, float b) {
  unsigned r;
  asm volatile("v_cvt_pk_bf16_f32 %0, %1, %2" : "=v"(r) : "v"(a), "v"(b));
  return r;
}
static __device__ __forceinline__ int swz4(int row, int c) { return c ^ ((row >> 1) & 3); }

// ---------------- LayerNorm: f32 (rows of 1024) -> bf16 ----------------
__global__ __launch_bounds__(256) void ln_kernel(
    const float* __restrict__ x, const float* __restrict__ ctx,
    const float* __restrict__ g, const float* __restrict__ b,
    const float* __restrict__ cg, const float* __restrict__ cb,
    u16* __restrict__ xn, u16* __restrict__ cn)
{
  const int row = blockIdx.x;
  const float* src; const float* gg; const float* bb; u16* dst;
  if (row < 4096) { src = x + (size_t)row * 1024; gg = g;  bb = b;  dst = xn + (size_t)row * 1024; }
  else            { src = ctx + (size_t)(row - 4096) * 1024; gg = cg; bb = cb; dst = cn + (size_t)(row - 4096) * 1024; }
  const int t = threadIdx.x;
  float4 v = *(const float4*)&src[t * 4];
  float s  = v.x + v.y + v.z + v.w;
  float s2 = v.x * v.x + v.y * v.y + v.z * v.z + v.w * v.w;
  #pragma unroll
  for (int off = 1; off < 64; off <<= 1) { s += __shfl_xor(s, off); s2 += __shfl_xor(s2, off); }
  __shared__ float ls[4], ls2[4];
  const int w = t >> 6;
  if ((t & 63) == 0) { ls[w] = s; ls2[w] = s2; }
  __syncthreads();
  s  = ls[0] + ls[1] + ls[2] + ls[3];
  s2 = ls2[0] + ls2[1] + ls2[2] + ls2[3];
  const float mu   = s * (1.0f / 1024.0f);
  const float var  = s2 * (1.0f / 1024.0f) - mu * mu;
  const float rstd = rsqrtf(var + 1e-5f);
  float xv[4] = { v.x, v.y, v.z, v.w };
  u16 o[4];
  #pragma unroll
  for (int i = 0; i < 4; ++i)
    o[i] = f2bf((xv[i] - mu) * rstd * gg[t * 4 + i] + bb[t * 4 + i]);
  uint2 pv;
  pv.x = (unsigned)o[0] | ((unsigned)o[1] << 16);
  pv.y = (unsigned)o[2] | ((unsigned)o[3] << 16);
  *(uint2*)&dst[t * 4] = pv;
}

// ---------------- transpose+convert: f32 (R,C) -> bf16 (C,R) with out leading dim ----------------
__global__ __launch_bounds__(256) void transpose_k(
    const float* __restrict__ in, u16* __restrict__ out, int R, int C, int ldo, float scale)
{
  __shared__ float tile[64][65];
  const int c0 = blockIdx.x * 64, r0 = blockIdx.y * 64;
  const int t = threadIdx.x;
  const int tr = t >> 4, tc = (t & 15) * 4;
  #pragma unroll
  for (int i = 0; i < 4; ++i) {
    int r = tr + i * 16;
    float4 v = *(const float4*)&in[(size_t)(r0 + r) * C + c0 + tc];
    tile[r][tc + 0] = v.x; tile[r][tc + 1] = v.y; tile[r][tc + 2] = v.z; tile[r][tc + 3] = v.w;
  }
  __syncthreads();
  #pragma unroll
  for (int i = 0; i < 2; ++i) {
    int c  = (t >> 3) + i * 32;
    int rb = (t & 7) * 8;
    union { u16 s[8]; uint4 v; } pk;
    #pragma unroll
    for (int u = 0; u < 8; ++u) pk.s[u] = f2bf(tile[rb + u][c] * scale);
    *(uint4*)&out[(size_t)(c0 + c) * ldo + r0 + rb] = pk.v;
  }
}

// ---------------- Wff1 transpose with (a,gate) fragment interleave ----------------
__global__ __launch_bounds__(256) void transpose_ff1(
    const float* __restrict__ in, u16* __restrict__ out)
{
  __shared__ float tile[64][65];
  const int c0 = blockIdx.x * 64, r0 = blockIdx.y * 64;
  const int t = threadIdx.x;
  const int tr = t >> 4, tc = (t & 15) * 4;
  #pragma unroll
  for (int i = 0; i < 4; ++i) {
    int r = tr + i * 16;
    float4 v = *(const float4*)&in[(size_t)(r0 + r) * 8192 + c0 + tc];
    tile[r][tc + 0] = v.x; tile[r][tc + 1] = v.y; tile[r][tc + 2] = v.z; tile[r][tc + 3] = v.w;
  }
  __syncthreads();
  #pragma unroll
  for (int i = 0; i < 2; ++i) {
    int c  = (t >> 3) + i * 32;
    int rb = (t & 7) * 8;
    const int gc = c0 + c;
    int j, add16;
    if (gc < 4096) { j = gc; add16 = 0; } else { j = gc - 4096; add16 = 16; }
    const int row = 1024 + ((j >> 7) << 8) + (((j >> 5) & 3) << 6) + (((j >> 4) & 1) << 5) + add16 + (j & 15);
    union { u16 s[8]; uint4 v; } pk;
    #pragma unroll
    for (int u = 0; u < 8; ++u) pk.s[u] = f2bf(tile[rb + u][c]);
    *(uint4*)&out[(size_t)row * 1024 + r0 + rb] = pk.v;
  }
}

// =============== 4-phase 256x256 GEMM, BK=32, 64 KB LDS -> 2 blocks/CU ===============
// Same 256^2 tile / 8-wave map / per-K ds+stage volume as the BK=64 version, but LDS
// halves so TWO independent blocks co-reside per CU — their MFMA fills the other's
// barrier/vmcnt stalls (m114 mechanism). Stage-into-read-buffer safety:
//   A-half0 = mq0 rows {0-63,128-191} (read at phase mq0), A-half1 = mq1 rows;
//   B fully read at each tile's first phase. Gates: 3 wave-loads in flight -> vmcnt(3).
#define MM32(MQ, M, NN) acc[MQ][M][NN] = __builtin_amdgcn_mfma_f32_16x16x32_bf16(af##M, bf##NN, acc[MQ][M][NN], 0, 0, 0)
#define MFMA16_32(MQ) \
  MM32(MQ,0,0); MM32(MQ,0,1); MM32(MQ,0,2); MM32(MQ,0,3); \
  MM32(MQ,1,0); MM32(MQ,1,1); MM32(MQ,1,2); MM32(MQ,1,3); \
  MM32(MQ,2,0); MM32(MQ,2,1); MM32(MQ,2,2); MM32(MQ,2,3); \
  MM32(MQ,3,0); MM32(MQ,3,1); MM32(MQ,3,2); MM32(MQ,3,3)

#define SA32(SBUF, H, KT) GLDS16(gA32[H] + ((size_t)(KT) << 5), SBUF + (size_t)((H) * 64 + w16o) * 32)
#define SB32(SBUF, H, KT) GLDS16(gB32[H] + ((size_t)(KT) << 5), SBUF + (size_t)((H) * 128 + w16o2) * 32)

#define DSB32(PB_) do { \
  bf0 = *(const short8*)(PB_ + 0    + cks); bf1 = *(const short8*)(PB_ + 512  + cks); \
  bf2 = *(const short8*)(PB_ + 1024 + cks); bf3 = *(const short8*)(PB_ + 1536 + cks); \
} while (0)

#define PC32(PA_, MQ, STAGE_STMT, GATE_STMT) do { \
  af0 = *(const short8*)(PA_ + (MQ) * 2048 + 0    + cks); \
  af1 = *(const short8*)(PA_ + (MQ) * 2048 + 512  + cks); \
  af2 = *(const short8*)(PA_ + (MQ) * 2048 + 1024 + cks); \
  af3 = *(const short8*)(PA_ + (MQ) * 2048 + 1536 + cks); \
  STAGE_STMT; \
  __builtin_amdgcn_s_barrier(); \
  asm volatile("s_waitcnt lgkmcnt(0)" ::: "memory"); \
  __builtin_amdgcn_s_setprio(1); \
  MFMA16_32(MQ); \
  __builtin_amdgcn_s_setprio(0); \
  GATE_STMT; \
  __builtin_amdgcn_s_barrier(); \
} while (0)

#define GATE3 asm volatile("s_waitcnt vmcnt(3)" ::: "memory")
#define GATE0 asm volatile("s_waitcnt vmcnt(0)" ::: "memory")

// MODE 2: qff fused epilogue (q bf16 + silu pair-fused h). MODE 3: bf16 split-K partials.
template<int MODE, int ORDER>
__global__ __launch_bounds__(512, 4) void gemm8p(
    const u16* __restrict__ A, const u16* __restrict__ BT, void* __restrict__ C,
    void* __restrict__ C2, int M, int N, int Ktot, int Kslice)
{
  __shared__ u16 sh[2][2][8192]; // [buf][A/B][256*32] = 64 KB
  const int nbn = N >> 8, nbm = M >> 8;
  const int nwg = gridDim.x;
  const int bid = blockIdx.x;
  const int o = (bid & 7) * (nwg >> 3) + (bid >> 3);  // chunked bijective XCD map (nwg%8==0)
  int bm, bn;
  if constexpr (ORDER == 0) { bm = o % nbm; bn = o / nbm; }  // B-strip per XCD
  else                      { bn = o % nbn; bm = o / nbn; }  // A-panels per XCD
  const int kbase = blockIdx.y * Kslice;
  const int NI = Kslice >> 6;      // two 32-K tiles per iteration

  const int t = threadIdx.x, w = t >> 6, lane = t & 63;
  const int wr = w >> 2, wc = w & 3;
  const int lr = lane & 15, lg = lane >> 4;
  const int l4 = lane >> 2, sl = lane & 3;
  const int w16o  = w * 16 + ((w >= 4) ? 64 : 0);  // A-half row base (mq rows of both wr groups)
  const int w16o2 = w * 16;                         // B-half row base

  const u16* gA32[2]; const u16* gB32[2];
  #pragma unroll
  for (int h = 0; h < 2; ++h) {
    const int rowA = h * 64 + w16o + l4;
    gA32[h] = A + (size_t)(bm * 256 + rowA) * Ktot + kbase + (size_t)((sl ^ ((rowA >> 1) & 3)) * 8);
    const int rowB = h * 128 + w16o2 + l4;
    gB32[h] = BT + (size_t)(bn * 256 + rowB) * Ktot + kbase + (size_t)((sl ^ ((rowB >> 1) & 3)) * 8);
  }
  u16* sA0 = &sh[0][0][0]; u16* sA1 = &sh[1][0][0];
  u16* sB0 = &sh[0][1][0]; u16* sB1 = &sh[1][1][0];
  const int cks = (lg ^ ((lr >> 1) & 3)) * 8;
  const u16* pA_b0 = sA0 + (wr * 128 + lr) * 32;
  const u16* pA_b1 = sA1 + (wr * 128 + lr) * 32;
  const u16* pB_b0 = sB0 + (wc * 64 + lr) * 32;
  const u16* pB_b1 = sB1 + (wc * 64 + lr) * 32;

  f32x4 acc[2][4][4];
  const f32x4 z4 = { 0.f, 0.f, 0.f, 0.f };
  #pragma unroll
  for (int a = 0; a < 2; ++a)
    #pragma unroll
    for (int b = 0; b < 4; ++b)
      #pragma unroll
      for (int c = 0; c < 4; ++c) acc[a][b][c] = z4;
  short8 af0, af1, af2, af3;
  short8 bf0, bf1, bf2, bf3;

  // prologue: tile0 -> buf0 (4 halves); tile1 -> buf1 (B0,B1,A0); A-h1(1) at first P0
  SA32(sA0, 0, 0); SA32(sA0, 1, 0); SB32(sB0, 0, 0); SB32(sB0, 1, 0);
  SB32(sB1, 0, 1); SB32(sB1, 1, 1); SA32(sA1, 0, 1);
  GATE3;
  __builtin_amdgcn_s_barrier();

  for (int i = 0; i < NI; ++i) {
    const bool st = (i < NI - 1);
    const int X = 2 * i + 2, Y = 2 * i + 3;
    // P0 (buf0, mq0): stage A-h1 of tile 2i+1 -> buf1 (its mq1 rows last read at prev P3)
    DSB32(pB_b0);
    PC32(pA_b0, 0, SA32(sA1, 1, 2 * i + 1), );
    // P1 (buf0, mq1): stage B + A-h0 of tile X -> buf0 (B + mq0 rows fully read); gate buf1
    PC32(pA_b0, 1,
         if (st) { SB32(sB0, 0, X); SB32(sB0, 1, X); SA32(sA0, 0, X); },
         if (st) { GATE3; } else { GATE0; });
    // P2 (buf1, mq0): stage A-h1(X) -> buf0 (mq1 rows read finished at P1)
    DSB32(pB_b1);
    PC32(pA_b1, 0, if (st) { SA32(sA0, 1, X); }, );
    // P3 (buf1, mq1): stage B + A-h0 of tile Y -> buf1; gate next buf0
    PC32(pA_b1, 1,
         if (st) { SB32(sB1, 0, Y); SB32(sB1, 1, Y); SA32(sA1, 0, Y); },
         if (st) { GATE3; });
  }

  if constexpr (MODE == 3) {
    u16* Co = (u16*)C + (size_t)blockIdx.y * M * N;
    #pragma unroll
    for (int mq = 0; mq < 2; ++mq)
      #pragma unroll
      for (int m = 0; m < 4; ++m)
        #pragma unroll
        for (int n = 0; n < 4; ++n)
          #pragma unroll
          for (int rr = 0; rr < 4; ++rr) {
            const int row = bm * 256 + wr * 128 + mq * 64 + m * 16 + lg * 4 + rr;
            const int col = bn * 256 + wc * 64 + n * 16 + lr;
            Co[(size_t)row * N + col] = f2bf(acc[mq][m][n][rr]);
          }
  } else {
    if (bn < 4) {
      u16* Co = (u16*)C; // qbuf, stride 1024
      #pragma unroll
      for (int mq = 0; mq < 2; ++mq)
        #pragma unroll
        for (int m = 0; m < 4; ++m)
          #pragma unroll
          for (int n = 0; n < 4; ++n)
            #pragma unroll
            for (int rr = 0; rr < 4; ++rr) {
              const int row = bm * 256 + wr * 128 + mq * 64 + m * 16 + lg * 4 + rr;
              const int col = bn * 256 + wc * 64 + n * 16 + lr;
              Co[(size_t)row * 1024 + col] = f2bf(acc[mq][m][n][rr]);
            }
    } else {
      u16* Ho = (u16*)C2; // aoh, stride 5120, h starts at col 1024
      const int colb = 1024 + (bn - 4) * 128 + wc * 32 + lr;
      #pragma unroll
      for (int mq = 0; mq < 2; ++mq)
        #pragma unroll
        for (int m = 0; m < 4; ++m)
          #pragma unroll
          for (int rr = 0; rr < 4; ++rr) {
            const int row = bm * 256 + wr * 128 + mq * 64 + m * 16 + lg * 4 + rr;
            #pragma unroll
            for (int n2 = 0; n2 < 2; ++n2) {
              const float a = acc[mq][m][2 * n2][rr];
              const float gt = acc[mq][m][2 * n2 + 1][rr];
              const float h = a * gt / (1.0f + __expf(-gt));
              Ho[(size_t)row * 5120 + colb + n2 * 16] = f2bf(h);
            }
          }
    }
  }
}

// ---------------- split-K GEMM 128x128 (kv projection), bf16 partials ----------------
__global__ __launch_bounds__(256) void gemm_bt_sk(
    const u16* __restrict__ A, const u16* __restrict__ BT, u16* __restrict__ Cp,
    int M, int N, int Kslice, int Ktot)
{
  __shared__ u16 As[128 * 32];
  __shared__ u16 Bs[128 * 32];
  const int bm = blockIdx.y, bn = blockIdx.x, z = blockIdx.z;
  const int t = threadIdx.x;
  const int w = t >> 6, lane = t & 63;
  const int wr = w >> 1, wc = w & 1;
  const int lr = lane & 15, lkc = lane >> 4;

  f32x4 acc[4][4];
  const f32x4 z4 = { 0.f, 0.f, 0.f, 0.f };
  #pragma unroll
  for (int mi = 0; mi < 4; ++mi)
    #pragma unroll
    for (int ni = 0; ni < 4; ++ni) acc[mi][ni] = z4;

  const int kbase = z * Kslice;
  const int i0 = t, i1 = t + 256;
  const int r0 = i0 >> 2, k0 = swz4(r0, i0 & 3) * 8;
  const int r1 = i1 >> 2, k1 = swz4(r1, i1 & 3) * 8;
  const u16* a0 = A + (size_t)(bm * 128 + r0) * Ktot + kbase + k0;
  const u16* a1 = A + (size_t)(bm * 128 + r1) * Ktot + kbase + k1;
  const u16* b0 = BT + (size_t)(bn * 128 + r0) * Ktot + kbase + k0;
  const u16* b1 = BT + (size_t)(bn * 128 + r1) * Ktot + kbase + k1;
  u16* As0 = As + (size_t)w * 512;
  u16* As1 = As + (size_t)(w + 4) * 512;
  u16* Bs0 = Bs + (size_t)w * 512;
  u16* Bs1 = Bs + (size_t)(w + 4) * 512;

  const int nk = Kslice >> 5;
  for (int kt = 0; kt < nk; ++kt) {
    __syncthreads();
    GLDS16(a0, As0); GLDS16(a1, As1); GLDS16(b0, Bs0); GLDS16(b1, Bs1);
    a0 += 32; a1 += 32; b0 += 32; b1 += 32;
    __syncthreads();
    short8 af[4], bf[4];
    #pragma unroll
    for (int mi = 0; mi < 4; ++mi) {
      int row = wr * 64 + mi * 16 + lr;
      af[mi] = *(const short8*)&As[row * 32 + swz4(row, lkc) * 8];
    }
    #pragma unroll
    for (int ni = 0; ni < 4; ++ni) {
      int row = wc * 64 + ni * 16 + lr;
      bf[ni] = *(const short8*)&Bs[row * 32 + swz4(row, lkc) * 8];
    }
    #pragma unroll
    for (int mi = 0; mi < 4; ++mi)
      #pragma unroll
      for (int ni = 0; ni < 4; ++ni)
        acc[mi][ni] = __builtin_amdgcn_mfma_f32_16x16x32_bf16(af[mi], bf[ni], acc[mi][ni], 0, 0, 0);
  }

  u16* Cz = Cp + (size_t)z * M * N;
  const int row0 = bm * 128 + wr * 64, col0 = bn * 128 + wc * 64;
  const int rsub = (lane >> 4) * 4;
  #pragma unroll
  for (int mi = 0; mi < 4; ++mi)
    #pragma unroll
    for (int ni = 0; ni < 4; ++ni)
      #pragma unroll
      for (int r = 0; r < 4; ++r)
        Cz[(size_t)(row0 + mi * 16 + rsub + r) * N + (col0 + ni * 16 + lr)] = f2bf(acc[mi][ni][r]);
}

// ---------------- reduce 8 bf16 partials (4096x128) -> bf16 ----------------
__global__ __launch_bounds__(256) void reduce_kv(const u16* __restrict__ part, u16* __restrict__ out)
{
  const size_t base = ((size_t)blockIdx.x * 256 + threadIdx.x) * 8;
  float s[8] = { 0.f, 0.f, 0.f, 0.f, 0.f, 0.f, 0.f, 0.f };
  #pragma unroll
  for (int zz = 0; zz < 8; ++zz) {
    const short8 v = *(const short8*)&part[(size_t)zz * 524288 + base];
    #pragma unroll
    for (int i = 0; i < 8; ++i) s[i] += bf2f((u16)v[i]);
  }
  union { u16 o[8]; uint4 v; } pk;
  #pragma unroll
  for (int i = 0; i < 8; ++i) pk.o[i] = f2bf(s[i]);
  *(uint4*)&out[base] = pk.v;
}

// ---------------- out = sum of 8 bf16 partials (4096x1024) -> f32 ----------------
__global__ __launch_bounds__(256) void reduce_out(const u16* __restrict__ part, float* __restrict__ out)
{
  const size_t base = ((size_t)blockIdx.x * 256 + threadIdx.x) * 8;
  float s[8] = { 0.f, 0.f, 0.f, 0.f, 0.f, 0.f, 0.f, 0.f };
  #pragma unroll
  for (int zz = 0; zz < 8; ++zz) {
    const short8 v = *(const short8*)&part[(size_t)zz * 4194304 + base];
    #pragma unroll
    for (int i = 0; i < 8; ++i) s[i] += bf2f((u16)v[i]);
  }
  f32x4 lo = { s[0], s[1], s[2], s[3] };
  f32x4 hi = { s[4], s[5], s[6], s[7] };
  *(f32x4*)&out[base] = lo;
  *(f32x4*)&out[base + 4] = hi;
}

// ---------------- flash cross-attention (multi-query: 1 KV head) ----------------
// 64 q-rows per wave (2 q32 tiles), 4 heads/block, grid (N/64, H/4, B) = 256 blocks.
// T13 defer-max: skip max-update + O-rescale when tile max <= m + 8 (wave-uniform).
__global__ __launch_bounds__(256) void attn_kernel(
    const u16* __restrict__ q, const u16* __restrict__ kv, u16* __restrict__ o)
{
  __shared__ u16 Ks[128 * 64];
  __shared__ u16 Vt[64 * 128];
  __shared__ u16 Ps[4][32 * 128];
  const int b = blockIdx.z, hb = blockIdx.y, qb = blockIdx.x;
  const int t = threadIdx.x, w = t >> 6, lane = t & 63;
  const int q32 = lane & 31, hl = lane >> 5;
  const int hd = hb * 4 + w;

  const size_t qbase = (size_t)b * 2048 + qb * 64;
  short8 qa[2][4];
  #pragma unroll
  for (int t32 = 0; t32 < 2; ++t32)
    #pragma unroll
    for (int dq = 0; dq < 4; ++dq)
      qa[t32][dq] = *(const short8*)&q[(qbase + t32 * 32 + q32) * 1024 + hd * 64 + dq * 16 + hl * 8];

  f32x16 oacc[2][2];
  #pragma unroll
  for (int i = 0; i < 2; ++i)
    #pragma unroll
    for (int j = 0; j < 2; ++j)
      #pragma unroll
      for (int r = 0; r < 16; ++r) oacc[i][j][r] = 0.f;
  float m_[2] = { -1e30f, -1e30f }, l_[2] = { 0.f, 0.f };

  const size_t kvb = (size_t)b * 2048 * 128;
  const int vd0 = (t & 7) * 8;
  const int vodd = (t >> 3) & 1;
  u16* Pw = &Ps[w][0];

  for (int jt = 0; jt < 16; ++jt) {
    __syncthreads();
    #pragma unroll
    for (int n = 0; n < 4; ++n) {
      const int cc = n * 256 + w * 64;
      const int ccl = cc + lane;
      const int row = ccl >> 3, lc = (ccl & 7) ^ (row & 7);
      GLDS16(&kv[kvb + (size_t)(jt * 128 + row) * 128 + lc * 8], Ks + (size_t)cc * 8);
    }
    #pragma unroll
    for (int c = 0; c < 4; ++c) {
      const int seg = c * 256 + t;
      const int vj = seg >> 3;
      const int jp = vj >> 1;
      const uint4 vv = *(const uint4*)&kv[kvb + (size_t)(jt * 128 + vj) * 128 + 64 + vd0];
      uint4 pvv;
      pvv.x = __shfl_xor((int)vv.x, 8);
      pvv.y = __shfl_xor((int)vv.y, 8);
      pvv.z = __shfl_xor((int)vv.z, 8);
      pvv.w = __shfl_xor((int)vv.w, 8);
      const unsigned ow[4] = { vv.x, vv.y, vv.z, vv.w };
      const unsigned pw[4] = { pvv.x, pvv.y, pvv.z, pvv.w };
      if (!vodd) {
        #pragma unroll
        for (int u = 0; u < 4; ++u) {
          const int d = vd0 + u;
          const unsigned own = (u & 1) ? (ow[u >> 1] >> 16) : (ow[u >> 1] & 0xffffu);
          const unsigned par = (u & 1) ? (pw[u >> 1] >> 16) : (pw[u >> 1] & 0xffffu);
          const int byteoff = d * 256 + ((4 * jp) ^ (((d & 7) ^ ((d >> 3) & 7)) << 4));
          *(unsigned*)((char*)Vt + byteoff) = own | (par << 16);
        }
      } else {
        #pragma unroll
        for (int u = 0; u < 4; ++u) {
          const int ue = u + 4;
          const int d = vd0 + ue;
          const unsigned own = (ue & 1) ? (ow[ue >> 1] >> 16) : (ow[ue >> 1] & 0xffffu);
          const unsigned par = (ue & 1) ? (pw[ue >> 1] >> 16) : (pw[ue >> 1] & 0xffffu);
          const int byteoff = d * 256 + ((4 * jp) ^ (((d & 7) ^ ((d >> 3) & 7)) << 4));
          *(unsigned*)((char*)Vt + byteoff) = par | (own << 16);
        }
      }
    }
    __syncthreads();

    #pragma unroll
    for (int t32 = 0; t32 < 2; ++t32) {
      f32x16 s[4];
      #pragma unroll
      for (int j32 = 0; j32 < 4; ++j32)
        #pragma unroll
        for (int r = 0; r < 16; ++r) s[j32][r] = 0.f;
      #pragma unroll
      for (int j32 = 0; j32 < 4; ++j32) {
        const int row = j32 * 32 + q32;
        #pragma unroll
        for (int dq = 0; dq < 4; ++dq) {
          const int slot = (dq * 2 + hl) ^ (row & 7);
          const short8 kf = *(const short8*)&Ks[row * 64 + slot * 8];
          s[j32] = __builtin_amdgcn_mfma_f32_32x32x16_bf16(kf, qa[t32][dq], s[j32], 0, 0, 0);
        }
      }
      float mt = -1e30f;
      #pragma unroll
      for (int j32 = 0; j32 < 4; ++j32)
        #pragma unroll
        for (int r = 0; r < 16; ++r) mt = fmaxf(mt, s[j32][r]);
      mt = fmaxf(mt, __shfl_xor(mt, 32));
      const bool noresc = (bool)__all(mt <= m_[t32] + 8.0f);
      float nm = m_[t32];
      if (!noresc) {
        nm = fmaxf(m_[t32], mt);
        const float alpha = __expf(m_[t32] - nm);
        m_[t32] = nm;
        l_[t32] *= alpha;
        #pragma unroll
        for (int d32 = 0; d32 < 2; ++d32)
          #pragma unroll
          for (int r = 0; r < 16; ++r) oacc[t32][d32][r] *= alpha;
      }
      float lsum = 0.f;
      #pragma unroll
      for (int j32 = 0; j32 < 4; ++j32) {
        float p[16];
        #pragma unroll
        for (int r = 0; r < 16; ++r) { p[r] = __expf(s[j32][r] - nm); lsum += p[r]; }
        #pragma unroll
        for (int g = 0; g < 4; ++g) {
          const unsigned lo = cvtpk(p[4 * g + 0], p[4 * g + 1]);
          const unsigned hi = cvtpk(p[4 * g + 2], p[4 * g + 3]);
          const int j2 = j32 * 64 + 16 * g + 8 * hl;
          const int byteoff = q32 * 256 + (j2 ^ ((q32 & 7) << 4));
          uint2 wv; wv.x = lo; wv.y = hi;
          *(uint2*)((char*)Pw + byteoff) = wv;
        }
      }
      lsum += __shfl_xor(lsum, 32);
      l_[t32] += lsum;
      short8 pf[8];
      #pragma unroll
      for (int kk = 0; kk < 8; ++kk) {
        const int byteoff = q32 * 256 + ((kk * 32 + hl * 16) ^ ((q32 & 7) << 4));
        pf[kk] = *(const short8*)((const char*)Pw + byteoff);
      }
      #pragma unroll
      for (int d32 = 0; d32 < 2; ++d32) {
        const int dr = d32 * 32 + q32;
        const int vswz = ((dr & 7) ^ ((dr >> 3) & 7)) << 4;
        #pragma unroll
        for (int kk = 0; kk < 8; ++kk) {
          const int byteoff = dr * 256 + ((kk * 32 + hl * 16) ^ vswz);
          const short8 vf = *(const short8*)((const char*)Vt + byteoff);
          oacc[t32][d32] = __builtin_amdgcn_mfma_f32_32x32x16_bf16(vf, pf[kk], oacc[t32][d32], 0, 0, 0);
        }
      }
    }
  }

  float* Ot = (float*)Pw;
  #pragma unroll
  for (int t32 = 0; t32 < 2; ++t32) {
    const float inv = 1.0f / l_[t32];
    #pragma unroll
    for (int d32 = 0; d32 < 2; ++d32) {
      #pragma unroll
      for (int r = 0; r < 16; ++r) {
        const int d = (r & 3) + 8 * (r >> 2) + 4 * hl;
        const int byteoff = q32 * 128 + ((4 * d) ^ ((q32 & 7) << 4));
        *(float*)((char*)Ot + byteoff) = oacc[t32][d32][r] * inv;
      }
      const int qr = lane >> 1, dc = (lane & 1) * 16;
      union { u16 s[16]; uint4 v[2]; } ob;
      #pragma unroll
      for (int cch = 0; cch < 4; ++cch) {
        const int byteoff = qr * 128 + ((4 * (dc + 4 * cch)) ^ ((qr & 7) << 4));
        const f32x4 vv = *(const f32x4*)((const char*)Ot + byteoff);
        ob.s[cch * 4 + 0] = f2bf(vv[0]);
        ob.s[cch * 4 + 1] = f2bf(vv[1]);
        ob.s[cch * 4 + 2] = f2bf(vv[2]);
        ob.s[cch * 4 + 3] = f2bf(vv[3]);
      }
      u16* orow = &o[(qbase + t32 * 32 + qr) * 5120 + hd * 64 + d32 * 32 + dc];
      *(uint4*)orow = ob.v[0];
      *(uint4*)(orow + 8) = ob.v[1];
    }
  }
}

extern "C" void kernel_launch(void* const* d_in, const int* in_sizes, int n_in,
                              void* d_out, int out_size, void* d_ws, size_t ws_size,
                              hipStream_t stream)
{
  const float* x    = (const float*)d_in[0];
  const float* ctx  = (const float*)d_in[1];
  const float* ng   = (const float*)d_in[2];
  const float* nb   = (const float*)d_in[3];
  const float* cg   = (const float*)d_in[4];
  const float* cb   = (const float*)d_in[5];
  const float* Wq   = (const float*)d_in[6];
  const float* Wkv  = (const float*)d_in[7];
  const float* Wo   = (const float*)d_in[8];
  const float* Wff1 = (const float*)d_in[9];
  const float* Wff2 = (const float*)d_in[10];

  u16* p = (u16*)d_ws;
  u16* W1T   = p; p += (size_t)9216 * 1024;
  u16* WkvT  = p; p += (size_t)128 * 1024;
  u16* WcT   = p; p += (size_t)1024 * 5120;
  u16* kvbuf = p; p += (size_t)4096 * 128;
  u16* aoh   = p; p += (size_t)4096 * 5120;
  u16* xn    = p; p += (size_t)4096 * 1024;
  u16* cn    = p; p += (size_t)4096 * 1024;
  u16* qbuf  = p; p += (size_t)4096 * 1024;
  u16* kvpart = W1T;   // 8 MB bf16 over W1T (dead after qff GEMM)
  u16* ffpart = xn;    // 64 MB bf16 over xn|cn|qbuf + ws tail (all dead by final GEMM)
  (void)in_sizes; (void)n_in; (void)out_size; (void)ws_size;

  ln_kernel<<<8192, 256, 0, stream>>>(x, ctx, ng, nb, cg, cb, xn, cn);

  transpose_k<<<dim3(16, 16),  256, 0, stream>>>(Wq,   W1T,        1024, 1024, 1024, 0.125f);
  transpose_ff1<<<dim3(128, 16), 256, 0, stream>>>(Wff1, W1T);
  transpose_k<<<dim3(2, 16),   256, 0, stream>>>(Wkv,  WkvT,       1024, 128,  1024, 1.0f);
  transpose_k<<<dim3(16, 16),  256, 0, stream>>>(Wo,   WcT,        1024, 1024, 5120, 1.0f);
  transpose_k<<<dim3(16, 64),  256, 0, stream>>>(Wff2, WcT + 1024, 4096, 1024, 5120, 1.0f);

  // fused: qbuf = xn@Wq*scale ; aoh[:,1024:] = silu(xn@Wff1); ORDER 0; 2 blocks/CU (64 KB LDS)
  gemm8p<2, 0><<<dim3(576), 512, 0, stream>>>(xn, W1T, qbuf, aoh, 4096, 9216, 1024, 1024);
  // kv = cn @ Wkv, split-K 8 (bf16 partials over dead W1T), reduce to bf16
  gemm_bt_sk<<<dim3(1, 32, 8), 256, 0, stream>>>(cn, WkvT, kvpart, 4096, 128, 128, 1024);
  reduce_kv<<<256, 256, 0, stream>>>(kvpart, kvbuf);
  // attention -> aoh[:,0:1024]
  attn_kernel<<<dim3(32, 4, 2), 256, 0, stream>>>(qbuf, kvbuf, aoh);
  // out = aoh @ [Wo ; Wff2], split-K 8 (512 blocks -> 2/CU), bf16 partials; ORDER 1
  gemm8p<3, 1><<<dim3(64, 8), 512, 0, stream>>>(aoh, WcT, ffpart, nullptr, 4096, 1024, 5120, 640);
  reduce_out<<<2048, 256, 0, stream>>>(ffpart, (float*)d_out);
}

// Round 12
// 307.300 us; speedup vs baseline: 4.4484x; 4.4484x over previous
//
#include <hip/hip_runtime.h>
#include <stdint.h>

typedef unsigned short u16;
typedef __attribute__((ext_vector_type(8))) short short8;
typedef __attribute__((ext_vector_type(4))) float f32x4;
typedef __attribute__((ext_vector_type(16))) float f32x16;

#define GPTR(p) ((const __attribute__((address_space(1))) void*)(p))
#define SPTR(p) ((__attribute__((address_space(3))) void*)(p))
#define GLDS16(g, l) __builtin_amdgcn_global_load_lds(GPTR(g), SPTR(l), 16, 0, 0)

static __device__ __forceinline__ float bf2f(u16 u) {
  union { unsigned int i; float f; } c; c.i = ((unsigned int)u) << 16; return c.f;
}
static __device__ __forceinline__ u16 f2bf(float f) {
  union { float f; unsigned int u; } c; c.f = f;
  unsigned int r = 0x7fffu + ((c.u >> 16) & 1u);
  return (u16)((c.u + r) >> 16);
}
static __device__ __forceinline__ unsigned cvtpk(float a, float b) {
  unsigned r;
  asm volatile("v_cvt_pk_bf16_f32 %0, %1, %2" : "=v"(r) : "v"(a), "v"(b));
  return r;
}
static __device__ __forceinline__ int swz4(int row, int c) { return c ^ ((row >> 1) & 3); }

// ---------------- LayerNorm: f32 (rows of 1024) -> bf16 ----------------
__global__ __launch_bounds__(256) void ln_kernel(
    const float* __restrict__ x, const float* __restrict__ ctx,
    const float* __restrict__ g, const float* __restrict__ b,
    const float* __restrict__ cg, const float* __restrict__ cb,
    u16* __restrict__ xn, u16* __restrict__ cn)
{
  const int row = blockIdx.x;
  const float* src; const float* gg; const float* bb; u16* dst;
  if (row < 4096) { src = x + (size_t)row * 1024; gg = g;  bb = b;  dst = xn + (size_t)row * 1024; }
  else            { src = ctx + (size_t)(row - 4096) * 1024; gg = cg; bb = cb; dst = cn + (size_t)(row - 4096) * 1024; }
  const int t = threadIdx.x;
  float4 v = *(const float4*)&src[t * 4];
  float s  = v.x + v.y + v.z + v.w;
  float s2 = v.x * v.x + v.y * v.y + v.z * v.z + v.w * v.w;
  #pragma unroll
  for (int off = 1; off < 64; off <<= 1) { s += __shfl_xor(s, off); s2 += __shfl_xor(s2, off); }
  __shared__ float ls[4], ls2[4];
  const int w = t >> 6;
  if ((t & 63) == 0) { ls[w] = s; ls2[w] = s2; }
  __syncthreads();
  s  = ls[0] + ls[1] + ls[2] + ls[3];
  s2 = ls2[0] + ls2[1] + ls2[2] + ls2[3];
  const float mu   = s * (1.0f / 1024.0f);
  const float var  = s2 * (1.0f / 1024.0f) - mu * mu;
  const float rstd = rsqrtf(var + 1e-5f);
  float xv[4] = { v.x, v.y, v.z, v.w };
  u16 o[4];
  #pragma unroll
  for (int i = 0; i < 4; ++i)
    o[i] = f2bf((xv[i] - mu) * rstd * gg[t * 4 + i] + bb[t * 4 + i]);
  uint2 pv;
  pv.x = (unsigned)o[0] | ((unsigned)o[1] << 16);
  pv.y = (unsigned)o[2] | ((unsigned)o[3] << 16);
  *(uint2*)&dst[t * 4] = pv;
}

// ---------------- transpose+convert: f32 (R,C) -> bf16 (C,R) with out leading dim ----------------
__global__ __launch_bounds__(256) void transpose_k(
    const float* __restrict__ in, u16* __restrict__ out, int R, int C, int ldo, float scale)
{
  __shared__ float tile[64][65];
  const int c0 = blockIdx.x * 64, r0 = blockIdx.y * 64;
  const int t = threadIdx.x;
  const int tr = t >> 4, tc = (t & 15) * 4;
  #pragma unroll
  for (int i = 0; i < 4; ++i) {
    int r = tr + i * 16;
    float4 v = *(const float4*)&in[(size_t)(r0 + r) * C + c0 + tc];
    tile[r][tc + 0] = v.x; tile[r][tc + 1] = v.y; tile[r][tc + 2] = v.z; tile[r][tc + 3] = v.w;
  }
  __syncthreads();
  #pragma unroll
  for (int i = 0; i < 2; ++i) {
    int c  = (t >> 3) + i * 32;
    int rb = (t & 7) * 8;
    union { u16 s[8]; uint4 v; } pk;
    #pragma unroll
    for (int u = 0; u < 8; ++u) pk.s[u] = f2bf(tile[rb + u][c] * scale);
    *(uint4*)&out[(size_t)(c0 + c) * ldo + r0 + rb] = pk.v;
  }
}

// ---------------- Wff1 transpose with (a,gate) fragment interleave ----------------
__global__ __launch_bounds__(256) void transpose_ff1(
    const float* __restrict__ in, u16* __restrict__ out)
{
  __shared__ float tile[64][65];
  const int c0 = blockIdx.x * 64, r0 = blockIdx.y * 64;
  const int t = threadIdx.x;
  const int tr = t >> 4, tc = (t & 15) * 4;
  #pragma unroll
  for (int i = 0; i < 4; ++i) {
    int r = tr + i * 16;
    float4 v = *(const float4*)&in[(size_t)(r0 + r) * 8192 + c0 + tc];
    tile[r][tc + 0] = v.x; tile[r][tc + 1] = v.y; tile[r][tc + 2] = v.z; tile[r][tc + 3] = v.w;
  }
  __syncthreads();
  #pragma unroll
  for (int i = 0; i < 2; ++i) {
    int c  = (t >> 3) + i * 32;
    int rb = (t & 7) * 8;
    const int gc = c0 + c;
    int j, add16;
    if (gc < 4096) { j = gc; add16 = 0; } else { j = gc - 4096; add16 = 16; }
    const int row = 1024 + ((j >> 7) << 8) + (((j >> 5) & 3) << 6) + (((j >> 4) & 1) << 5) + add16 + (j & 15);
    union { u16 s[8]; uint4 v; } pk;
    #pragma unroll
    for (int u = 0; u < 8; ++u) pk.s[u] = f2bf(tile[rb + u][c]);
    *(uint4*)&out[(size_t)row * 1024 + r0 + rb] = pk.v;
  }
}

// =============== 4-phase 256x256 GEMM, BK=32, 64 KB LDS -> 2 blocks/CU ===============
// R11 retry with the launch-bounds bug fixed: (512,2) = 2 blocks/CU (CUDA semantics),
// 128-VGPR cap (spill-free for this accumulator; BK=64 build compiled to exactly 128).
#define MM32(MQ, M, NN) acc[MQ][M][NN] = __builtin_amdgcn_mfma_f32_16x16x32_bf16(af##M, bf##NN, acc[MQ][M][NN], 0, 0, 0)
#define MFMA16_32(MQ) \
  MM32(MQ,0,0); MM32(MQ,0,1); MM32(MQ,0,2); MM32(MQ,0,3); \
  MM32(MQ,1,0); MM32(MQ,1,1); MM32(MQ,1,2); MM32(MQ,1,3); \
  MM32(MQ,2,0); MM32(MQ,2,1); MM32(MQ,2,2); MM32(MQ,2,3); \
  MM32(MQ,3,0); MM32(MQ,3,1); MM32(MQ,3,2); MM32(MQ,3,3)

#define SA32(SBUF, H, KT) GLDS16(gA32[H] + ((size_t)(KT) << 5), SBUF + (size_t)((H) * 64 + w16o) * 32)
#define SB32(SBUF, H, KT) GLDS16(gB32[H] + ((size_t)(KT) << 5), SBUF + (size_t)((H) * 128 + w16o2) * 32)

#define DSB32(PB_) do { \
  bf0 = *(const short8*)(PB_ + 0    + cks); bf1 = *(const short8*)(PB_ + 512  + cks); \
  bf2 = *(const short8*)(PB_ + 1024 + cks); bf3 = *(const short8*)(PB_ + 1536 + cks); \
} while (0)

#define PC32(PA_, MQ, STAGE_STMT, GATE_STMT) do { \
  af0 = *(const short8*)(PA_ + (MQ) * 2048 + 0    + cks); \
  af1 = *(const short8*)(PA_ + (MQ) * 2048 + 512  + cks); \
  af2 = *(const short8*)(PA_ + (MQ) * 2048 + 1024 + cks); \
  af3 = *(const short8*)(PA_ + (MQ) * 2048 + 1536 + cks); \
  STAGE_STMT; \
  __builtin_amdgcn_s_barrier(); \
  asm volatile("s_waitcnt lgkmcnt(0)" ::: "memory"); \
  __builtin_amdgcn_s_setprio(1); \
  MFMA16_32(MQ); \
  __builtin_amdgcn_s_setprio(0); \
  GATE_STMT; \
  __builtin_amdgcn_s_barrier(); \
} while (0)

#define GATE3 asm volatile("s_waitcnt vmcnt(3)" ::: "memory")
#define GATE0 asm volatile("s_waitcnt vmcnt(0)" ::: "memory")

// MODE 2: qff fused epilogue (q bf16 + silu pair-fused h). MODE 3: bf16 split-K partials.
template<int MODE, int ORDER>
__global__ __launch_bounds__(512, 2) void gemm8p(
    const u16* __restrict__ A, const u16* __restrict__ BT, void* __restrict__ C,
    void* __restrict__ C2, int M, int N, int Ktot, int Kslice)
{
  __shared__ u16 sh[2][2][8192]; // [buf][A/B][256*32] = 64 KB
  const int nbn = N >> 8, nbm = M >> 8;
  const int nwg = gridDim.x;
  const int bid = blockIdx.x;
  const int o = (bid & 7) * (nwg >> 3) + (bid >> 3);  // chunked bijective XCD map (nwg%8==0)
  int bm, bn;
  if constexpr (ORDER == 0) { bm = o % nbm; bn = o / nbm; }  // B-strip per XCD
  else                      { bn = o % nbn; bm = o / nbn; }  // A-panels per XCD
  const int kbase = blockIdx.y * Kslice;
  const int NI = Kslice >> 6;      // two 32-K tiles per iteration

  const int t = threadIdx.x, w = t >> 6, lane = t & 63;
  const int wr = w >> 2, wc = w & 3;
  const int lr = lane & 15, lg = lane >> 4;
  const int l4 = lane >> 2, sl = lane & 3;
  const int w16o  = w * 16 + ((w >= 4) ? 64 : 0);  // A-half row base
  const int w16o2 = w * 16;                         // B-half row base

  const u16* gA32[2]; const u16* gB32[2];
  #pragma unroll
  for (int h = 0; h < 2; ++h) {
    const int rowA = h * 64 + w16o + l4;
    gA32[h] = A + (size_t)(bm * 256 + rowA) * Ktot + kbase + (size_t)((sl ^ ((rowA >> 1) & 3)) * 8);
    const int rowB = h * 128 + w16o2 + l4;
    gB32[h] = BT + (size_t)(bn * 256 + rowB) * Ktot + kbase + (size_t)((sl ^ ((rowB >> 1) & 3)) * 8);
  }
  u16* sA0 = &sh[0][0][0]; u16* sA1 = &sh[1][0][0];
  u16* sB0 = &sh[0][1][0]; u16* sB1 = &sh[1][1][0];
  const int cks = (lg ^ ((lr >> 1) & 3)) * 8;
  const u16* pA_b0 = sA0 + (wr * 128 + lr) * 32;
  const u16* pA_b1 = sA1 + (wr * 128 + lr) * 32;
  const u16* pB_b0 = sB0 + (wc * 64 + lr) * 32;
  const u16* pB_b1 = sB1 + (wc * 64 + lr) * 32;

  f32x4 acc[2][4][4];
  const f32x4 z4 = { 0.f, 0.f, 0.f, 0.f };
  #pragma unroll
  for (int a = 0; a < 2; ++a)
    #pragma unroll
    for (int b = 0; b < 4; ++b)
      #pragma unroll
      for (int c = 0; c < 4; ++c) acc[a][b][c] = z4;
  short8 af0, af1, af2, af3;
  short8 bf0, bf1, bf2, bf3;

  // prologue: tile0 -> buf0 (4 halves); tile1 -> buf1 (B0,B1,A0); A-h1(1) at first P0
  SA32(sA0, 0, 0); SA32(sA0, 1, 0); SB32(sB0, 0, 0); SB32(sB0, 1, 0);
  SB32(sB1, 0, 1); SB32(sB1, 1, 1); SA32(sA1, 0, 1);
  GATE3;
  __builtin_amdgcn_s_barrier();

  for (int i = 0; i < NI; ++i) {
    const bool st = (i < NI - 1);
    const int X = 2 * i + 2, Y = 2 * i + 3;
    // P0 (buf0, mq0): stage A-h1 of tile 2i+1 -> buf1
    DSB32(pB_b0);
    PC32(pA_b0, 0, SA32(sA1, 1, 2 * i + 1), );
    // P1 (buf0, mq1): stage B + A-h0 of tile X -> buf0; gate buf1
    PC32(pA_b0, 1,
         if (st) { SB32(sB0, 0, X); SB32(sB0, 1, X); SA32(sA0, 0, X); },
         if (st) { GATE3; } else { GATE0; });
    // P2 (buf1, mq0): stage A-h1(X) -> buf0
    DSB32(pB_b1);
    PC32(pA_b1, 0, if (st) { SA32(sA0, 1, X); }, );
    // P3 (buf1, mq1): stage B + A-h0 of tile Y -> buf1; gate next buf0
    PC32(pA_b1, 1,
         if (st) { SB32(sB1, 0, Y); SB32(sB1, 1, Y); SA32(sA1, 0, Y); },
         if (st) { GATE3; });
  }

  if constexpr (MODE == 3) {
    u16* Co = (u16*)C + (size_t)blockIdx.y * M * N;
    #pragma unroll
    for (int mq = 0; mq < 2; ++mq)
      #pragma unroll
      for (int m = 0; m < 4; ++m)
        #pragma unroll
        for (int n = 0; n < 4; ++n)
          #pragma unroll
          for (int rr = 0; rr < 4; ++rr) {
            const int row = bm * 256 + wr * 128 + mq * 64 + m * 16 + lg * 4 + rr;
            const int col = bn * 256 + wc * 64 + n * 16 + lr;
            Co[(size_t)row * N + col] = f2bf(acc[mq][m][n][rr]);
          }
  } else {
    if (bn < 4) {
      u16* Co = (u16*)C; // qbuf, stride 1024
      #pragma unroll
      for (int mq = 0; mq < 2; ++mq)
        #pragma unroll
        for (int m = 0; m < 4; ++m)
          #pragma unroll
          for (int n = 0; n < 4; ++n)
            #pragma unroll
            for (int rr = 0; rr < 4; ++rr) {
              const int row = bm * 256 + wr * 128 + mq * 64 + m * 16 + lg * 4 + rr;
              const int col = bn * 256 + wc * 64 + n * 16 + lr;
              Co[(size_t)row * 1024 + col] = f2bf(acc[mq][m][n][rr]);
            }
    } else {
      u16* Ho = (u16*)C2; // aoh, stride 5120, h starts at col 1024
      const int colb = 1024 + (bn - 4) * 128 + wc * 32 + lr;
      #pragma unroll
      for (int mq = 0; mq < 2; ++mq)
        #pragma unroll
        for (int m = 0; m < 4; ++m)
          #pragma unroll
          for (int rr = 0; rr < 4; ++rr) {
            const int row = bm * 256 + wr * 128 + mq * 64 + m * 16 + lg * 4 + rr;
            #pragma unroll
            for (int n2 = 0; n2 < 2; ++n2) {
              const float a = acc[mq][m][2 * n2][rr];
              const float gt = acc[mq][m][2 * n2 + 1][rr];
              const float h = a * gt / (1.0f + __expf(-gt));
              Ho[(size_t)row * 5120 + colb + n2 * 16] = f2bf(h);
            }
          }
    }
  }
}

// ---------------- split-K GEMM 128x128 (kv projection), bf16 partials ----------------
__global__ __launch_bounds__(256) void gemm_bt_sk(
    const u16* __restrict__ A, const u16* __restrict__ BT, u16* __restrict__ Cp,
    int M, int N, int Kslice, int Ktot)
{
  __shared__ u16 As[128 * 32];
  __shared__ u16 Bs[128 * 32];
  const int bm = blockIdx.y, bn = blockIdx.x, z = blockIdx.z;
  const int t = threadIdx.x;
  const int w = t >> 6, lane = t & 63;
  const int wr = w >> 1, wc = w & 1;
  const int lr = lane & 15, lkc = lane >> 4;

  f32x4 acc[4][4];
  const f32x4 z4 = { 0.f, 0.f, 0.f, 0.f };
  #pragma unroll
  for (int mi = 0; mi < 4; ++mi)
    #pragma unroll
    for (int ni = 0; ni < 4; ++ni) acc[mi][ni] = z4;

  const int kbase = z * Kslice;
  const int i0 = t, i1 = t + 256;
  const int r0 = i0 >> 2, k0 = swz4(r0, i0 & 3) * 8;
  const int r1 = i1 >> 2, k1 = swz4(r1, i1 & 3) * 8;
  const u16* a0 = A + (size_t)(bm * 128 + r0) * Ktot + kbase + k0;
  const u16* a1 = A + (size_t)(bm * 128 + r1) * Ktot + kbase + k1;
  const u16* b0 = BT + (size_t)(bn * 128 + r0) * Ktot + kbase + k0;
  const u16* b1 = BT + (size_t)(bn * 128 + r1) * Ktot + kbase + k1;
  u16* As0 = As + (size_t)w * 512;
  u16* As1 = As + (size_t)(w + 4) * 512;
  u16* Bs0 = Bs + (size_t)w * 512;
  u16* Bs1 = Bs + (size_t)(w + 4) * 512;

  const int nk = Kslice >> 5;
  for (int kt = 0; kt < nk; ++kt) {
    __syncthreads();
    GLDS16(a0, As0); GLDS16(a1, As1); GLDS16(b0, Bs0); GLDS16(b1, Bs1);
    a0 += 32; a1 += 32; b0 += 32; b1 += 32;
    __syncthreads();
    short8 af[4], bf[4];
    #pragma unroll
    for (int mi = 0; mi < 4; ++mi) {
      int row = wr * 64 + mi * 16 + lr;
      af[mi] = *(const short8*)&As[row * 32 + swz4(row, lkc) * 8];
    }
    #pragma unroll
    for (int ni = 0; ni < 4; ++ni) {
      int row = wc * 64 + ni * 16 + lr;
      bf[ni] = *(const short8*)&Bs[row * 32 + swz4(row, lkc) * 8];
    }
    #pragma unroll
    for (int mi = 0; mi < 4; ++mi)
      #pragma unroll
      for (int ni = 0; ni < 4; ++ni)
        acc[mi][ni] = __builtin_amdgcn_mfma_f32_16x16x32_bf16(af[mi], bf[ni], acc[mi][ni], 0, 0, 0);
  }

  u16* Cz = Cp + (size_t)z * M * N;
  const int row0 = bm * 128 + wr * 64, col0 = bn * 128 + wc * 64;
  const int rsub = (lane >> 4) * 4;
  #pragma unroll
  for (int mi = 0; mi < 4; ++mi)
    #pragma unroll
    for (int ni = 0; ni < 4; ++ni)
      #pragma unroll
      for (int r = 0; r < 4; ++r)
        Cz[(size_t)(row0 + mi * 16 + rsub + r) * N + (col0 + ni * 16 + lr)] = f2bf(acc[mi][ni][r]);
}

// ---------------- reduce 8 bf16 partials (4096x128) -> bf16 ----------------
__global__ __launch_bounds__(256) void reduce_kv(const u16* __restrict__ part, u16* __restrict__ out)
{
  const size_t base = ((size_t)blockIdx.x * 256 + threadIdx.x) * 8;
  float s[8] = { 0.f, 0.f, 0.f, 0.f, 0.f, 0.f, 0.f, 0.f };
  #pragma unroll
  for (int zz = 0; zz < 8; ++zz) {
    const short8 v = *(const short8*)&part[(size_t)zz * 524288 + base];
    #pragma unroll
    for (int i = 0; i < 8; ++i) s[i] += bf2f((u16)v[i]);
  }
  union { u16 o[8]; uint4 v; } pk;
  #pragma unroll
  for (int i = 0; i < 8; ++i) pk.o[i] = f2bf(s[i]);
  *(uint4*)&out[base] = pk.v;
}

// ---------------- out = sum of 8 bf16 partials (4096x1024) -> f32 ----------------
__global__ __launch_bounds__(256) void reduce_out(const u16* __restrict__ part, float* __restrict__ out)
{
  const size_t base = ((size_t)blockIdx.x * 256 + threadIdx.x) * 8;
  float s[8] = { 0.f, 0.f, 0.f, 0.f, 0.f, 0.f, 0.f, 0.f };
  #pragma unroll
  for (int zz = 0; zz < 8; ++zz) {
    const short8 v = *(const short8*)&part[(size_t)zz * 4194304 + base];
    #pragma unroll
    for (int i = 0; i < 8; ++i) s[i] += bf2f((u16)v[i]);
  }
  f32x4 lo = { s[0], s[1], s[2], s[3] };
  f32x4 hi = { s[4], s[5], s[6], s[7] };
  *(f32x4*)&out[base] = lo;
  *(f32x4*)&out[base + 4] = hi;
}

// ---------------- flash cross-attention (multi-query: 1 KV head) ----------------
__global__ __launch_bounds__(256) void attn_kernel(
    const u16* __restrict__ q, const u16* __restrict__ kv, u16* __restrict__ o)
{
  __shared__ u16 Ks[128 * 64];
  __shared__ u16 Vt[64 * 128];
  __shared__ u16 Ps[4][32 * 128];
  const int b = blockIdx.z, hb = blockIdx.y, qb = blockIdx.x;
  const int t = threadIdx.x, w = t >> 6, lane = t & 63;
  const int q32 = lane & 31, hl = lane >> 5;
  const int hd = hb * 4 + w;

  const size_t qbase = (size_t)b * 2048 + qb * 64;
  short8 qa[2][4];
  #pragma unroll
  for (int t32 = 0; t32 < 2; ++t32)
    #pragma unroll
    for (int dq = 0; dq < 4; ++dq)
      qa[t32][dq] = *(const short8*)&q[(qbase + t32 * 32 + q32) * 1024 + hd * 64 + dq * 16 + hl * 8];

  f32x16 oacc[2][2];
  #pragma unroll
  for (int i = 0; i < 2; ++i)
    #pragma unroll
    for (int j = 0; j < 2; ++j)
      #pragma unroll
      for (int r = 0; r < 16; ++r) oacc[i][j][r] = 0.f;
  float m_[2] = { -1e30f, -1e30f }, l_[2] = { 0.f, 0.f };

  const size_t kvb = (size_t)b * 2048 * 128;
  const int vd0 = (t & 7) * 8;
  const int vodd = (t >> 3) & 1;
  u16* Pw = &Ps[w][0];

  for (int jt = 0; jt < 16; ++jt) {
    __syncthreads();
    #pragma unroll
    for (int n = 0; n < 4; ++n) {
      const int cc = n * 256 + w * 64;
      const int ccl = cc + lane;
      const int row = ccl >> 3, lc = (ccl & 7) ^ (row & 7);
      GLDS16(&kv[kvb + (size_t)(jt * 128 + row) * 128 + lc * 8], Ks + (size_t)cc * 8);
    }
    #pragma unroll
    for (int c = 0; c < 4; ++c) {
      const int seg = c * 256 + t;
      const int vj = seg >> 3;
      const int jp = vj >> 1;
      const uint4 vv = *(const uint4*)&kv[kvb + (size_t)(jt * 128 + vj) * 128 + 64 + vd0];
      uint4 pvv;
      pvv.x = __shfl_xor((int)vv.x, 8);
      pvv.y = __shfl_xor((int)vv.y, 8);
      pvv.z = __shfl_xor((int)vv.z, 8);
      pvv.w = __shfl_xor((int)vv.w, 8);
      const unsigned ow[4] = { vv.x, vv.y, vv.z, vv.w };
      const unsigned pw[4] = { pvv.x, pvv.y, pvv.z, pvv.w };
      if (!vodd) {
        #pragma unroll
        for (int u = 0; u < 4; ++u) {
          const int d = vd0 + u;
          const unsigned own = (u & 1) ? (ow[u >> 1] >> 16) : (ow[u >> 1] & 0xffffu);
          const unsigned par = (u & 1) ? (pw[u >> 1] >> 16) : (pw[u >> 1] & 0xffffu);
          const int byteoff = d * 256 + ((4 * jp) ^ (((d & 7) ^ ((d >> 3) & 7)) << 4));
          *(unsigned*)((char*)Vt + byteoff) = own | (par << 16);
        }
      } else {
        #pragma unroll
        for (int u = 0; u < 4; ++u) {
          const int ue = u + 4;
          const int d = vd0 + ue;
          const unsigned own = (ue & 1) ? (ow[ue >> 1] >> 16) : (ow[ue >> 1] & 0xffffu);
          const unsigned par = (ue & 1) ? (pw[ue >> 1] >> 16) : (pw[ue >> 1] & 0xffffu);
          const int byteoff = d * 256 + ((4 * jp) ^ (((d & 7) ^ ((d >> 3) & 7)) << 4));
          *(unsigned*)((char*)Vt + byteoff) = par | (own << 16);
        }
      }
    }
    __syncthreads();

    #pragma unroll
    for (int t32 = 0; t32 < 2; ++t32) {
      f32x16 s[4];
      #pragma unroll
      for (int j32 = 0; j32 < 4; ++j32)
        #pragma unroll
        for (int r = 0; r < 16; ++r) s[j32][r] = 0.f;
      #pragma unroll
      for (int j32 = 0; j32 < 4; ++j32) {
        const int row = j32 * 32 + q32;
        #pragma unroll
        for (int dq = 0; dq < 4; ++dq) {
          const int slot = (dq * 2 + hl) ^ (row & 7);
          const short8 kf = *(const short8*)&Ks[row * 64 + slot * 8];
          s[j32] = __builtin_amdgcn_mfma_f32_32x32x16_bf16(kf, qa[t32][dq], s[j32], 0, 0, 0);
        }
      }
      float mt = -1e30f;
      #pragma unroll
      for (int j32 = 0; j32 < 4; ++j32)
        #pragma unroll
        for (int r = 0; r < 16; ++r) mt = fmaxf(mt, s[j32][r]);
      mt = fmaxf(mt, __shfl_xor(mt, 32));
      const bool noresc = (bool)__all(mt <= m_[t32] + 8.0f);
      float nm = m_[t32];
      if (!noresc) {
        nm = fmaxf(m_[t32], mt);
        const float alpha = __expf(m_[t32] - nm);
        m_[t32] = nm;
        l_[t32] *= alpha;
        #pragma unroll
        for (int d32 = 0; d32 < 2; ++d32)
          #pragma unroll
          for (int r = 0; r < 16; ++r) oacc[t32][d32][r] *= alpha;
      }
      float lsum = 0.f;
      #pragma unroll
      for (int j32 = 0; j32 < 4; ++j32) {
        float p[16];
        #pragma unroll
        for (int r = 0; r < 16; ++r) { p[r] = __expf(s[j32][r] - nm); lsum += p[r]; }
        #pragma unroll
        for (int g = 0; g < 4; ++g) {
          const unsigned lo = cvtpk(p[4 * g + 0], p[4 * g + 1]);
          const unsigned hi = cvtpk(p[4 * g + 2], p[4 * g + 3]);
          const int j2 = j32 * 64 + 16 * g + 8 * hl;
          const int byteoff = q32 * 256 + (j2 ^ ((q32 & 7) << 4));
          uint2 wv; wv.x = lo; wv.y = hi;
          *(uint2*)((char*)Pw + byteoff) = wv;
        }
      }
      lsum += __shfl_xor(lsum, 32);
      l_[t32] += lsum;
      short8 pf[8];
      #pragma unroll
      for (int kk = 0; kk < 8; ++kk) {
        const int byteoff = q32 * 256 + ((kk * 32 + hl * 16) ^ ((q32 & 7) << 4));
        pf[kk] = *(const short8*)((const char*)Pw + byteoff);
      }
      #pragma unroll
      for (int d32 = 0; d32 < 2; ++d32) {
        const int dr = d32 * 32 + q32;
        const int vswz = ((dr & 7) ^ ((dr >> 3) & 7)) << 4;
        #pragma unroll
        for (int kk = 0; kk < 8; ++kk) {
          const int byteoff = dr * 256 + ((kk * 32 + hl * 16) ^ vswz);
          const short8 vf = *(const short8*)((const char*)Vt + byteoff);
          oacc[t32][d32] = __builtin_amdgcn_mfma_f32_32x32x16_bf16(vf, pf[kk], oacc[t32][d32], 0, 0, 0);
        }
      }
    }
  }

  float* Ot = (float*)Pw;
  #pragma unroll
  for (int t32 = 0; t32 < 2; ++t32) {
    const float inv = 1.0f / l_[t32];
    #pragma unroll
    for (int d32 = 0; d32 < 2; ++d32) {
      #pragma unroll
      for (int r = 0; r < 16; ++r) {
        const int d = (r & 3) + 8 * (r >> 2) + 4 * hl;
        const int byteoff = q32 * 128 + ((4 * d) ^ ((q32 & 7) << 4));
        *(float*)((char*)Ot + byteoff) = oacc[t32][d32][r] * inv;
      }
      const int qr = lane >> 1, dc = (lane & 1) * 16;
      union { u16 s[16]; uint4 v[2]; } ob;
      #pragma unroll
      for (int cch = 0; cch < 4; ++cch) {
        const int byteoff = qr * 128 + ((4 * (dc + 4 * cch)) ^ ((qr & 7) << 4));
        const f32x4 vv = *(const f32x4*)((const char*)Ot + byteoff);
        ob.s[cch * 4 + 0] = f2bf(vv[0]);
        ob.s[cch * 4 + 1] = f2bf(vv[1]);
        ob.s[cch * 4 + 2] = f2bf(vv[2]);
        ob.s[cch * 4 + 3] = f2bf(vv[3]);
      }
      u16* orow = &o[(qbase + t32 * 32 + qr) * 5120 + hd * 64 + d32 * 32 + dc];
      *(uint4*)orow = ob.v[0];
      *(uint4*)(orow + 8) = ob.v[1];
    }
  }
}

extern "C" void kernel_launch(void* const* d_in, const int* in_sizes, int n_in,
                              void* d_out, int out_size, void* d_ws, size_t ws_size,
                              hipStream_t stream)
{
  const float* x    = (const float*)d_in[0];
  const float* ctx  = (const float*)d_in[1];
  const float* ng   = (const float*)d_in[2];
  const float* nb   = (const float*)d_in[3];
  const float* cg   = (const float*)d_in[4];
  const float* cb   = (const float*)d_in[5];
  const float* Wq   = (const float*)d_in[6];
  const float* Wkv  = (const float*)d_in[7];
  const float* Wo   = (const float*)d_in[8];
  const float* Wff1 = (const float*)d_in[9];
  const float* Wff2 = (const float*)d_in[10];

  u16* p = (u16*)d_ws;
  u16* W1T   = p; p += (size_t)9216 * 1024;
  u16* WkvT  = p; p += (size_t)128 * 1024;
  u16* WcT   = p; p += (size_t)1024 * 5120;
  u16* kvbuf = p; p += (size_t)4096 * 128;
  u16* aoh   = p; p += (size_t)4096 * 5120;
  u16* xn    = p; p += (size_t)4096 * 1024;
  u16* cn    = p; p += (size_t)4096 * 1024;
  u16* qbuf  = p; p += (size_t)4096 * 1024;
  u16* kvpart = W1T;   // 8 MB bf16 over W1T (dead after qff GEMM)
  u16* ffpart = xn;    // 64 MB bf16 over xn|cn|qbuf + ws tail (all dead by final GEMM)
  (void)in_sizes; (void)n_in; (void)out_size; (void)ws_size;

  ln_kernel<<<8192, 256, 0, stream>>>(x, ctx, ng, nb, cg, cb, xn, cn);

  transpose_k<<<dim3(16, 16),  256, 0, stream>>>(Wq,   W1T,        1024, 1024, 1024, 0.125f);
  transpose_ff1<<<dim3(128, 16), 256, 0, stream>>>(Wff1, W1T);
  transpose_k<<<dim3(2, 16),   256, 0, stream>>>(Wkv,  WkvT,       1024, 128,  1024, 1.0f);
  transpose_k<<<dim3(16, 16),  256, 0, stream>>>(Wo,   WcT,        1024, 1024, 5120, 1.0f);
  transpose_k<<<dim3(16, 64),  256, 0, stream>>>(Wff2, WcT + 1024, 4096, 1024, 5120, 1.0f);

  // fused: qbuf = xn@Wq*scale ; aoh[:,1024:] = silu(xn@Wff1); ORDER 0; 2 blocks/CU
  gemm8p<2, 0><<<dim3(576), 512, 0, stream>>>(xn, W1T, qbuf, aoh, 4096, 9216, 1024, 1024);
  // kv = cn @ Wkv, split-K 8 (bf16 partials over dead W1T), reduce to bf16
  gemm_bt_sk<<<dim3(1, 32, 8), 256, 0, stream>>>(cn, WkvT, kvpart, 4096, 128, 128, 1024);
  reduce_kv<<<256, 256, 0, stream>>>(kvpart, kvbuf);
  // attention -> aoh[:,0:1024]
  attn_kernel<<<dim3(32, 4, 2), 256, 0, stream>>>(qbuf, kvbuf, aoh);
  // out = aoh @ [Wo ; Wff2], split-K 8 (512 blocks -> 2/CU), bf16 partials; ORDER 1
  gemm8p<3, 1><<<dim3(64, 8), 512, 0, stream>>>(aoh, WcT, ffpart, nullptr, 4096, 1024, 5120, 640);
  reduce_out<<<2048, 256, 0, stream>>>(ffpart, (float*)d_out);
}

// Round 13
// 289.772 us; speedup vs baseline: 4.7175x; 1.0605x over previous
//
#include <hip/hip_runtime.h>
#include <stdint.h>

typedef unsigned short u16;
typedef __attribute__((ext_vector_type(8))) short short8;
typedef __attribute__((ext_vector_type(4))) float f32x4;
typedef __attribute__((ext_vector_type(16))) float f32x16;

#define GPTR(p) ((const __attribute__((address_space(1))) void*)(p))
#define SPTR(p) ((__attribute__((address_space(3))) void*)(p))
#define GLDS16(g, l) __builtin_amdgcn_global_load_lds(GPTR(g), SPTR(l), 16, 0, 0)

static __device__ __forceinline__ float bf2f(u16 u) {
  union { unsigned int i; float f; } c; c.i = ((unsigned int)u) << 16; return c.f;
}
static __device__ __forceinline__ u16 f2bf(float f) {
  union { float f; unsigned int u; } c; c.f = f;
  unsigned int r = 0x7fffu + ((c.u >> 16) & 1u);
  return (u16)((c.u + r) >> 16);
}
static __device__ __forceinline__ unsigned cvtpk(float a, float b) {
  unsigned r;
  asm volatile("v_cvt_pk_bf16_f32 %0, %1, %2" : "=v"(r) : "v"(a), "v"(b));
  return r;
}
static __device__ __forceinline__ int swz4(int row, int c) { return c ^ ((row >> 1) & 3); }

// ---------------- LayerNorm: f32 (rows of 1024) -> bf16 ----------------
__global__ __launch_bounds__(256) void ln_kernel(
    const float* __restrict__ x, const float* __restrict__ ctx,
    const float* __restrict__ g, const float* __restrict__ b,
    const float* __restrict__ cg, const float* __restrict__ cb,
    u16* __restrict__ xn, u16* __restrict__ cn)
{
  const int row = blockIdx.x;
  const float* src; const float* gg; const float* bb; u16* dst;
  if (row < 4096) { src = x + (size_t)row * 1024; gg = g;  bb = b;  dst = xn + (size_t)row * 1024; }
  else            { src = ctx + (size_t)(row - 4096) * 1024; gg = cg; bb = cb; dst = cn + (size_t)(row - 4096) * 1024; }
  const int t = threadIdx.x;
  float4 v = *(const float4*)&src[t * 4];
  float s  = v.x + v.y + v.z + v.w;
  float s2 = v.x * v.x + v.y * v.y + v.z * v.z + v.w * v.w;
  #pragma unroll
  for (int off = 1; off < 64; off <<= 1) { s += __shfl_xor(s, off); s2 += __shfl_xor(s2, off); }
  __shared__ float ls[4], ls2[4];
  const int w = t >> 6;
  if ((t & 63) == 0) { ls[w] = s; ls2[w] = s2; }
  __syncthreads();
  s  = ls[0] + ls[1] + ls[2] + ls[3];
  s2 = ls2[0] + ls2[1] + ls2[2] + ls2[3];
  const float mu   = s * (1.0f / 1024.0f);
  const float var  = s2 * (1.0f / 1024.0f) - mu * mu;
  const float rstd = rsqrtf(var + 1e-5f);
  float xv[4] = { v.x, v.y, v.z, v.w };
  u16 o[4];
  #pragma unroll
  for (int i = 0; i < 4; ++i)
    o[i] = f2bf((xv[i] - mu) * rstd * gg[t * 4 + i] + bb[t * 4 + i]);
  uint2 pv;
  pv.x = (unsigned)o[0] | ((unsigned)o[1] << 16);
  pv.y = (unsigned)o[2] | ((unsigned)o[3] << 16);
  *(uint2*)&dst[t * 4] = pv;
}

// ---------------- transpose+convert: f32 (R,C) -> bf16 (C,R) with out leading dim ----------------
__global__ __launch_bounds__(256) void transpose_k(
    const float* __restrict__ in, u16* __restrict__ out, int R, int C, int ldo, float scale)
{
  __shared__ float tile[64][65];
  const int c0 = blockIdx.x * 64, r0 = blockIdx.y * 64;
  const int t = threadIdx.x;
  const int tr = t >> 4, tc = (t & 15) * 4;
  #pragma unroll
  for (int i = 0; i < 4; ++i) {
    int r = tr + i * 16;
    float4 v = *(const float4*)&in[(size_t)(r0 + r) * C + c0 + tc];
    tile[r][tc + 0] = v.x; tile[r][tc + 1] = v.y; tile[r][tc + 2] = v.z; tile[r][tc + 3] = v.w;
  }
  __syncthreads();
  #pragma unroll
  for (int i = 0; i < 2; ++i) {
    int c  = (t >> 3) + i * 32;
    int rb = (t & 7) * 8;
    union { u16 s[8]; uint4 v; } pk;
    #pragma unroll
    for (int u = 0; u < 8; ++u) pk.s[u] = f2bf(tile[rb + u][c] * scale);
    *(uint4*)&out[(size_t)(c0 + c) * ldo + r0 + rb] = pk.v;
  }
}

// ---------------- Wff1 transpose with (a,gate) fragment interleave ----------------
__global__ __launch_bounds__(256) void transpose_ff1(
    const float* __restrict__ in, u16* __restrict__ out)
{
  __shared__ float tile[64][65];
  const int c0 = blockIdx.x * 64, r0 = blockIdx.y * 64;
  const int t = threadIdx.x;
  const int tr = t >> 4, tc = (t & 15) * 4;
  #pragma unroll
  for (int i = 0; i < 4; ++i) {
    int r = tr + i * 16;
    float4 v = *(const float4*)&in[(size_t)(r0 + r) * 8192 + c0 + tc];
    tile[r][tc + 0] = v.x; tile[r][tc + 1] = v.y; tile[r][tc + 2] = v.z; tile[r][tc + 3] = v.w;
  }
  __syncthreads();
  #pragma unroll
  for (int i = 0; i < 2; ++i) {
    int c  = (t >> 3) + i * 32;
    int rb = (t & 7) * 8;
    const int gc = c0 + c;
    int j, add16;
    if (gc < 4096) { j = gc; add16 = 0; } else { j = gc - 4096; add16 = 16; }
    const int row = 1024 + ((j >> 7) << 8) + (((j >> 5) & 3) << 6) + (((j >> 4) & 1) << 5) + add16 + (j & 15);
    union { u16 s[8]; uint4 v; } pk;
    #pragma unroll
    for (int u = 0; u < 8; ++u) pk.s[u] = f2bf(tile[rb + u][c]);
    *(uint4*)&out[(size_t)row * 1024 + r0 + rb] = pk.v;
  }
}

// =============== BK=32 4-phase 256x256 GEMM (qff; measured best for K=1024 M-heavy) ===============
#define MM32(MQ, M, NN) acc[MQ][M][NN] = __builtin_amdgcn_mfma_f32_16x16x32_bf16(af##M, bf##NN, acc[MQ][M][NN], 0, 0, 0)
#define MFMA16_32(MQ) \
  MM32(MQ,0,0); MM32(MQ,0,1); MM32(MQ,0,2); MM32(MQ,0,3); \
  MM32(MQ,1,0); MM32(MQ,1,1); MM32(MQ,1,2); MM32(MQ,1,3); \
  MM32(MQ,2,0); MM32(MQ,2,1); MM32(MQ,2,2); MM32(MQ,2,3); \
  MM32(MQ,3,0); MM32(MQ,3,1); MM32(MQ,3,2); MM32(MQ,3,3)

#define SA32(SBUF, H, KT) GLDS16(gA32[H] + ((size_t)(KT) << 5), SBUF + (size_t)((H) * 64 + w16o) * 32)
#define SB32(SBUF, H, KT) GLDS16(gB32[H] + ((size_t)(KT) << 5), SBUF + (size_t)((H) * 128 + w16o2) * 32)

#define DSB32(PB_) do { \
  bf0 = *(const short8*)(PB_ + 0    + cks); bf1 = *(const short8*)(PB_ + 512  + cks); \
  bf2 = *(const short8*)(PB_ + 1024 + cks); bf3 = *(const short8*)(PB_ + 1536 + cks); \
} while (0)

#define PC32(PA_, MQ, STAGE_STMT, GATE_STMT) do { \
  af0 = *(const short8*)(PA_ + (MQ) * 2048 + 0    + cks); \
  af1 = *(const short8*)(PA_ + (MQ) * 2048 + 512  + cks); \
  af2 = *(const short8*)(PA_ + (MQ) * 2048 + 1024 + cks); \
  af3 = *(const short8*)(PA_ + (MQ) * 2048 + 1536 + cks); \
  STAGE_STMT; \
  __builtin_amdgcn_s_barrier(); \
  asm volatile("s_waitcnt lgkmcnt(0)" ::: "memory"); \
  __builtin_amdgcn_s_setprio(1); \
  MFMA16_32(MQ); \
  __builtin_amdgcn_s_setprio(0); \
  GATE_STMT; \
  __builtin_amdgcn_s_barrier(); \
} while (0)

#define GATE3 asm volatile("s_waitcnt vmcnt(3)" ::: "memory")
#define GATE0 asm volatile("s_waitcnt vmcnt(0)" ::: "memory")

// MODE 2: qff fused epilogue (q bf16 + silu pair-fused h)
template<int MODE, int ORDER>
__global__ __launch_bounds__(512, 2) void gemm32(
    const u16* __restrict__ A, const u16* __restrict__ BT, void* __restrict__ C,
    void* __restrict__ C2, int M, int N, int Ktot, int Kslice)
{
  __shared__ u16 sh[2][2][8192]; // 64 KB
  const int nbn = N >> 8, nbm = M >> 8;
  const int nwg = gridDim.x;
  const int bid = blockIdx.x;
  const int o = (bid & 7) * (nwg >> 3) + (bid >> 3);
  int bm, bn;
  if constexpr (ORDER == 0) { bm = o % nbm; bn = o / nbm; }
  else                      { bn = o % nbn; bm = o / nbn; }
  const int kbase = blockIdx.y * Kslice;
  const int NI = Kslice >> 6;

  const int t = threadIdx.x, w = t >> 6, lane = t & 63;
  const int wr = w >> 2, wc = w & 3;
  const int lr = lane & 15, lg = lane >> 4;
  const int l4 = lane >> 2, sl = lane & 3;
  const int w16o  = w * 16 + ((w >= 4) ? 64 : 0);
  const int w16o2 = w * 16;

  const u16* gA32[2]; const u16* gB32[2];
  #pragma unroll
  for (int h = 0; h < 2; ++h) {
    const int rowA = h * 64 + w16o + l4;
    gA32[h] = A + (size_t)(bm * 256 + rowA) * Ktot + kbase + (size_t)((sl ^ ((rowA >> 1) & 3)) * 8);
    const int rowB = h * 128 + w16o2 + l4;
    gB32[h] = BT + (size_t)(bn * 256 + rowB) * Ktot + kbase + (size_t)((sl ^ ((rowB >> 1) & 3)) * 8);
  }
  u16* sA0 = &sh[0][0][0]; u16* sA1 = &sh[1][0][0];
  u16* sB0 = &sh[0][1][0]; u16* sB1 = &sh[1][1][0];
  const int cks = (lg ^ ((lr >> 1) & 3)) * 8;
  const u16* pA_b0 = sA0 + (wr * 128 + lr) * 32;
  const u16* pA_b1 = sA1 + (wr * 128 + lr) * 32;
  const u16* pB_b0 = sB0 + (wc * 64 + lr) * 32;
  const u16* pB_b1 = sB1 + (wc * 64 + lr) * 32;

  f32x4 acc[2][4][4];
  const f32x4 z4 = { 0.f, 0.f, 0.f, 0.f };
  #pragma unroll
  for (int a = 0; a < 2; ++a)
    #pragma unroll
    for (int b = 0; b < 4; ++b)
      #pragma unroll
      for (int c = 0; c < 4; ++c) acc[a][b][c] = z4;
  short8 af0, af1, af2, af3;
  short8 bf0, bf1, bf2, bf3;

  SA32(sA0, 0, 0); SA32(sA0, 1, 0); SB32(sB0, 0, 0); SB32(sB0, 1, 0);
  SB32(sB1, 0, 1); SB32(sB1, 1, 1); SA32(sA1, 0, 1);
  GATE3;
  __builtin_amdgcn_s_barrier();

  for (int i = 0; i < NI; ++i) {
    const bool st = (i < NI - 1);
    const int X = 2 * i + 2, Y = 2 * i + 3;
    DSB32(pB_b0);
    PC32(pA_b0, 0, SA32(sA1, 1, 2 * i + 1), );
    PC32(pA_b0, 1,
         if (st) { SB32(sB0, 0, X); SB32(sB0, 1, X); SA32(sA0, 0, X); },
         if (st) { GATE3; } else { GATE0; });
    DSB32(pB_b1);
    PC32(pA_b1, 0, if (st) { SA32(sA0, 1, X); }, );
    PC32(pA_b1, 1,
         if (st) { SB32(sB1, 0, Y); SB32(sB1, 1, Y); SA32(sA1, 0, Y); },
         if (st) { GATE3; });
  }

  if (bn < 4) {
    u16* Co = (u16*)C; // qbuf, stride 1024
    #pragma unroll
    for (int mq = 0; mq < 2; ++mq)
      #pragma unroll
      for (int m = 0; m < 4; ++m)
        #pragma unroll
        for (int n = 0; n < 4; ++n)
          #pragma unroll
          for (int rr = 0; rr < 4; ++rr) {
            const int row = bm * 256 + wr * 128 + mq * 64 + m * 16 + lg * 4 + rr;
            const int col = bn * 256 + wc * 64 + n * 16 + lr;
            Co[(size_t)row * 1024 + col] = f2bf(acc[mq][m][n][rr]);
          }
  } else {
    u16* Ho = (u16*)C2; // aoh, stride 5120, h starts at col 1024
    const int colb = 1024 + (bn - 4) * 128 + wc * 32 + lr;
    #pragma unroll
    for (int mq = 0; mq < 2; ++mq)
      #pragma unroll
      for (int m = 0; m < 4; ++m)
        #pragma unroll
        for (int rr = 0; rr < 4; ++rr) {
          const int row = bm * 256 + wr * 128 + mq * 64 + m * 16 + lg * 4 + rr;
          #pragma unroll
          for (int n2 = 0; n2 < 2; ++n2) {
            const float a = acc[mq][m][2 * n2][rr];
            const float gt = acc[mq][m][2 * n2 + 1][rr];
            const float h = a * gt / (1.0f + __expf(-gt));
            Ho[(size_t)row * 5120 + colb + n2 * 16] = f2bf(h);
          }
        }
  }
}

// =============== BK=64 8-phase 256x256 GEMM (final GEMM; measured best for K=5120 split-K 4) ===============
#define MM1(MQ, M, NN, BF) acc[MQ][M][NN] = __builtin_amdgcn_mfma_f32_16x16x32_bf16(af##M, BF, acc[MQ][M][NN], 0, 0, 0)
#define MFMA16(MQ, KS) \
  MM1(MQ,0,0,bf##KS##0); MM1(MQ,0,1,bf##KS##1); MM1(MQ,0,2,bf##KS##2); MM1(MQ,0,3,bf##KS##3); \
  MM1(MQ,1,0,bf##KS##0); MM1(MQ,1,1,bf##KS##1); MM1(MQ,1,2,bf##KS##2); MM1(MQ,1,3,bf##KS##3); \
  MM1(MQ,2,0,bf##KS##0); MM1(MQ,2,1,bf##KS##1); MM1(MQ,2,2,bf##KS##2); MM1(MQ,2,3,bf##KS##3); \
  MM1(MQ,3,0,bf##KS##0); MM1(MQ,3,1,bf##KS##1); MM1(MQ,3,2,bf##KS##2); MM1(MQ,3,3,bf##KS##3)

#define SG_A(SBUF, H, KT) do { \
    GLDS16(gA[H][0] + ((size_t)(KT) << 6), SBUF + ((H) * 64 + w16o) * 64); \
    GLDS16(gA[H][1] + ((size_t)(KT) << 6), SBUF + ((H) * 64 + w16o + 8) * 64); \
  } while (0)
#define SG_B(SBUF, H, KT) do { \
    GLDS16(gB[H][0] + ((size_t)(KT) << 6), SBUF + ((H) * 128 + w16o2) * 64); \
    GLDS16(gB[H][1] + ((size_t)(KT) << 6), SBUF + ((H) * 128 + w16o2 + 8) * 64); \
  } while (0)

#define DS_B(PB_) do { \
  bf00 = *(const short8*)(PB_ + 0    + cks0); bf01 = *(const short8*)(PB_ + 1024 + cks0); \
  bf02 = *(const short8*)(PB_ + 2048 + cks0); bf03 = *(const short8*)(PB_ + 3072 + cks0); \
  bf10 = *(const short8*)(PB_ + 0    + cks1); bf11 = *(const short8*)(PB_ + 1024 + cks1); \
  bf12 = *(const short8*)(PB_ + 2048 + cks1); bf13 = *(const short8*)(PB_ + 3072 + cks1); \
} while (0)

#define P_CORE(PA_, MQ, KS, STAGE_STMT, PREB_STMT, GATE_STMT) do { \
  af0 = *(const short8*)(PA_ + (MQ) * 4096 + 0    + cks##KS); \
  af1 = *(const short8*)(PA_ + (MQ) * 4096 + 1024 + cks##KS); \
  af2 = *(const short8*)(PA_ + (MQ) * 4096 + 2048 + cks##KS); \
  af3 = *(const short8*)(PA_ + (MQ) * 4096 + 3072 + cks##KS); \
  STAGE_STMT; \
  PREB_STMT; \
  __builtin_amdgcn_s_barrier(); \
  asm volatile("s_waitcnt lgkmcnt(0)" ::: "memory"); \
  __builtin_amdgcn_s_setprio(1); \
  MFMA16(MQ, KS); \
  __builtin_amdgcn_s_setprio(0); \
  GATE_STMT; \
  __builtin_amdgcn_s_barrier(); \
} while (0)

#define GATE6 asm volatile("s_waitcnt vmcnt(6)" ::: "memory")
#define HINT8 asm volatile("s_waitcnt lgkmcnt(8)" ::: "memory")

// MODE 3: bf16 split-K partials. ORDER 1: A-panels per XCD.
template<int MODE, int ORDER>
__global__ __launch_bounds__(512, 2) void gemm64(
    const u16* __restrict__ A, const u16* __restrict__ BT, void* __restrict__ C,
    void* __restrict__ C2, int M, int N, int Ktot, int Kslice)
{
  __shared__ u16 sh[2][2][16384]; // 128 KB
  const int nbn = N >> 8, nbm = M >> 8;
  const int nwg = gridDim.x;
  const int bid = blockIdx.x;
  const int o = (bid & 7) * (nwg >> 3) + (bid >> 3);
  int bm, bn;
  if constexpr (ORDER == 0) { bm = o % nbm; bn = o / nbm; }
  else                      { bn = o % nbn; bm = o / nbn; }
  const int kbase = blockIdx.y * Kslice;
  const int NI = Kslice >> 7;

  const int t = threadIdx.x, w = t >> 6, lane = t & 63;
  const int wr = w >> 2, wc = w & 3;
  const int lr = lane & 15, lg = lane >> 4;
  const int r8 = lane >> 3, ch = lane & 7;
  const int clog = ch ^ r8;
  const int w16o  = w * 16 + ((w >= 4) ? 64 : 0);
  const int w16o2 = w * 16;

  const u16* gA[2][2]; const u16* gB[2][2];
  #pragma unroll
  for (int h = 0; h < 2; ++h)
    #pragma unroll
    for (int qq = 0; qq < 2; ++qq) {
      gA[h][qq] = A  + (size_t)(bm * 256 + h * 64  + w16o  + qq * 8 + r8) * Ktot + kbase + clog * 8;
      gB[h][qq] = BT + (size_t)(bn * 256 + h * 128 + w16o2 + qq * 8 + r8) * Ktot + kbase + clog * 8;
    }
  u16* sA0 = &sh[0][0][0]; u16* sA1 = &sh[1][0][0];
  u16* sB0 = &sh[0][1][0]; u16* sB1 = &sh[1][1][0];
  const int cks0 = ((0 + lg) ^ (lr & 7)) * 8;
  const int cks1 = ((4 + lg) ^ (lr & 7)) * 8;
  const u16* pA_b0 = sA0 + (wr * 128 + lr) * 64;
  const u16* pA_b1 = sA1 + (wr * 128 + lr) * 64;
  const u16* pB_b0 = sB0 + (wc * 64 + lr) * 64;
  const u16* pB_b1 = sB1 + (wc * 64 + lr) * 64;

  f32x4 acc[2][4][4];
  const f32x4 z4 = { 0.f, 0.f, 0.f, 0.f };
  #pragma unroll
  for (int a = 0; a < 2; ++a)
    #pragma unroll
    for (int b = 0; b < 4; ++b)
      #pragma unroll
      for (int c = 0; c < 4; ++c) acc[a][b][c] = z4;
  short8 af0, af1, af2, af3;
  short8 bf00, bf01, bf02, bf03, bf10, bf11, bf12, bf13;

  SG_B(sB0, 0, 0); SG_B(sB0, 1, 0); SG_A(sA0, 0, 0); SG_A(sA0, 1, 0);
  SG_B(sB1, 0, 1); SG_B(sB1, 1, 1); SG_A(sA1, 0, 1);
  GATE6;
  __builtin_amdgcn_s_barrier();

  for (int i = 0; i < NI; ++i) {
    const int k2 = 2 * i;
    const bool st = (i < NI - 1);
    DS_B(pB_b0);
    P_CORE(pA_b0, 0, 0, SG_A(sA1, 1, k2 + 1), HINT8, );
    P_CORE(pA_b0, 1, 0, if (st) SG_B(sB0, 0, k2 + 2), , );
    P_CORE(pA_b0, 0, 1, if (st) SG_B(sB0, 1, k2 + 2), , );
    P_CORE(pA_b0, 1, 1, if (st) SG_A(sA0, 0, k2 + 2), ,
           if (st) { GATE6; } else { GATE0; });
    DS_B(pB_b1);
    P_CORE(pA_b1, 0, 0, if (st) SG_A(sA0, 1, k2 + 2), HINT8, );
    P_CORE(pA_b1, 1, 0, if (st) SG_B(sB1, 0, k2 + 3), , );
    P_CORE(pA_b1, 0, 1, if (st) SG_B(sB1, 1, k2 + 3), , );
    P_CORE(pA_b1, 1, 1, if (st) SG_A(sA1, 0, k2 + 3), ,
           if (st) { GATE6; });
  }

  u16* Co = (u16*)C + (size_t)blockIdx.y * M * N;
  #pragma unroll
  for (int mq = 0; mq < 2; ++mq)
    #pragma unroll
    for (int m = 0; m < 4; ++m)
      #pragma unroll
      for (int n = 0; n < 4; ++n)
        #pragma unroll
        for (int rr = 0; rr < 4; ++rr) {
          const int row = bm * 256 + wr * 128 + mq * 64 + m * 16 + lg * 4 + rr;
          const int col = bn * 256 + wc * 64 + n * 16 + lr;
          Co[(size_t)row * N + col] = f2bf(acc[mq][m][n][rr]);
        }
}

// ---------------- split-K GEMM 128x128 (kv projection), bf16 partials ----------------
__global__ __launch_bounds__(256) void gemm_bt_sk(
    const u16* __restrict__ A, const u16* __restrict__ BT, u16* __restrict__ Cp,
    int M, int N, int Kslice, int Ktot)
{
  __shared__ u16 As[128 * 32];
  __shared__ u16 Bs[128 * 32];
  const int bm = blockIdx.y, bn = blockIdx.x, z = blockIdx.z;
  const int t = threadIdx.x;
  const int w = t >> 6, lane = t & 63;
  const int wr = w >> 1, wc = w & 1;
  const int lr = lane & 15, lkc = lane >> 4;

  f32x4 acc[4][4];
  const f32x4 z4 = { 0.f, 0.f, 0.f, 0.f };
  #pragma unroll
  for (int mi = 0; mi < 4; ++mi)
    #pragma unroll
    for (int ni = 0; ni < 4; ++ni) acc[mi][ni] = z4;

  const int kbase = z * Kslice;
  const int i0 = t, i1 = t + 256;
  const int r0 = i0 >> 2, k0 = swz4(r0, i0 & 3) * 8;
  const int r1 = i1 >> 2, k1 = swz4(r1, i1 & 3) * 8;
  const u16* a0 = A + (size_t)(bm * 128 + r0) * Ktot + kbase + k0;
  const u16* a1 = A + (size_t)(bm * 128 + r1) * Ktot + kbase + k1;
  const u16* b0 = BT + (size_t)(bn * 128 + r0) * Ktot + kbase + k0;
  const u16* b1 = BT + (size_t)(bn * 128 + r1) * Ktot + kbase + k1;
  u16* As0 = As + (size_t)w * 512;
  u16* As1 = As + (size_t)(w + 4) * 512;
  u16* Bs0 = Bs + (size_t)w * 512;
  u16* Bs1 = Bs + (size_t)(w + 4) * 512;

  const int nk = Kslice >> 5;
  for (int kt = 0; kt < nk; ++kt) {
    __syncthreads();
    GLDS16(a0, As0); GLDS16(a1, As1); GLDS16(b0, Bs0); GLDS16(b1, Bs1);
    a0 += 32; a1 += 32; b0 += 32; b1 += 32;
    __syncthreads();
    short8 af[4], bf[4];
    #pragma unroll
    for (int mi = 0; mi < 4; ++mi) {
      int row = wr * 64 + mi * 16 + lr;
      af[mi] = *(const short8*)&As[row * 32 + swz4(row, lkc) * 8];
    }
    #pragma unroll
    for (int ni = 0; ni < 4; ++ni) {
      int row = wc * 64 + ni * 16 + lr;
      bf[ni] = *(const short8*)&Bs[row * 32 + swz4(row, lkc) * 8];
    }
    #pragma unroll
    for (int mi = 0; mi < 4; ++mi)
      #pragma unroll
      for (int ni = 0; ni < 4; ++ni)
        acc[mi][ni] = __builtin_amdgcn_mfma_f32_16x16x32_bf16(af[mi], bf[ni], acc[mi][ni], 0, 0, 0);
  }

  u16* Cz = Cp + (size_t)z * M * N;
  const int row0 = bm * 128 + wr * 64, col0 = bn * 128 + wc * 64;
  const int rsub = (lane >> 4) * 4;
  #pragma unroll
  for (int mi = 0; mi < 4; ++mi)
    #pragma unroll
    for (int ni = 0; ni < 4; ++ni)
      #pragma unroll
      for (int r = 0; r < 4; ++r)
        Cz[(size_t)(row0 + mi * 16 + rsub + r) * N + (col0 + ni * 16 + lr)] = f2bf(acc[mi][ni][r]);
}

// ---------------- reduce 8 bf16 partials (4096x128) -> bf16 ----------------
__global__ __launch_bounds__(256) void reduce_kv(const u16* __restrict__ part, u16* __restrict__ out)
{
  const size_t base = ((size_t)blockIdx.x * 256 + threadIdx.x) * 8;
  float s[8] = { 0.f, 0.f, 0.f, 0.f, 0.f, 0.f, 0.f, 0.f };
  #pragma unroll
  for (int zz = 0; zz < 8; ++zz) {
    const short8 v = *(const short8*)&part[(size_t)zz * 524288 + base];
    #pragma unroll
    for (int i = 0; i < 8; ++i) s[i] += bf2f((u16)v[i]);
  }
  union { u16 o[8]; uint4 v; } pk;
  #pragma unroll
  for (int i = 0; i < 8; ++i) pk.o[i] = f2bf(s[i]);
  *(uint4*)&out[base] = pk.v;
}

// ---------------- out = sum of 4 bf16 partials (4096x1024) -> f32 ----------------
__global__ __launch_bounds__(256) void reduce_out(const u16* __restrict__ part, float* __restrict__ out)
{
  const size_t base = ((size_t)blockIdx.x * 256 + threadIdx.x) * 8;
  float s[8] = { 0.f, 0.f, 0.f, 0.f, 0.f, 0.f, 0.f, 0.f };
  #pragma unroll
  for (int zz = 0; zz < 4; ++zz) {
    const short8 v = *(const short8*)&part[(size_t)zz * 4194304 + base];
    #pragma unroll
    for (int i = 0; i < 8; ++i) s[i] += bf2f((u16)v[i]);
  }
  f32x4 lo = { s[0], s[1], s[2], s[3] };
  f32x4 hi = { s[4], s[5], s[6], s[7] };
  *(f32x4*)&out[base] = lo;
  *(f32x4*)&out[base + 4] = hi;
}

// ---------------- flash cross-attention (multi-query: 1 KV head) ----------------
// 64 q-rows per wave (2 q32 tiles), 4 heads/block, grid (N/64, H/4, B) = 256 blocks.
// T13 defer-max: skip max-update + O-rescale when tile max <= m + 8 (wave-uniform).
__global__ __launch_bounds__(256) void attn_kernel(
    const u16* __restrict__ q, const u16* __restrict__ kv, u16* __restrict__ o)
{
  __shared__ u16 Ks[128 * 64];
  __shared__ u16 Vt[64 * 128];
  __shared__ u16 Ps[4][32 * 128];
  const int b = blockIdx.z, hb = blockIdx.y, qb = blockIdx.x;
  const int t = threadIdx.x, w = t >> 6, lane = t & 63;
  const int q32 = lane & 31, hl = lane >> 5;
  const int hd = hb * 4 + w;

  const size_t qbase = (size_t)b * 2048 + qb * 64;
  short8 qa[2][4];
  #pragma unroll
  for (int t32 = 0; t32 < 2; ++t32)
    #pragma unroll
    for (int dq = 0; dq < 4; ++dq)
      qa[t32][dq] = *(const short8*)&q[(qbase + t32 * 32 + q32) * 1024 + hd * 64 + dq * 16 + hl * 8];

  f32x16 oacc[2][2];
  #pragma unroll
  for (int i = 0; i < 2; ++i)
    #pragma unroll
    for (int j = 0; j < 2; ++j)
      #pragma unroll
      for (int r = 0; r < 16; ++r) oacc[i][j][r] = 0.f;
  float m_[2] = { -1e30f, -1e30f }, l_[2] = { 0.f, 0.f };

  const size_t kvb = (size_t)b * 2048 * 128;
  const int vd0 = (t & 7) * 8;
  const int vodd = (t >> 3) & 1;
  u16* Pw = &Ps[w][0];

  for (int jt = 0; jt < 16; ++jt) {
    __syncthreads();
    #pragma unroll
    for (int n = 0; n < 4; ++n) {
      const int cc = n * 256 + w * 64;
      const int ccl = cc + lane;
      const int row = ccl >> 3, lc = (ccl & 7) ^ (row & 7);
      GLDS16(&kv[kvb + (size_t)(jt * 128 + row) * 128 + lc * 8], Ks + (size_t)cc * 8);
    }
    #pragma unroll
    for (int c = 0; c < 4; ++c) {
      const int seg = c * 256 + t;
      const int vj = seg >> 3;
      const int jp = vj >> 1;
      const uint4 vv = *(const uint4*)&kv[kvb + (size_t)(jt * 128 + vj) * 128 + 64 + vd0];
      uint4 pvv;
      pvv.x = __shfl_xor((int)vv.x, 8);
      pvv.y = __shfl_xor((int)vv.y, 8);
      pvv.z = __shfl_xor((int)vv.z, 8);
      pvv.w = __shfl_xor((int)vv.w, 8);
      const unsigned ow[4] = { vv.x, vv.y, vv.z, vv.w };
      const unsigned pw[4] = { pvv.x, pvv.y, pvv.z, pvv.w };
      if (!vodd) {
        #pragma unroll
        for (int u = 0; u < 4; ++u) {
          const int d = vd0 + u;
          const unsigned own = (u & 1) ? (ow[u >> 1] >> 16) : (ow[u >> 1] & 0xffffu);
          const unsigned par = (u & 1) ? (pw[u >> 1] >> 16) : (pw[u >> 1] & 0xffffu);
          const int byteoff = d * 256 + ((4 * jp) ^ (((d & 7) ^ ((d >> 3) & 7)) << 4));
          *(unsigned*)((char*)Vt + byteoff) = own | (par << 16);
        }
      } else {
        #pragma unroll
        for (int u = 0; u < 4; ++u) {
          const int ue = u + 4;
          const int d = vd0 + ue;
          const unsigned own = (ue & 1) ? (ow[ue >> 1] >> 16) : (ow[ue >> 1] & 0xffffu);
          const unsigned par = (ue & 1) ? (pw[ue >> 1] >> 16) : (pw[ue >> 1] & 0xffffu);
          const int byteoff = d * 256 + ((4 * jp) ^ (((d & 7) ^ ((d >> 3) & 7)) << 4));
          *(unsigned*)((char*)Vt + byteoff) = par | (own << 16);
        }
      }
    }
    __syncthreads();

    #pragma unroll
    for (int t32 = 0; t32 < 2; ++t32) {
      f32x16 s[4];
      #pragma unroll
      for (int j32 = 0; j32 < 4; ++j32)
        #pragma unroll
        for (int r = 0; r < 16; ++r) s[j32][r] = 0.f;
      #pragma unroll
      for (int j32 = 0; j32 < 4; ++j32) {
        const int row = j32 * 32 + q32;
        #pragma unroll
        for (int dq = 0; dq < 4; ++dq) {
          const int slot = (dq * 2 + hl) ^ (row & 7);
          const short8 kf = *(const short8*)&Ks[row * 64 + slot * 8];
          s[j32] = __builtin_amdgcn_mfma_f32_32x32x16_bf16(kf, qa[t32][dq], s[j32], 0, 0, 0);
        }
      }
      float mt = -1e30f;
      #pragma unroll
      for (int j32 = 0; j32 < 4; ++j32)
        #pragma unroll
        for (int r = 0; r < 16; ++r) mt = fmaxf(mt, s[j32][r]);
      mt = fmaxf(mt, __shfl_xor(mt, 32));
      const bool noresc = (bool)__all(mt <= m_[t32] + 8.0f);
      float nm = m_[t32];
      if (!noresc) {
        nm = fmaxf(m_[t32], mt);
        const float alpha = __expf(m_[t32] - nm);
        m_[t32] = nm;
        l_[t32] *= alpha;
        #pragma unroll
        for (int d32 = 0; d32 < 2; ++d32)
          #pragma unroll
          for (int r = 0; r < 16; ++r) oacc[t32][d32][r] *= alpha;
      }
      float lsum = 0.f;
      #pragma unroll
      for (int j32 = 0; j32 < 4; ++j32) {
        float p[16];
        #pragma unroll
        for (int r = 0; r < 16; ++r) { p[r] = __expf(s[j32][r] - nm); lsum += p[r]; }
        #pragma unroll
        for (int g = 0; g < 4; ++g) {
          const unsigned lo = cvtpk(p[4 * g + 0], p[4 * g + 1]);
          const unsigned hi = cvtpk(p[4 * g + 2], p[4 * g + 3]);
          const int j2 = j32 * 64 + 16 * g + 8 * hl;
          const int byteoff = q32 * 256 + (j2 ^ ((q32 & 7) << 4));
          uint2 wv; wv.x = lo; wv.y = hi;
          *(uint2*)((char*)Pw + byteoff) = wv;
        }
      }
      lsum += __shfl_xor(lsum, 32);
      l_[t32] += lsum;
      short8 pf[8];
      #pragma unroll
      for (int kk = 0; kk < 8; ++kk) {
        const int byteoff = q32 * 256 + ((kk * 32 + hl * 16) ^ ((q32 & 7) << 4));
        pf[kk] = *(const short8*)((const char*)Pw + byteoff);
      }
      #pragma unroll
      for (int d32 = 0; d32 < 2; ++d32) {
        const int dr = d32 * 32 + q32;
        const int vswz = ((dr & 7) ^ ((dr >> 3) & 7)) << 4;
        #pragma unroll
        for (int kk = 0; kk < 8; ++kk) {
          const int byteoff = dr * 256 + ((kk * 32 + hl * 16) ^ vswz);
          const short8 vf = *(const short8*)((const char*)Vt + byteoff);
          oacc[t32][d32] = __builtin_amdgcn_mfma_f32_32x32x16_bf16(vf, pf[kk], oacc[t32][d32], 0, 0, 0);
        }
      }
    }
  }

  float* Ot = (float*)Pw;
  #pragma unroll
  for (int t32 = 0; t32 < 2; ++t32) {
    const float inv = 1.0f / l_[t32];
    #pragma unroll
    for (int d32 = 0; d32 < 2; ++d32) {
      #pragma unroll
      for (int r = 0; r < 16; ++r) {
        const int d = (r & 3) + 8 * (r >> 2) + 4 * hl;
        const int byteoff = q32 * 128 + ((4 * d) ^ ((q32 & 7) << 4));
        *(float*)((char*)Ot + byteoff) = oacc[t32][d32][r] * inv;
      }
      const int qr = lane >> 1, dc = (lane & 1) * 16;
      union { u16 s[16]; uint4 v[2]; } ob;
      #pragma unroll
      for (int cch = 0; cch < 4; ++cch) {
        const int byteoff = qr * 128 + ((4 * (dc + 4 * cch)) ^ ((qr & 7) << 4));
        const f32x4 vv = *(const f32x4*)((const char*)Ot + byteoff);
        ob.s[cch * 4 + 0] = f2bf(vv[0]);
        ob.s[cch * 4 + 1] = f2bf(vv[1]);
        ob.s[cch * 4 + 2] = f2bf(vv[2]);
        ob.s[cch * 4 + 3] = f2bf(vv[3]);
      }
      u16* orow = &o[(qbase + t32 * 32 + qr) * 5120 + hd * 64 + d32 * 32 + dc];
      *(uint4*)orow = ob.v[0];
      *(uint4*)(orow + 8) = ob.v[1];
    }
  }
}

extern "C" void kernel_launch(void* const* d_in, const int* in_sizes, int n_in,
                              void* d_out, int out_size, void* d_ws, size_t ws_size,
                              hipStream_t stream)
{
  const float* x    = (const float*)d_in[0];
  const float* ctx  = (const float*)d_in[1];
  const float* ng   = (const float*)d_in[2];
  const float* nb   = (const float*)d_in[3];
  const float* cg   = (const float*)d_in[4];
  const float* cb   = (const float*)d_in[5];
  const float* Wq   = (const float*)d_in[6];
  const float* Wkv  = (const float*)d_in[7];
  const float* Wo   = (const float*)d_in[8];
  const float* Wff1 = (const float*)d_in[9];
  const float* Wff2 = (const float*)d_in[10];

  u16* p = (u16*)d_ws;
  u16* W1T   = p; p += (size_t)9216 * 1024;
  u16* WkvT  = p; p += (size_t)128 * 1024;
  u16* WcT   = p; p += (size_t)1024 * 5120;
  u16* kvbuf = p; p += (size_t)4096 * 128;
  u16* aoh   = p; p += (size_t)4096 * 5120;
  u16* xn    = p; p += (size_t)4096 * 1024;
  u16* cn    = p; p += (size_t)4096 * 1024;
  u16* qbuf  = p; p += (size_t)4096 * 1024;
  u16* kvpart = W1T;   // 8 MB bf16 over W1T (dead after qff GEMM)
  u16* ffpart = xn;    // 32 MB bf16 over xn|cn|qbuf + tail (dead by final GEMM)
  (void)in_sizes; (void)n_in; (void)out_size; (void)ws_size;

  ln_kernel<<<8192, 256, 0, stream>>>(x, ctx, ng, nb, cg, cb, xn, cn);

  transpose_k<<<dim3(16, 16),  256, 0, stream>>>(Wq,   W1T,        1024, 1024, 1024, 0.125f);
  transpose_ff1<<<dim3(128, 16), 256, 0, stream>>>(Wff1, W1T);
  transpose_k<<<dim3(2, 16),   256, 0, stream>>>(Wkv,  WkvT,       1024, 128,  1024, 1.0f);
  transpose_k<<<dim3(16, 16),  256, 0, stream>>>(Wo,   WcT,        1024, 1024, 5120, 1.0f);
  transpose_k<<<dim3(16, 64),  256, 0, stream>>>(Wff2, WcT + 1024, 4096, 1024, 5120, 1.0f);

  // fused: qbuf = xn@Wq*scale ; aoh[:,1024:] = silu(xn@Wff1); BK=32 variant (measured best)
  gemm32<2, 0><<<dim3(576), 512, 0, stream>>>(xn, W1T, qbuf, aoh, 4096, 9216, 1024, 1024);
  // kv = cn @ Wkv, split-K 8 (bf16 partials over dead W1T), reduce to bf16
  gemm_bt_sk<<<dim3(1, 32, 8), 256, 0, stream>>>(cn, WkvT, kvpart, 4096, 128, 128, 1024);
  reduce_kv<<<256, 256, 0, stream>>>(kvpart, kvbuf);
  // attention -> aoh[:,0:1024]
  attn_kernel<<<dim3(32, 4, 2), 256, 0, stream>>>(qbuf, kvbuf, aoh);
  // out = aoh @ [Wo ; Wff2], split-K 4, bf16 partials; BK=64 variant (measured best)
  gemm64<3, 1><<<dim3(64, 4), 512, 0, stream>>>(aoh, WcT, ffpart, nullptr, 4096, 1024, 5120, 1280);
  reduce_out<<<2048, 256, 0, stream>>>(ffpart, (float*)d_out);
}

// Round 14
// 287.440 us; speedup vs baseline: 4.7558x; 1.0081x over previous
//
#include <hip/hip_runtime.h>
#include <stdint.h>

typedef unsigned short u16;
typedef __attribute__((ext_vector_type(8))) short short8;
typedef __attribute__((ext_vector_type(4))) float f32x4;
typedef __attribute__((ext_vector_type(16))) float f32x16;

#define GPTR(p) ((const __attribute__((address_space(1))) void*)(p))
#define SPTR(p) ((__attribute__((address_space(3))) void*)(p))
#define GLDS16(g, l) __builtin_amdgcn_global_load_lds(GPTR(g), SPTR(l), 16, 0, 0)

static __device__ __forceinline__ float bf2f(u16 u) {
  union { unsigned int i; float f; } c; c.i = ((unsigned int)u) << 16; return c.f;
}
static __device__ __forceinline__ u16 f2bf(float f) {
  union { float f; unsigned int u; } c; c.f = f;
  unsigned int r = 0x7fffu + ((c.u >> 16) & 1u);
  return (u16)((c.u + r) >> 16);
}
static __device__ __forceinline__ unsigned cvtpk(float a, float b) {
  unsigned r;
  asm volatile("v_cvt_pk_bf16_f32 %0, %1, %2" : "=v"(r) : "v"(a), "v"(b));
  return r;
}
static __device__ __forceinline__ int swz4(int row, int c) { return c ^ ((row >> 1) & 3); }

// ---------------- LayerNorm: f32 (rows of 1024) -> bf16 ----------------
__global__ __launch_bounds__(256) void ln_kernel(
    const float* __restrict__ x, const float* __restrict__ ctx,
    const float* __restrict__ g, const float* __restrict__ b,
    const float* __restrict__ cg, const float* __restrict__ cb,
    u16* __restrict__ xn, u16* __restrict__ cn)
{
  const int row = blockIdx.x;
  const float* src; const float* gg; const float* bb; u16* dst;
  if (row < 4096) { src = x + (size_t)row * 1024; gg = g;  bb = b;  dst = xn + (size_t)row * 1024; }
  else            { src = ctx + (size_t)(row - 4096) * 1024; gg = cg; bb = cb; dst = cn + (size_t)(row - 4096) * 1024; }
  const int t = threadIdx.x;
  float4 v = *(const float4*)&src[t * 4];
  float s  = v.x + v.y + v.z + v.w;
  float s2 = v.x * v.x + v.y * v.y + v.z * v.z + v.w * v.w;
  #pragma unroll
  for (int off = 1; off < 64; off <<= 1) { s += __shfl_xor(s, off); s2 += __shfl_xor(s2, off); }
  __shared__ float ls[4], ls2[4];
  const int w = t >> 6;
  if ((t & 63) == 0) { ls[w] = s; ls2[w] = s2; }
  __syncthreads();
  s  = ls[0] + ls[1] + ls[2] + ls[3];
  s2 = ls2[0] + ls2[1] + ls2[2] + ls2[3];
  const float mu   = s * (1.0f / 1024.0f);
  const float var  = s2 * (1.0f / 1024.0f) - mu * mu;
  const float rstd = rsqrtf(var + 1e-5f);
  float xv[4] = { v.x, v.y, v.z, v.w };
  u16 o[4];
  #pragma unroll
  for (int i = 0; i < 4; ++i)
    o[i] = f2bf((xv[i] - mu) * rstd * gg[t * 4 + i] + bb[t * 4 + i]);
  uint2 pv;
  pv.x = (unsigned)o[0] | ((unsigned)o[1] << 16);
  pv.y = (unsigned)o[2] | ((unsigned)o[3] << 16);
  *(uint2*)&dst[t * 4] = pv;
}

// ---------------- transpose+convert: f32 (R,C) -> bf16 (C,R) with out leading dim ----------------
__global__ __launch_bounds__(256) void transpose_k(
    const float* __restrict__ in, u16* __restrict__ out, int R, int C, int ldo, float scale)
{
  __shared__ float tile[64][65];
  const int c0 = blockIdx.x * 64, r0 = blockIdx.y * 64;
  const int t = threadIdx.x;
  const int tr = t >> 4, tc = (t & 15) * 4;
  #pragma unroll
  for (int i = 0; i < 4; ++i) {
    int r = tr + i * 16;
    float4 v = *(const float4*)&in[(size_t)(r0 + r) * C + c0 + tc];
    tile[r][tc + 0] = v.x; tile[r][tc + 1] = v.y; tile[r][tc + 2] = v.z; tile[r][tc + 3] = v.w;
  }
  __syncthreads();
  #pragma unroll
  for (int i = 0; i < 2; ++i) {
    int c  = (t >> 3) + i * 32;
    int rb = (t & 7) * 8;
    union { u16 s[8]; uint4 v; } pk;
    #pragma unroll
    for (int u = 0; u < 8; ++u) pk.s[u] = f2bf(tile[rb + u][c] * scale);
    *(uint4*)&out[(size_t)(c0 + c) * ldo + r0 + rb] = pk.v;
  }
}

// ---------------- Wff1 transpose with (a,gate) fragment interleave ----------------
__global__ __launch_bounds__(256) void transpose_ff1(
    const float* __restrict__ in, u16* __restrict__ out)
{
  __shared__ float tile[64][65];
  const int c0 = blockIdx.x * 64, r0 = blockIdx.y * 64;
  const int t = threadIdx.x;
  const int tr = t >> 4, tc = (t & 15) * 4;
  #pragma unroll
  for (int i = 0; i < 4; ++i) {
    int r = tr + i * 16;
    float4 v = *(const float4*)&in[(size_t)(r0 + r) * 8192 + c0 + tc];
    tile[r][tc + 0] = v.x; tile[r][tc + 1] = v.y; tile[r][tc + 2] = v.z; tile[r][tc + 3] = v.w;
  }
  __syncthreads();
  #pragma unroll
  for (int i = 0; i < 2; ++i) {
    int c  = (t >> 3) + i * 32;
    int rb = (t & 7) * 8;
    const int gc = c0 + c;
    int j, add16;
    if (gc < 4096) { j = gc; add16 = 0; } else { j = gc - 4096; add16 = 16; }
    const int row = 1024 + ((j >> 7) << 8) + (((j >> 5) & 3) << 6) + (((j >> 4) & 1) << 5) + add16 + (j & 15);
    union { u16 s[8]; uint4 v; } pk;
    #pragma unroll
    for (int u = 0; u < 8; ++u) pk.s[u] = f2bf(tile[rb + u][c]);
    *(uint4*)&out[(size_t)row * 1024 + r0 + rb] = pk.v;
  }
}

// =============== BK=32 4-phase 256x256 GEMM (qff) ===============
#define MM32(MQ, M, NN) acc[MQ][M][NN] = __builtin_amdgcn_mfma_f32_16x16x32_bf16(af##M, bf##NN, acc[MQ][M][NN], 0, 0, 0)
#define MFMA16_32(MQ) \
  MM32(MQ,0,0); MM32(MQ,0,1); MM32(MQ,0,2); MM32(MQ,0,3); \
  MM32(MQ,1,0); MM32(MQ,1,1); MM32(MQ,1,2); MM32(MQ,1,3); \
  MM32(MQ,2,0); MM32(MQ,2,1); MM32(MQ,2,2); MM32(MQ,2,3); \
  MM32(MQ,3,0); MM32(MQ,3,1); MM32(MQ,3,2); MM32(MQ,3,3)

#define SA32(SBUF, H, KT) GLDS16(gA32[H] + ((size_t)(KT) << 5), SBUF + (size_t)((H) * 64 + w16o) * 32)
#define SB32(SBUF, H, KT) GLDS16(gB32[H] + ((size_t)(KT) << 5), SBUF + (size_t)((H) * 128 + w16o2) * 32)

#define DSB32(PB_) do { \
  bf0 = *(const short8*)(PB_ + 0    + cks); bf1 = *(const short8*)(PB_ + 512  + cks); \
  bf2 = *(const short8*)(PB_ + 1024 + cks); bf3 = *(const short8*)(PB_ + 1536 + cks); \
} while (0)

#define PC32(PA_, MQ, STAGE_STMT, GATE_STMT) do { \
  af0 = *(const short8*)(PA_ + (MQ) * 2048 + 0    + cks); \
  af1 = *(const short8*)(PA_ + (MQ) * 2048 + 512  + cks); \
  af2 = *(const short8*)(PA_ + (MQ) * 2048 + 1024 + cks); \
  af3 = *(const short8*)(PA_ + (MQ) * 2048 + 1536 + cks); \
  STAGE_STMT; \
  __builtin_amdgcn_s_barrier(); \
  asm volatile("s_waitcnt lgkmcnt(0)" ::: "memory"); \
  __builtin_amdgcn_s_setprio(1); \
  MFMA16_32(MQ); \
  __builtin_amdgcn_s_setprio(0); \
  GATE_STMT; \
  __builtin_amdgcn_s_barrier(); \
} while (0)

#define GATE3 asm volatile("s_waitcnt vmcnt(3)" ::: "memory")
#define GATE0 asm volatile("s_waitcnt vmcnt(0)" ::: "memory")

template<int MODE, int ORDER>
__global__ __launch_bounds__(512, 2) void gemm32(
    const u16* __restrict__ A, const u16* __restrict__ BT, void* __restrict__ C,
    void* __restrict__ C2, int M, int N, int Ktot, int Kslice)
{
  __shared__ u16 sh[2][2][8192]; // 64 KB
  const int nbn = N >> 8, nbm = M >> 8;
  const int nwg = gridDim.x;
  const int bid = blockIdx.x;
  const int o = (bid & 7) * (nwg >> 3) + (bid >> 3);
  int bm, bn;
  if constexpr (ORDER == 0) { bm = o % nbm; bn = o / nbm; }
  else                      { bn = o % nbn; bm = o / nbn; }
  const int kbase = blockIdx.y * Kslice;
  const int NI = Kslice >> 6;

  const int t = threadIdx.x, w = t >> 6, lane = t & 63;
  const int wr = w >> 2, wc = w & 3;
  const int lr = lane & 15, lg = lane >> 4;
  const int l4 = lane >> 2, sl = lane & 3;
  const int w16o  = w * 16 + ((w >= 4) ? 64 : 0);
  const int w16o2 = w * 16;

  const u16* gA32[2]; const u16* gB32[2];
  #pragma unroll
  for (int h = 0; h < 2; ++h) {
    const int rowA = h * 64 + w16o + l4;
    gA32[h] = A + (size_t)(bm * 256 + rowA) * Ktot + kbase + (size_t)((sl ^ ((rowA >> 1) & 3)) * 8);
    const int rowB = h * 128 + w16o2 + l4;
    gB32[h] = BT + (size_t)(bn * 256 + rowB) * Ktot + kbase + (size_t)((sl ^ ((rowB >> 1) & 3)) * 8);
  }
  u16* sA0 = &sh[0][0][0]; u16* sA1 = &sh[1][0][0];
  u16* sB0 = &sh[0][1][0]; u16* sB1 = &sh[1][1][0];
  const int cks = (lg ^ ((lr >> 1) & 3)) * 8;
  const u16* pA_b0 = sA0 + (wr * 128 + lr) * 32;
  const u16* pA_b1 = sA1 + (wr * 128 + lr) * 32;
  const u16* pB_b0 = sB0 + (wc * 64 + lr) * 32;
  const u16* pB_b1 = sB1 + (wc * 64 + lr) * 32;

  f32x4 acc[2][4][4];
  const f32x4 z4 = { 0.f, 0.f, 0.f, 0.f };
  #pragma unroll
  for (int a = 0; a < 2; ++a)
    #pragma unroll
    for (int b = 0; b < 4; ++b)
      #pragma unroll
      for (int c = 0; c < 4; ++c) acc[a][b][c] = z4;
  short8 af0, af1, af2, af3;
  short8 bf0, bf1, bf2, bf3;

  SA32(sA0, 0, 0); SA32(sA0, 1, 0); SB32(sB0, 0, 0); SB32(sB0, 1, 0);
  SB32(sB1, 0, 1); SB32(sB1, 1, 1); SA32(sA1, 0, 1);
  GATE3;
  __builtin_amdgcn_s_barrier();

  for (int i = 0; i < NI; ++i) {
    const bool st = (i < NI - 1);
    const int X = 2 * i + 2, Y = 2 * i + 3;
    DSB32(pB_b0);
    PC32(pA_b0, 0, SA32(sA1, 1, 2 * i + 1), );
    PC32(pA_b0, 1,
         if (st) { SB32(sB0, 0, X); SB32(sB0, 1, X); SA32(sA0, 0, X); },
         if (st) { GATE3; } else { GATE0; });
    DSB32(pB_b1);
    PC32(pA_b1, 0, if (st) { SA32(sA0, 1, X); }, );
    PC32(pA_b1, 1,
         if (st) { SB32(sB1, 0, Y); SB32(sB1, 1, Y); SA32(sA1, 0, Y); },
         if (st) { GATE3; });
  }

  if (bn < 4) {
    u16* Co = (u16*)C; // qbuf, stride 1024
    #pragma unroll
    for (int mq = 0; mq < 2; ++mq)
      #pragma unroll
      for (int m = 0; m < 4; ++m)
        #pragma unroll
        for (int n = 0; n < 4; ++n)
          #pragma unroll
          for (int rr = 0; rr < 4; ++rr) {
            const int row = bm * 256 + wr * 128 + mq * 64 + m * 16 + lg * 4 + rr;
            const int col = bn * 256 + wc * 64 + n * 16 + lr;
            Co[(size_t)row * 1024 + col] = f2bf(acc[mq][m][n][rr]);
          }
  } else {
    u16* Ho = (u16*)C2; // aoh, stride 5120, h starts at col 1024
    const int colb = 1024 + (bn - 4) * 128 + wc * 32 + lr;
    #pragma unroll
    for (int mq = 0; mq < 2; ++mq)
      #pragma unroll
      for (int m = 0; m < 4; ++m)
        #pragma unroll
        for (int rr = 0; rr < 4; ++rr) {
          const int row = bm * 256 + wr * 128 + mq * 64 + m * 16 + lg * 4 + rr;
          #pragma unroll
          for (int n2 = 0; n2 < 2; ++n2) {
            const float a = acc[mq][m][2 * n2][rr];
            const float gt = acc[mq][m][2 * n2 + 1][rr];
            const float h = a * gt / (1.0f + __expf(-gt));
            Ho[(size_t)row * 5120 + colb + n2 * 16] = f2bf(h);
          }
        }
  }
}

// =============== BK=64 8-phase 256x256 GEMM (final GEMM) ===============
#define MM1(MQ, M, NN, BF) acc[MQ][M][NN] = __builtin_amdgcn_mfma_f32_16x16x32_bf16(af##M, BF, acc[MQ][M][NN], 0, 0, 0)
#define MFMA16(MQ, KS) \
  MM1(MQ,0,0,bf##KS##0); MM1(MQ,0,1,bf##KS##1); MM1(MQ,0,2,bf##KS##2); MM1(MQ,0,3,bf##KS##3); \
  MM1(MQ,1,0,bf##KS##0); MM1(MQ,1,1,bf##KS##1); MM1(MQ,1,2,bf##KS##2); MM1(MQ,1,3,bf##KS##3); \
  MM1(MQ,2,0,bf##KS##0); MM1(MQ,2,1,bf##KS##1); MM1(MQ,2,2,bf##KS##2); MM1(MQ,2,3,bf##KS##3); \
  MM1(MQ,3,0,bf##KS##0); MM1(MQ,3,1,bf##KS##1); MM1(MQ,3,2,bf##KS##2); MM1(MQ,3,3,bf##KS##3)

#define SG_A(SBUF, H, KT) do { \
    GLDS16(gA[H][0] + ((size_t)(KT) << 6), SBUF + ((H) * 64 + w16o) * 64); \
    GLDS16(gA[H][1] + ((size_t)(KT) << 6), SBUF + ((H) * 64 + w16o + 8) * 64); \
  } while (0)
#define SG_B(SBUF, H, KT) do { \
    GLDS16(gB[H][0] + ((size_t)(KT) << 6), SBUF + ((H) * 128 + w16o2) * 64); \
    GLDS16(gB[H][1] + ((size_t)(KT) << 6), SBUF + ((H) * 128 + w16o2 + 8) * 64); \
  } while (0)

#define DS_B(PB_) do { \
  bf00 = *(const short8*)(PB_ + 0    + cks0); bf01 = *(const short8*)(PB_ + 1024 + cks0); \
  bf02 = *(const short8*)(PB_ + 2048 + cks0); bf03 = *(const short8*)(PB_ + 3072 + cks0); \
  bf10 = *(const short8*)(PB_ + 0    + cks1); bf11 = *(const short8*)(PB_ + 1024 + cks1); \
  bf12 = *(const short8*)(PB_ + 2048 + cks1); bf13 = *(const short8*)(PB_ + 3072 + cks1); \
} while (0)

#define P_CORE(PA_, MQ, KS, STAGE_STMT, PREB_STMT, GATE_STMT) do { \
  af0 = *(const short8*)(PA_ + (MQ) * 4096 + 0    + cks##KS); \
  af1 = *(const short8*)(PA_ + (MQ) * 4096 + 1024 + cks##KS); \
  af2 = *(const short8*)(PA_ + (MQ) * 4096 + 2048 + cks##KS); \
  af3 = *(const short8*)(PA_ + (MQ) * 4096 + 3072 + cks##KS); \
  STAGE_STMT; \
  PREB_STMT; \
  __builtin_amdgcn_s_barrier(); \
  asm volatile("s_waitcnt lgkmcnt(0)" ::: "memory"); \
  __builtin_amdgcn_s_setprio(1); \
  MFMA16(MQ, KS); \
  __builtin_amdgcn_s_setprio(0); \
  GATE_STMT; \
  __builtin_amdgcn_s_barrier(); \
} while (0)

#define GATE6 asm volatile("s_waitcnt vmcnt(6)" ::: "memory")
#define HINT8 asm volatile("s_waitcnt lgkmcnt(8)" ::: "memory")

template<int MODE, int ORDER>
__global__ __launch_bounds__(512, 2) void gemm64(
    const u16* __restrict__ A, const u16* __restrict__ BT, void* __restrict__ C,
    void* __restrict__ C2, int M, int N, int Ktot, int Kslice)
{
  __shared__ u16 sh[2][2][16384]; // 128 KB
  const int nbn = N >> 8, nbm = M >> 8;
  const int nwg = gridDim.x;
  const int bid = blockIdx.x;
  const int o = (bid & 7) * (nwg >> 3) + (bid >> 3);
  int bm, bn;
  if constexpr (ORDER == 0) { bm = o % nbm; bn = o / nbm; }
  else                      { bn = o % nbn; bm = o / nbn; }
  const int kbase = blockIdx.y * Kslice;
  const int NI = Kslice >> 7;

  const int t = threadIdx.x, w = t >> 6, lane = t & 63;
  const int wr = w >> 2, wc = w & 3;
  const int lr = lane & 15, lg = lane >> 4;
  const int r8 = lane >> 3, ch = lane & 7;
  const int clog = ch ^ r8;
  const int w16o  = w * 16 + ((w >= 4) ? 64 : 0);
  const int w16o2 = w * 16;

  const u16* gA[2][2]; const u16* gB[2][2];
  #pragma unroll
  for (int h = 0; h < 2; ++h)
    #pragma unroll
    for (int qq = 0; qq < 2; ++qq) {
      gA[h][qq] = A  + (size_t)(bm * 256 + h * 64  + w16o  + qq * 8 + r8) * Ktot + kbase + clog * 8;
      gB[h][qq] = BT + (size_t)(bn * 256 + h * 128 + w16o2 + qq * 8 + r8) * Ktot + kbase + clog * 8;
    }
  u16* sA0 = &sh[0][0][0]; u16* sA1 = &sh[1][0][0];
  u16* sB0 = &sh[0][1][0]; u16* sB1 = &sh[1][1][0];
  const int cks0 = ((0 + lg) ^ (lr & 7)) * 8;
  const int cks1 = ((4 + lg) ^ (lr & 7)) * 8;
  const u16* pA_b0 = sA0 + (wr * 128 + lr) * 64;
  const u16* pA_b1 = sA1 + (wr * 128 + lr) * 64;
  const u16* pB_b0 = sB0 + (wc * 64 + lr) * 64;
  const u16* pB_b1 = sB1 + (wc * 64 + lr) * 64;

  f32x4 acc[2][4][4];
  const f32x4 z4 = { 0.f, 0.f, 0.f, 0.f };
  #pragma unroll
  for (int a = 0; a < 2; ++a)
    #pragma unroll
    for (int b = 0; b < 4; ++b)
      #pragma unroll
      for (int c = 0; c < 4; ++c) acc[a][b][c] = z4;
  short8 af0, af1, af2, af3;
  short8 bf00, bf01, bf02, bf03, bf10, bf11, bf12, bf13;

  SG_B(sB0, 0, 0); SG_B(sB0, 1, 0); SG_A(sA0, 0, 0); SG_A(sA0, 1, 0);
  SG_B(sB1, 0, 1); SG_B(sB1, 1, 1); SG_A(sA1, 0, 1);
  GATE6;
  __builtin_amdgcn_s_barrier();

  for (int i = 0; i < NI; ++i) {
    const int k2 = 2 * i;
    const bool st = (i < NI - 1);
    DS_B(pB_b0);
    P_CORE(pA_b0, 0, 0, SG_A(sA1, 1, k2 + 1), HINT8, );
    P_CORE(pA_b0, 1, 0, if (st) SG_B(sB0, 0, k2 + 2), , );
    P_CORE(pA_b0, 0, 1, if (st) SG_B(sB0, 1, k2 + 2), , );
    P_CORE(pA_b0, 1, 1, if (st) SG_A(sA0, 0, k2 + 2), ,
           if (st) { GATE6; } else { GATE0; });
    DS_B(pB_b1);
    P_CORE(pA_b1, 0, 0, if (st) SG_A(sA0, 1, k2 + 2), HINT8, );
    P_CORE(pA_b1, 1, 0, if (st) SG_B(sB1, 0, k2 + 3), , );
    P_CORE(pA_b1, 0, 1, if (st) SG_B(sB1, 1, k2 + 3), , );
    P_CORE(pA_b1, 1, 1, if (st) SG_A(sA1, 0, k2 + 3), ,
           if (st) { GATE6; });
  }

  u16* Co = (u16*)C + (size_t)blockIdx.y * M * N;
  #pragma unroll
  for (int mq = 0; mq < 2; ++mq)
    #pragma unroll
    for (int m = 0; m < 4; ++m)
      #pragma unroll
      for (int n = 0; n < 4; ++n)
        #pragma unroll
        for (int rr = 0; rr < 4; ++rr) {
          const int row = bm * 256 + wr * 128 + mq * 64 + m * 16 + lg * 4 + rr;
          const int col = bn * 256 + wc * 64 + n * 16 + lr;
          Co[(size_t)row * N + col] = f2bf(acc[mq][m][n][rr]);
        }
}

// ---------------- split-K GEMM 128x128 (kv projection), bf16 partials ----------------
__global__ __launch_bounds__(256) void gemm_bt_sk(
    const u16* __restrict__ A, const u16* __restrict__ BT, u16* __restrict__ Cp,
    int M, int N, int Kslice, int Ktot)
{
  __shared__ u16 As[128 * 32];
  __shared__ u16 Bs[128 * 32];
  const int bm = blockIdx.y, bn = blockIdx.x, z = blockIdx.z;
  const int t = threadIdx.x;
  const int w = t >> 6, lane = t & 63;
  const int wr = w >> 1, wc = w & 1;
  const int lr = lane & 15, lkc = lane >> 4;

  f32x4 acc[4][4];
  const f32x4 z4 = { 0.f, 0.f, 0.f, 0.f };
  #pragma unroll
  for (int mi = 0; mi < 4; ++mi)
    #pragma unroll
    for (int ni = 0; ni < 4; ++ni) acc[mi][ni] = z4;

  const int kbase = z * Kslice;
  const int i0 = t, i1 = t + 256;
  const int r0 = i0 >> 2, k0 = swz4(r0, i0 & 3) * 8;
  const int r1 = i1 >> 2, k1 = swz4(r1, i1 & 3) * 8;
  const u16* a0 = A + (size_t)(bm * 128 + r0) * Ktot + kbase + k0;
  const u16* a1 = A + (size_t)(bm * 128 + r1) * Ktot + kbase + k1;
  const u16* b0 = BT + (size_t)(bn * 128 + r0) * Ktot + kbase + k0;
  const u16* b1 = BT + (size_t)(bn * 128 + r1) * Ktot + kbase + k1;
  u16* As0 = As + (size_t)w * 512;
  u16* As1 = As + (size_t)(w + 4) * 512;
  u16* Bs0 = Bs + (size_t)w * 512;
  u16* Bs1 = Bs + (size_t)(w + 4) * 512;

  const int nk = Kslice >> 5;
  for (int kt = 0; kt < nk; ++kt) {
    __syncthreads();
    GLDS16(a0, As0); GLDS16(a1, As1); GLDS16(b0, Bs0); GLDS16(b1, Bs1);
    a0 += 32; a1 += 32; b0 += 32; b1 += 32;
    __syncthreads();
    short8 af[4], bf[4];
    #pragma unroll
    for (int mi = 0; mi < 4; ++mi) {
      int row = wr * 64 + mi * 16 + lr;
      af[mi] = *(const short8*)&As[row * 32 + swz4(row, lkc) * 8];
    }
    #pragma unroll
    for (int ni = 0; ni < 4; ++ni) {
      int row = wc * 64 + ni * 16 + lr;
      bf[ni] = *(const short8*)&Bs[row * 32 + swz4(row, lkc) * 8];
    }
    #pragma unroll
    for (int mi = 0; mi < 4; ++mi)
      #pragma unroll
      for (int ni = 0; ni < 4; ++ni)
        acc[mi][ni] = __builtin_amdgcn_mfma_f32_16x16x32_bf16(af[mi], bf[ni], acc[mi][ni], 0, 0, 0);
  }

  u16* Cz = Cp + (size_t)z * M * N;
  const int row0 = bm * 128 + wr * 64, col0 = bn * 128 + wc * 64;
  const int rsub = (lane >> 4) * 4;
  #pragma unroll
  for (int mi = 0; mi < 4; ++mi)
    #pragma unroll
    for (int ni = 0; ni < 4; ++ni)
      #pragma unroll
      for (int r = 0; r < 4; ++r)
        Cz[(size_t)(row0 + mi * 16 + rsub + r) * N + (col0 + ni * 16 + lr)] = f2bf(acc[mi][ni][r]);
}

// ---------------- reduce 8 bf16 partials (4096x128) -> bf16 ----------------
__global__ __launch_bounds__(256) void reduce_kv(const u16* __restrict__ part, u16* __restrict__ out)
{
  const size_t base = ((size_t)blockIdx.x * 256 + threadIdx.x) * 8;
  float s[8] = { 0.f, 0.f, 0.f, 0.f, 0.f, 0.f, 0.f, 0.f };
  #pragma unroll
  for (int zz = 0; zz < 8; ++zz) {
    const short8 v = *(const short8*)&part[(size_t)zz * 524288 + base];
    #pragma unroll
    for (int i = 0; i < 8; ++i) s[i] += bf2f((u16)v[i]);
  }
  union { u16 o[8]; uint4 v; } pk;
  #pragma unroll
  for (int i = 0; i < 8; ++i) pk.o[i] = f2bf(s[i]);
  *(uint4*)&out[base] = pk.v;
}

// ---------------- out = sum of 4 bf16 partials (4096x1024) -> f32 ----------------
__global__ __launch_bounds__(256) void reduce_out(const u16* __restrict__ part, float* __restrict__ out)
{
  const size_t base = ((size_t)blockIdx.x * 256 + threadIdx.x) * 8;
  float s[8] = { 0.f, 0.f, 0.f, 0.f, 0.f, 0.f, 0.f, 0.f };
  #pragma unroll
  for (int zz = 0; zz < 4; ++zz) {
    const short8 v = *(const short8*)&part[(size_t)zz * 4194304 + base];
    #pragma unroll
    for (int i = 0; i < 8; ++i) s[i] += bf2f((u16)v[i]);
  }
  f32x4 lo = { s[0], s[1], s[2], s[3] };
  f32x4 hi = { s[4], s[5], s[6], s[7] };
  *(f32x4*)&out[base] = lo;
  *(f32x4*)&out[base + 4] = hi;
}

// ---------------- flash cross-attention (multi-query: 1 KV head) ----------------
// 64 q-rows per wave, 4 heads/block, 256 blocks. T13 defer-max.
// T14 async-V: V-tile jt+1 global loads issued during staging(jt), complete under compute(jt).
// Second barrier = counted vmcnt(4)+lgkm(0) writer-fence + raw s_barrier (V loads ride across).
// T5 setprio around the QK/PV MFMA clusters.
__global__ __launch_bounds__(256) void attn_kernel(
    const u16* __restrict__ q, const u16* __restrict__ kv, u16* __restrict__ o)
{
  __shared__ u16 Ks[128 * 64];
  __shared__ u16 Vt[64 * 128];
  __shared__ u16 Ps[4][32 * 128];
  const int b = blockIdx.z, hb = blockIdx.y, qb = blockIdx.x;
  const int t = threadIdx.x, w = t >> 6, lane = t & 63;
  const int q32 = lane & 31, hl = lane >> 5;
  const int hd = hb * 4 + w;

  const size_t qbase = (size_t)b * 2048 + qb * 64;
  short8 qa[2][4];
  #pragma unroll
  for (int t32 = 0; t32 < 2; ++t32)
    #pragma unroll
    for (int dq = 0; dq < 4; ++dq)
      qa[t32][dq] = *(const short8*)&q[(qbase + t32 * 32 + q32) * 1024 + hd * 64 + dq * 16 + hl * 8];

  f32x16 oacc[2][2];
  #pragma unroll
  for (int i = 0; i < 2; ++i)
    #pragma unroll
    for (int j = 0; j < 2; ++j)
      #pragma unroll
      for (int r = 0; r < 16; ++r) oacc[i][j][r] = 0.f;
  float m_[2] = { -1e30f, -1e30f }, l_[2] = { 0.f, 0.f };

  const size_t kvb = (size_t)b * 2048 * 128;
  const int vd0 = (t & 7) * 8;
  const int vodd = (t >> 3) & 1;
  u16* Pw = &Ps[w][0];

  // T14 prologue: V(0) into held regs
  uint4 vhold[4];
  #pragma unroll
  for (int c = 0; c < 4; ++c) {
    const int vj = (c * 256 + t) >> 3;
    vhold[c] = *(const uint4*)&kv[kvb + (size_t)vj * 128 + 64 + vd0];
  }

  for (int jt = 0; jt < 16; ++jt) {
    __syncthreads();
    // stage K(jt) via GLDS (4 wave-loads)
    #pragma unroll
    for (int n = 0; n < 4; ++n) {
      const int cc = n * 256 + w * 64;
      const int ccl = cc + lane;
      const int row = ccl >> 3, lc = (ccl & 7) ^ (row & 7);
      GLDS16(&kv[kvb + (size_t)(jt * 128 + row) * 128 + lc * 8], Ks + (size_t)cc * 8);
    }
    // write V(jt) to Vt from held regs (shfl pair-exchange + packed b32)
    #pragma unroll
    for (int c = 0; c < 4; ++c) {
      const int seg = c * 256 + t;
      const int vj = seg >> 3;
      const int jp = vj >> 1;
      const uint4 vv = vhold[c];
      uint4 pvv;
      pvv.x = __shfl_xor((int)vv.x, 8);
      pvv.y = __shfl_xor((int)vv.y, 8);
      pvv.z = __shfl_xor((int)vv.z, 8);
      pvv.w = __shfl_xor((int)vv.w, 8);
      const unsigned ow[4] = { vv.x, vv.y, vv.z, vv.w };
      const unsigned pw[4] = { pvv.x, pvv.y, pvv.z, pvv.w };
      if (!vodd) {
        #pragma unroll
        for (int u = 0; u < 4; ++u) {
          const int d = vd0 + u;
          const unsigned own = (u & 1) ? (ow[u >> 1] >> 16) : (ow[u >> 1] & 0xffffu);
          const unsigned par = (u & 1) ? (pw[u >> 1] >> 16) : (pw[u >> 1] & 0xffffu);
          const int byteoff = d * 256 + ((4 * jp) ^ (((d & 7) ^ ((d >> 3) & 7)) << 4));
          *(unsigned*)((char*)Vt + byteoff) = own | (par << 16);
        }
      } else {
        #pragma unroll
        for (int u = 0; u < 4; ++u) {
          const int ue = u + 4;
          const int d = vd0 + ue;
          const unsigned own = (ue & 1) ? (ow[ue >> 1] >> 16) : (ow[ue >> 1] & 0xffffu);
          const unsigned par = (ue & 1) ? (pw[ue >> 1] >> 16) : (pw[ue >> 1] & 0xffffu);
          const int byteoff = d * 256 + ((4 * jp) ^ (((d & 7) ^ ((d >> 3) & 7)) << 4));
          *(unsigned*)((char*)Vt + byteoff) = par | (own << 16);
        }
      }
    }
    // pin issue order: K-GLDS (and ds writes) above, V reloads below
    __builtin_amdgcn_sched_barrier(0);
    if (jt < 15) {
      #pragma unroll
      for (int c = 0; c < 4; ++c) {
        const int vj = (c * 256 + t) >> 3;
        vhold[c] = *(const uint4*)&kv[kvb + (size_t)((jt + 1) * 128 + vj) * 128 + 64 + vd0];
      }
      asm volatile("s_waitcnt vmcnt(4) lgkmcnt(0)" ::: "memory"); // K done + Vt writes done; V(jt+1) in flight
    } else {
      asm volatile("s_waitcnt vmcnt(0) lgkmcnt(0)" ::: "memory");
    }
    __builtin_amdgcn_s_barrier();
    __builtin_amdgcn_sched_barrier(0);   // reader fence: no LDS read hoists above barrier

    #pragma unroll
    for (int t32 = 0; t32 < 2; ++t32) {
      f32x16 s[4];
      #pragma unroll
      for (int j32 = 0; j32 < 4; ++j32)
        #pragma unroll
        for (int r = 0; r < 16; ++r) s[j32][r] = 0.f;
      __builtin_amdgcn_s_setprio(1);
      #pragma unroll
      for (int j32 = 0; j32 < 4; ++j32) {
        const int row = j32 * 32 + q32;
        #pragma unroll
        for (int dq = 0; dq < 4; ++dq) {
          const int slot = (dq * 2 + hl) ^ (row & 7);
          const short8 kf = *(const short8*)&Ks[row * 64 + slot * 8];
          s[j32] = __builtin_amdgcn_mfma_f32_32x32x16_bf16(kf, qa[t32][dq], s[j32], 0, 0, 0);
        }
      }
      __builtin_amdgcn_s_setprio(0);
      float mt = -1e30f;
      #pragma unroll
      for (int j32 = 0; j32 < 4; ++j32)
        #pragma unroll
        for (int r = 0; r < 16; ++r) mt = fmaxf(mt, s[j32][r]);
      mt = fmaxf(mt, __shfl_xor(mt, 32));
      const bool noresc = (bool)__all(mt <= m_[t32] + 8.0f);
      float nm = m_[t32];
      if (!noresc) {
        nm = fmaxf(m_[t32], mt);
        const float alpha = __expf(m_[t32] - nm);
        m_[t32] = nm;
        l_[t32] *= alpha;
        #pragma unroll
        for (int d32 = 0; d32 < 2; ++d32)
          #pragma unroll
          for (int r = 0; r < 16; ++r) oacc[t32][d32][r] *= alpha;
      }
      float lsum = 0.f;
      #pragma unroll
      for (int j32 = 0; j32 < 4; ++j32) {
        float p[16];
        #pragma unroll
        for (int r = 0; r < 16; ++r) { p[r] = __expf(s[j32][r] - nm); lsum += p[r]; }
        #pragma unroll
        for (int g = 0; g < 4; ++g) {
          const unsigned lo = cvtpk(p[4 * g + 0], p[4 * g + 1]);
          const unsigned hi = cvtpk(p[4 * g + 2], p[4 * g + 3]);
          const int j2 = j32 * 64 + 16 * g + 8 * hl;
          const int byteoff = q32 * 256 + (j2 ^ ((q32 & 7) << 4));
          uint2 wv; wv.x = lo; wv.y = hi;
          *(uint2*)((char*)Pw + byteoff) = wv;
        }
      }
      lsum += __shfl_xor(lsum, 32);
      l_[t32] += lsum;
      short8 pf[8];
      #pragma unroll
      for (int kk = 0; kk < 8; ++kk) {
        const int byteoff = q32 * 256 + ((kk * 32 + hl * 16) ^ ((q32 & 7) << 4));
        pf[kk] = *(const short8*)((const char*)Pw + byteoff);
      }
      __builtin_amdgcn_s_setprio(1);
      #pragma unroll
      for (int d32 = 0; d32 < 2; ++d32) {
        const int dr = d32 * 32 + q32;
        const int vswz = ((dr & 7) ^ ((dr >> 3) & 7)) << 4;
        #pragma unroll
        for (int kk = 0; kk < 8; ++kk) {
          const int byteoff = dr * 256 + ((kk * 32 + hl * 16) ^ vswz);
          const short8 vf = *(const short8*)((const char*)Vt + byteoff);
          oacc[t32][d32] = __builtin_amdgcn_mfma_f32_32x32x16_bf16(vf, pf[kk], oacc[t32][d32], 0, 0, 0);
        }
      }
      __builtin_amdgcn_s_setprio(0);
    }
  }

  float* Ot = (float*)Pw;
  #pragma unroll
  for (int t32 = 0; t32 < 2; ++t32) {
    const float inv = 1.0f / l_[t32];
    #pragma unroll
    for (int d32 = 0; d32 < 2; ++d32) {
      #pragma unroll
      for (int r = 0; r < 16; ++r) {
        const int d = (r & 3) + 8 * (r >> 2) + 4 * hl;
        const int byteoff = q32 * 128 + ((4 * d) ^ ((q32 & 7) << 4));
        *(float*)((char*)Ot + byteoff) = oacc[t32][d32][r] * inv;
      }
      const int qr = lane >> 1, dc = (lane & 1) * 16;
      union { u16 s[16]; uint4 v[2]; } ob;
      #pragma unroll
      for (int cch = 0; cch < 4; ++cch) {
        const int byteoff = qr * 128 + ((4 * (dc + 4 * cch)) ^ ((qr & 7) << 4));
        const f32x4 vv = *(const f32x4*)((const char*)Ot + byteoff);
        ob.s[cch * 4 + 0] = f2bf(vv[0]);
        ob.s[cch * 4 + 1] = f2bf(vv[1]);
        ob.s[cch * 4 + 2] = f2bf(vv[2]);
        ob.s[cch * 4 + 3] = f2bf(vv[3]);
      }
      u16* orow = &o[(qbase + t32 * 32 + qr) * 5120 + hd * 64 + d32 * 32 + dc];
      *(uint4*)orow = ob.v[0];
      *(uint4*)(orow + 8) = ob.v[1];
    }
  }
}

extern "C" void kernel_launch(void* const* d_in, const int* in_sizes, int n_in,
                              void* d_out, int out_size, void* d_ws, size_t ws_size,
                              hipStream_t stream)
{
  const float* x    = (const float*)d_in[0];
  const float* ctx  = (const float*)d_in[1];
  const float* ng   = (const float*)d_in[2];
  const float* nb   = (const float*)d_in[3];
  const float* cg   = (const float*)d_in[4];
  const float* cb   = (const float*)d_in[5];
  const float* Wq   = (const float*)d_in[6];
  const float* Wkv  = (const float*)d_in[7];
  const float* Wo   = (const float*)d_in[8];
  const float* Wff1 = (const float*)d_in[9];
  const float* Wff2 = (const float*)d_in[10];

  u16* p = (u16*)d_ws;
  u16* W1T   = p; p += (size_t)9216 * 1024;
  u16* WkvT  = p; p += (size_t)128 * 1024;
  u16* WcT   = p; p += (size_t)1024 * 5120;
  u16* kvbuf = p; p += (size_t)4096 * 128;
  u16* aoh   = p; p += (size_t)4096 * 5120;
  u16* xn    = p; p += (size_t)4096 * 1024;
  u16* cn    = p; p += (size_t)4096 * 1024;
  u16* qbuf  = p; p += (size_t)4096 * 1024;
  u16* kvpart = W1T;   // 8 MB bf16 over W1T (dead after qff GEMM)
  u16* ffpart = xn;    // 32 MB bf16 over xn|cn|qbuf + tail (dead by final GEMM)
  (void)in_sizes; (void)n_in; (void)out_size; (void)ws_size;

  ln_kernel<<<8192, 256, 0, stream>>>(x, ctx, ng, nb, cg, cb, xn, cn);

  transpose_k<<<dim3(16, 16),  256, 0, stream>>>(Wq,   W1T,        1024, 1024, 1024, 0.125f);
  transpose_ff1<<<dim3(128, 16), 256, 0, stream>>>(Wff1, W1T);
  transpose_k<<<dim3(2, 16),   256, 0, stream>>>(Wkv,  WkvT,       1024, 128,  1024, 1.0f);
  transpose_k<<<dim3(16, 16),  256, 0, stream>>>(Wo,   WcT,        1024, 1024, 5120, 1.0f);
  transpose_k<<<dim3(16, 64),  256, 0, stream>>>(Wff2, WcT + 1024, 4096, 1024, 5120, 1.0f);

  // fused: qbuf = xn@Wq*scale ; aoh[:,1024:] = silu(xn@Wff1); BK=32 variant
  gemm32<2, 0><<<dim3(576), 512, 0, stream>>>(xn, W1T, qbuf, aoh, 4096, 9216, 1024, 1024);
  // kv = cn @ Wkv, split-K 8 (bf16 partials over dead W1T), reduce to bf16
  gemm_bt_sk<<<dim3(1, 32, 8), 256, 0, stream>>>(cn, WkvT, kvpart, 4096, 128, 128, 1024);
  reduce_kv<<<256, 256, 0, stream>>>(kvpart, kvbuf);
  // attention -> aoh[:,0:1024] (T14 async-V + T5 setprio)
  attn_kernel<<<dim3(32, 4, 2), 256, 0, stream>>>(qbuf, kvbuf, aoh);
  // out = aoh @ [Wo ; Wff2], split-K 4, bf16 partials; BK=64 variant
  gemm64<3, 1><<<dim3(64, 4), 512, 0, stream>>>(aoh, WcT, ffpart, nullptr, 4096, 1024, 5120, 1280);
  reduce_out<<<2048, 256, 0, stream>>>(ffpart, (float*)d_out);
}

// Round 15
// 285.416 us; speedup vs baseline: 4.7895x; 1.0071x over previous
//
#include <hip/hip_runtime.h>
#include <stdint.h>

typedef unsigned short u16;
typedef __attribute__((ext_vector_type(8))) short short8;
typedef __attribute__((ext_vector_type(4))) float f32x4;
typedef __attribute__((ext_vector_type(16))) float f32x16;

#define GPTR(p) ((const __attribute__((address_space(1))) void*)(p))
#define SPTR(p) ((__attribute__((address_space(3))) void*)(p))
#define GLDS16(g, l) __builtin_amdgcn_global_load_lds(GPTR(g), SPTR(l), 16, 0, 0)

static __device__ __forceinline__ float bf2f(u16 u) {
  union { unsigned int i; float f; } c; c.i = ((unsigned int)u) << 16; return c.f;
}
static __device__ __forceinline__ u16 f2bf(float f) {
  union { float f; unsigned int u; } c; c.f = f;
  unsigned int r = 0x7fffu + ((c.u >> 16) & 1u);
  return (u16)((c.u + r) >> 16);
}
static __device__ __forceinline__ unsigned cvtpk(float a, float b) {
  unsigned r;
  asm volatile("v_cvt_pk_bf16_f32 %0, %1, %2" : "=v"(r) : "v"(a), "v"(b));
  return r;
}
static __device__ __forceinline__ int swz4(int row, int c) { return c ^ ((row >> 1) & 3); }

// ---------------- LayerNorm: f32 (rows of 1024) -> bf16 ----------------
__global__ __launch_bounds__(256) void ln_kernel(
    const float* __restrict__ x, const float* __restrict__ ctx,
    const float* __restrict__ g, const float* __restrict__ b,
    const float* __restrict__ cg, const float* __restrict__ cb,
    u16* __restrict__ xn, u16* __restrict__ cn)
{
  const int row = blockIdx.x;
  const float* src; const float* gg; const float* bb; u16* dst;
  if (row < 4096) { src = x + (size_t)row * 1024; gg = g;  bb = b;  dst = xn + (size_t)row * 1024; }
  else            { src = ctx + (size_t)(row - 4096) * 1024; gg = cg; bb = cb; dst = cn + (size_t)(row - 4096) * 1024; }
  const int t = threadIdx.x;
  float4 v = *(const float4*)&src[t * 4];
  float s  = v.x + v.y + v.z + v.w;
  float s2 = v.x * v.x + v.y * v.y + v.z * v.z + v.w * v.w;
  #pragma unroll
  for (int off = 1; off < 64; off <<= 1) { s += __shfl_xor(s, off); s2 += __shfl_xor(s2, off); }
  __shared__ float ls[4], ls2[4];
  const int w = t >> 6;
  if ((t & 63) == 0) { ls[w] = s; ls2[w] = s2; }
  __syncthreads();
  s  = ls[0] + ls[1] + ls[2] + ls[3];
  s2 = ls2[0] + ls2[1] + ls2[2] + ls2[3];
  const float mu   = s * (1.0f / 1024.0f);
  const float var  = s2 * (1.0f / 1024.0f) - mu * mu;
  const float rstd = rsqrtf(var + 1e-5f);
  float xv[4] = { v.x, v.y, v.z, v.w };
  u16 o[4];
  #pragma unroll
  for (int i = 0; i < 4; ++i)
    o[i] = f2bf((xv[i] - mu) * rstd * gg[t * 4 + i] + bb[t * 4 + i]);
  uint2 pv;
  pv.x = (unsigned)o[0] | ((unsigned)o[1] << 16);
  pv.y = (unsigned)o[2] | ((unsigned)o[3] << 16);
  *(uint2*)&dst[t * 4] = pv;
}

// ---------------- transpose+convert: f32 (R,C) -> bf16 (C,R) with out leading dim ----------------
__global__ __launch_bounds__(256) void transpose_k(
    const float* __restrict__ in, u16* __restrict__ out, int R, int C, int ldo, float scale)
{
  __shared__ float tile[64][65];
  const int c0 = blockIdx.x * 64, r0 = blockIdx.y * 64;
  const int t = threadIdx.x;
  const int tr = t >> 4, tc = (t & 15) * 4;
  #pragma unroll
  for (int i = 0; i < 4; ++i) {
    int r = tr + i * 16;
    float4 v = *(const float4*)&in[(size_t)(r0 + r) * C + c0 + tc];
    tile[r][tc + 0] = v.x; tile[r][tc + 1] = v.y; tile[r][tc + 2] = v.z; tile[r][tc + 3] = v.w;
  }
  __syncthreads();
  #pragma unroll
  for (int i = 0; i < 2; ++i) {
    int c  = (t >> 3) + i * 32;
    int rb = (t & 7) * 8;
    union { u16 s[8]; uint4 v; } pk;
    #pragma unroll
    for (int u = 0; u < 8; ++u) pk.s[u] = f2bf(tile[rb + u][c] * scale);
    *(uint4*)&out[(size_t)(c0 + c) * ldo + r0 + rb] = pk.v;
  }
}

// ---------------- Wff1 transpose with (a,gate) fragment interleave -> W2T (8192 rows) ----------------
__global__ __launch_bounds__(256) void transpose_ff1(
    const float* __restrict__ in, u16* __restrict__ out)
{
  __shared__ float tile[64][65];
  const int c0 = blockIdx.x * 64, r0 = blockIdx.y * 64;
  const int t = threadIdx.x;
  const int tr = t >> 4, tc = (t & 15) * 4;
  #pragma unroll
  for (int i = 0; i < 4; ++i) {
    int r = tr + i * 16;
    float4 v = *(const float4*)&in[(size_t)(r0 + r) * 8192 + c0 + tc];
    tile[r][tc + 0] = v.x; tile[r][tc + 1] = v.y; tile[r][tc + 2] = v.z; tile[r][tc + 3] = v.w;
  }
  __syncthreads();
  #pragma unroll
  for (int i = 0; i < 2; ++i) {
    int c  = (t >> 3) + i * 32;
    int rb = (t & 7) * 8;
    const int gc = c0 + c;
    int j, add16;
    if (gc < 4096) { j = gc; add16 = 0; } else { j = gc - 4096; add16 = 16; }
    const int row = ((j >> 7) << 8) + (((j >> 5) & 3) << 6) + (((j >> 4) & 1) << 5) + add16 + (j & 15);
    union { u16 s[8]; uint4 v; } pk;
    #pragma unroll
    for (int u = 0; u < 8; ++u) pk.s[u] = f2bf(tile[rb + u][c]);
    *(uint4*)&out[(size_t)row * 1024 + r0 + rb] = pk.v;
  }
}

// =============== BK=32 4-phase 256x256 GEMM (ff: N=8192, 512 blocks = exact 2/CU pack) ===============
#define MM32(MQ, M, NN) acc[MQ][M][NN] = __builtin_amdgcn_mfma_f32_16x16x32_bf16(af##M, bf##NN, acc[MQ][M][NN], 0, 0, 0)
#define MFMA16_32(MQ) \
  MM32(MQ,0,0); MM32(MQ,0,1); MM32(MQ,0,2); MM32(MQ,0,3); \
  MM32(MQ,1,0); MM32(MQ,1,1); MM32(MQ,1,2); MM32(MQ,1,3); \
  MM32(MQ,2,0); MM32(MQ,2,1); MM32(MQ,2,2); MM32(MQ,2,3); \
  MM32(MQ,3,0); MM32(MQ,3,1); MM32(MQ,3,2); MM32(MQ,3,3)

#define SA32(SBUF, H, KT) GLDS16(gA32[H] + ((size_t)(KT) << 5), SBUF + (size_t)((H) * 64 + w16o) * 32)
#define SB32(SBUF, H, KT) GLDS16(gB32[H] + ((size_t)(KT) << 5), SBUF + (size_t)((H) * 128 + w16o2) * 32)

#define DSB32(PB_) do { \
  bf0 = *(const short8*)(PB_ + 0    + cks); bf1 = *(const short8*)(PB_ + 512  + cks); \
  bf2 = *(const short8*)(PB_ + 1024 + cks); bf3 = *(const short8*)(PB_ + 1536 + cks); \
} while (0)

#define PC32(PA_, MQ, STAGE_STMT, GATE_STMT) do { \
  af0 = *(const short8*)(PA_ + (MQ) * 2048 + 0    + cks); \
  af1 = *(const short8*)(PA_ + (MQ) * 2048 + 512  + cks); \
  af2 = *(const short8*)(PA_ + (MQ) * 2048 + 1024 + cks); \
  af3 = *(const short8*)(PA_ + (MQ) * 2048 + 1536 + cks); \
  STAGE_STMT; \
  __builtin_amdgcn_s_barrier(); \
  asm volatile("s_waitcnt lgkmcnt(0)" ::: "memory"); \
  __builtin_amdgcn_s_setprio(1); \
  MFMA16_32(MQ); \
  __builtin_amdgcn_s_setprio(0); \
  GATE_STMT; \
  __builtin_amdgcn_s_barrier(); \
} while (0)

#define GATE3 asm volatile("s_waitcnt vmcnt(3)" ::: "memory")
#define GATE0 asm volatile("s_waitcnt vmcnt(0)" ::: "memory")

__global__ __launch_bounds__(512, 2) void gemm32_ff(
    const u16* __restrict__ A, const u16* __restrict__ BT, u16* __restrict__ Ho,
    int M, int N, int Ktot)
{
  __shared__ u16 sh[2][2][8192]; // 64 KB
  const int nbm = M >> 8;
  const int nwg = gridDim.x;
  const int bid = blockIdx.x;
  const int o = (bid & 7) * (nwg >> 3) + (bid >> 3);
  const int bm = o % nbm, bn = o / nbm;   // B-strip per XCD
  const int NI = Ktot >> 6;

  const int t = threadIdx.x, w = t >> 6, lane = t & 63;
  const int wr = w >> 2, wc = w & 3;
  const int lr = lane & 15, lg = lane >> 4;
  const int l4 = lane >> 2, sl = lane & 3;
  const int w16o  = w * 16 + ((w >= 4) ? 64 : 0);
  const int w16o2 = w * 16;

  const u16* gA32[2]; const u16* gB32[2];
  #pragma unroll
  for (int h = 0; h < 2; ++h) {
    const int rowA = h * 64 + w16o + l4;
    gA32[h] = A + (size_t)(bm * 256 + rowA) * Ktot + (size_t)((sl ^ ((rowA >> 1) & 3)) * 8);
    const int rowB = h * 128 + w16o2 + l4;
    gB32[h] = BT + (size_t)(bn * 256 + rowB) * Ktot + (size_t)((sl ^ ((rowB >> 1) & 3)) * 8);
  }
  u16* sA0 = &sh[0][0][0]; u16* sA1 = &sh[1][0][0];
  u16* sB0 = &sh[0][1][0]; u16* sB1 = &sh[1][1][0];
  const int cks = (lg ^ ((lr >> 1) & 3)) * 8;
  const u16* pA_b0 = sA0 + (wr * 128 + lr) * 32;
  const u16* pA_b1 = sA1 + (wr * 128 + lr) * 32;
  const u16* pB_b0 = sB0 + (wc * 64 + lr) * 32;
  const u16* pB_b1 = sB1 + (wc * 64 + lr) * 32;

  f32x4 acc[2][4][4];
  const f32x4 z4 = { 0.f, 0.f, 0.f, 0.f };
  #pragma unroll
  for (int a = 0; a < 2; ++a)
    #pragma unroll
    for (int b = 0; b < 4; ++b)
      #pragma unroll
      for (int c = 0; c < 4; ++c) acc[a][b][c] = z4;
  short8 af0, af1, af2, af3;
  short8 bf0, bf1, bf2, bf3;

  SA32(sA0, 0, 0); SA32(sA0, 1, 0); SB32(sB0, 0, 0); SB32(sB0, 1, 0);
  SB32(sB1, 0, 1); SB32(sB1, 1, 1); SA32(sA1, 0, 1);
  GATE3;
  __builtin_amdgcn_s_barrier();

  for (int i = 0; i < NI; ++i) {
    const bool st = (i < NI - 1);
    const int X = 2 * i + 2, Y = 2 * i + 3;
    DSB32(pB_b0);
    PC32(pA_b0, 0, SA32(sA1, 1, 2 * i + 1), );
    PC32(pA_b0, 1,
         if (st) { SB32(sB0, 0, X); SB32(sB0, 1, X); SA32(sA0, 0, X); },
         if (st) { GATE3; } else { GATE0; });
    DSB32(pB_b1);
    PC32(pA_b1, 0, if (st) { SA32(sA0, 1, X); }, );
    PC32(pA_b1, 1,
         if (st) { SB32(sB1, 0, Y); SB32(sB1, 1, Y); SA32(sA1, 0, Y); },
         if (st) { GATE3; });
  }

  // silu(gate)*a pair-fused epilogue -> aoh cols 1024 + bn*128 .. (stride 5120)
  const int colb = 1024 + bn * 128 + wc * 32 + lr;
  #pragma unroll
  for (int mq = 0; mq < 2; ++mq)
    #pragma unroll
    for (int m = 0; m < 4; ++m)
      #pragma unroll
      for (int rr = 0; rr < 4; ++rr) {
        const int row = bm * 256 + wr * 128 + mq * 64 + m * 16 + lg * 4 + rr;
        #pragma unroll
        for (int n2 = 0; n2 < 2; ++n2) {
          const float a = acc[mq][m][2 * n2][rr];
          const float gt = acc[mq][m][2 * n2 + 1][rr];
          const float h = a * gt / (1.0f + __expf(-gt));
          Ho[(size_t)row * 5120 + colb + n2 * 16] = f2bf(h);
        }
      }
}

// =============== BK=64 8-phase 256x256 GEMM (final GEMM, split-K 4, bf16 partials) ===============
#define MM1(MQ, M, NN, BF) acc[MQ][M][NN] = __builtin_amdgcn_mfma_f32_16x16x32_bf16(af##M, BF, acc[MQ][M][NN], 0, 0, 0)
#define MFMA16(MQ, KS) \
  MM1(MQ,0,0,bf##KS##0); MM1(MQ,0,1,bf##KS##1); MM1(MQ,0,2,bf##KS##2); MM1(MQ,0,3,bf##KS##3); \
  MM1(MQ,1,0,bf##KS##0); MM1(MQ,1,1,bf##KS##1); MM1(MQ,1,2,bf##KS##2); MM1(MQ,1,3,bf##KS##3); \
  MM1(MQ,2,0,bf##KS##0); MM1(MQ,2,1,bf##KS##1); MM1(MQ,2,2,bf##KS##2); MM1(MQ,2,3,bf##KS##3); \
  MM1(MQ,3,0,bf##KS##0); MM1(MQ,3,1,bf##KS##1); MM1(MQ,3,2,bf##KS##2); MM1(MQ,3,3,bf##KS##3)

#define SG_A(SBUF, H, KT) do { \
    GLDS16(gA[H][0] + ((size_t)(KT) << 6), SBUF + ((H) * 64 + w16o) * 64); \
    GLDS16(gA[H][1] + ((size_t)(KT) << 6), SBUF + ((H) * 64 + w16o + 8) * 64); \
  } while (0)
#define SG_B(SBUF, H, KT) do { \
    GLDS16(gB[H][0] + ((size_t)(KT) << 6), SBUF + ((H) * 128 + w16o2) * 64); \
    GLDS16(gB[H][1] + ((size_t)(KT) << 6), SBUF + ((H) * 128 + w16o2 + 8) * 64); \
  } while (0)

#define DS_B(PB_) do { \
  bf00 = *(const short8*)(PB_ + 0    + cks0); bf01 = *(const short8*)(PB_ + 1024 + cks0); \
  bf02 = *(const short8*)(PB_ + 2048 + cks0); bf03 = *(const short8*)(PB_ + 3072 + cks0); \
  bf10 = *(const short8*)(PB_ + 0    + cks1); bf11 = *(const short8*)(PB_ + 1024 + cks1); \
  bf12 = *(const short8*)(PB_ + 2048 + cks1); bf13 = *(const short8*)(PB_ + 3072 + cks1); \
} while (0)

#define P_CORE(PA_, MQ, KS, STAGE_STMT, PREB_STMT, GATE_STMT) do { \
  af0 = *(const short8*)(PA_ + (MQ) * 4096 + 0    + cks##KS); \
  af1 = *(const short8*)(PA_ + (MQ) * 4096 + 1024 + cks##KS); \
  af2 = *(const short8*)(PA_ + (MQ) * 4096 + 2048 + cks##KS); \
  af3 = *(const short8*)(PA_ + (MQ) * 4096 + 3072 + cks##KS); \
  STAGE_STMT; \
  PREB_STMT; \
  __builtin_amdgcn_s_barrier(); \
  asm volatile("s_waitcnt lgkmcnt(0)" ::: "memory"); \
  __builtin_amdgcn_s_setprio(1); \
  MFMA16(MQ, KS); \
  __builtin_amdgcn_s_setprio(0); \
  GATE_STMT; \
  __builtin_amdgcn_s_barrier(); \
} while (0)

#define GATE6 asm volatile("s_waitcnt vmcnt(6)" ::: "memory")
#define HINT8 asm volatile("s_waitcnt lgkmcnt(8)" ::: "memory")

__global__ __launch_bounds__(512, 2) void gemm64_sk(
    const u16* __restrict__ A, const u16* __restrict__ BT, u16* __restrict__ C,
    int M, int N, int Ktot, int Kslice)
{
  __shared__ u16 sh[2][2][16384]; // 128 KB
  const int nbn = N >> 8;
  const int nwg = gridDim.x;
  const int bid = blockIdx.x;
  const int o = (bid & 7) * (nwg >> 3) + (bid >> 3);
  const int bn = o % nbn, bm = o / nbn;   // A-panels per XCD
  const int kbase = blockIdx.y * Kslice;
  const int NI = Kslice >> 7;

  const int t = threadIdx.x, w = t >> 6, lane = t & 63;
  const int wr = w >> 2, wc = w & 3;
  const int lr = lane & 15, lg = lane >> 4;
  const int r8 = lane >> 3, ch = lane & 7;
  const int clog = ch ^ r8;
  const int w16o  = w * 16 + ((w >= 4) ? 64 : 0);
  const int w16o2 = w * 16;

  const u16* gA[2][2]; const u16* gB[2][2];
  #pragma unroll
  for (int h = 0; h < 2; ++h)
    #pragma unroll
    for (int qq = 0; qq < 2; ++qq) {
      gA[h][qq] = A  + (size_t)(bm * 256 + h * 64  + w16o  + qq * 8 + r8) * Ktot + kbase + clog * 8;
      gB[h][qq] = BT + (size_t)(bn * 256 + h * 128 + w16o2 + qq * 8 + r8) * Ktot + kbase + clog * 8;
    }
  u16* sA0 = &sh[0][0][0]; u16* sA1 = &sh[1][0][0];
  u16* sB0 = &sh[0][1][0]; u16* sB1 = &sh[1][1][0];
  const int cks0 = ((0 + lg) ^ (lr & 7)) * 8;
  const int cks1 = ((4 + lg) ^ (lr & 7)) * 8;
  const u16* pA_b0 = sA0 + (wr * 128 + lr) * 64;
  const u16* pA_b1 = sA1 + (wr * 128 + lr) * 64;
  const u16* pB_b0 = sB0 + (wc * 64 + lr) * 64;
  const u16* pB_b1 = sB1 + (wc * 64 + lr) * 64;

  f32x4 acc[2][4][4];
  const f32x4 z4 = { 0.f, 0.f, 0.f, 0.f };
  #pragma unroll
  for (int a = 0; a < 2; ++a)
    #pragma unroll
    for (int b = 0; b < 4; ++b)
      #pragma unroll
      for (int c = 0; c < 4; ++c) acc[a][b][c] = z4;
  short8 af0, af1, af2, af3;
  short8 bf00, bf01, bf02, bf03, bf10, bf11, bf12, bf13;

  SG_B(sB0, 0, 0); SG_B(sB0, 1, 0); SG_A(sA0, 0, 0); SG_A(sA0, 1, 0);
  SG_B(sB1, 0, 1); SG_B(sB1, 1, 1); SG_A(sA1, 0, 1);
  GATE6;
  __builtin_amdgcn_s_barrier();

  for (int i = 0; i < NI; ++i) {
    const int k2 = 2 * i;
    const bool st = (i < NI - 1);
    DS_B(pB_b0);
    P_CORE(pA_b0, 0, 0, SG_A(sA1, 1, k2 + 1), HINT8, );
    P_CORE(pA_b0, 1, 0, if (st) SG_B(sB0, 0, k2 + 2), , );
    P_CORE(pA_b0, 0, 1, if (st) SG_B(sB0, 1, k2 + 2), , );
    P_CORE(pA_b0, 1, 1, if (st) SG_A(sA0, 0, k2 + 2), ,
           if (st) { GATE6; } else { GATE0; });
    DS_B(pB_b1);
    P_CORE(pA_b1, 0, 0, if (st) SG_A(sA0, 1, k2 + 2), HINT8, );
    P_CORE(pA_b1, 1, 0, if (st) SG_B(sB1, 0, k2 + 3), , );
    P_CORE(pA_b1, 0, 1, if (st) SG_B(sB1, 1, k2 + 3), , );
    P_CORE(pA_b1, 1, 1, if (st) SG_A(sA1, 0, k2 + 3), ,
           if (st) { GATE6; });
  }

  u16* Co = C + (size_t)blockIdx.y * M * N;
  #pragma unroll
  for (int mq = 0; mq < 2; ++mq)
    #pragma unroll
    for (int m = 0; m < 4; ++m)
      #pragma unroll
      for (int n = 0; n < 4; ++n)
        #pragma unroll
        for (int rr = 0; rr < 4; ++rr) {
          const int row = bm * 256 + wr * 128 + mq * 64 + m * 16 + lg * 4 + rr;
          const int col = bn * 256 + wc * 64 + n * 16 + lr;
          Co[(size_t)row * N + col] = f2bf(acc[mq][m][n][rr]);
        }
}

// ---------------- split-K / plain GEMM 128x128, bf16 out (q projection + kv projection) ----------------
__global__ __launch_bounds__(256) void gemm_bt_sk(
    const u16* __restrict__ A, const u16* __restrict__ BT, u16* __restrict__ Cp,
    int M, int N, int Kslice, int Ktot)
{
  __shared__ u16 As[128 * 32];
  __shared__ u16 Bs[128 * 32];
  const int bm = blockIdx.y, bn = blockIdx.x, z = blockIdx.z;
  const int t = threadIdx.x;
  const int w = t >> 6, lane = t & 63;
  const int wr = w >> 1, wc = w & 1;
  const int lr = lane & 15, lkc = lane >> 4;

  f32x4 acc[4][4];
  const f32x4 z4 = { 0.f, 0.f, 0.f, 0.f };
  #pragma unroll
  for (int mi = 0; mi < 4; ++mi)
    #pragma unroll
    for (int ni = 0; ni < 4; ++ni) acc[mi][ni] = z4;

  const int kbase = z * Kslice;
  const int i0 = t, i1 = t + 256;
  const int r0 = i0 >> 2, k0 = swz4(r0, i0 & 3) * 8;
  const int r1 = i1 >> 2, k1 = swz4(r1, i1 & 3) * 8;
  const u16* a0 = A + (size_t)(bm * 128 + r0) * Ktot + kbase + k0;
  const u16* a1 = A + (size_t)(bm * 128 + r1) * Ktot + kbase + k1;
  const u16* b0 = BT + (size_t)(bn * 128 + r0) * Ktot + kbase + k0;
  const u16* b1 = BT + (size_t)(bn * 128 + r1) * Ktot + kbase + k1;
  u16* As0 = As + (size_t)w * 512;
  u16* As1 = As + (size_t)(w + 4) * 512;
  u16* Bs0 = Bs + (size_t)w * 512;
  u16* Bs1 = Bs + (size_t)(w + 4) * 512;

  const int nk = Kslice >> 5;
  for (int kt = 0; kt < nk; ++kt) {
    __syncthreads();
    GLDS16(a0, As0); GLDS16(a1, As1); GLDS16(b0, Bs0); GLDS16(b1, Bs1);
    a0 += 32; a1 += 32; b0 += 32; b1 += 32;
    __syncthreads();
    short8 af[4], bf[4];
    #pragma unroll
    for (int mi = 0; mi < 4; ++mi) {
      int row = wr * 64 + mi * 16 + lr;
      af[mi] = *(const short8*)&As[row * 32 + swz4(row, lkc) * 8];
    }
    #pragma unroll
    for (int ni = 0; ni < 4; ++ni) {
      int row = wc * 64 + ni * 16 + lr;
      bf[ni] = *(const short8*)&Bs[row * 32 + swz4(row, lkc) * 8];
    }
    #pragma unroll
    for (int mi = 0; mi < 4; ++mi)
      #pragma unroll
      for (int ni = 0; ni < 4; ++ni)
        acc[mi][ni] = __builtin_amdgcn_mfma_f32_16x16x32_bf16(af[mi], bf[ni], acc[mi][ni], 0, 0, 0);
  }

  u16* Cz = Cp + (size_t)z * M * N;
  const int row0 = bm * 128 + wr * 64, col0 = bn * 128 + wc * 64;
  const int rsub = (lane >> 4) * 4;
  #pragma unroll
  for (int mi = 0; mi < 4; ++mi)
    #pragma unroll
    for (int ni = 0; ni < 4; ++ni)
      #pragma unroll
      for (int r = 0; r < 4; ++r)
        Cz[(size_t)(row0 + mi * 16 + rsub + r) * N + (col0 + ni * 16 + lr)] = f2bf(acc[mi][ni][r]);
}

// ---------------- reduce 8 bf16 partials (4096x128) -> bf16 ----------------
__global__ __launch_bounds__(256) void reduce_kv(const u16* __restrict__ part, u16* __restrict__ out)
{
  const size_t base = ((size_t)blockIdx.x * 256 + threadIdx.x) * 8;
  float s[8] = { 0.f, 0.f, 0.f, 0.f, 0.f, 0.f, 0.f, 0.f };
  #pragma unroll
  for (int zz = 0; zz < 8; ++zz) {
    const short8 v = *(const short8*)&part[(size_t)zz * 524288 + base];
    #pragma unroll
    for (int i = 0; i < 8; ++i) s[i] += bf2f((u16)v[i]);
  }
  union { u16 o[8]; uint4 v; } pk;
  #pragma unroll
  for (int i = 0; i < 8; ++i) pk.o[i] = f2bf(s[i]);
  *(uint4*)&out[base] = pk.v;
}

// ---------------- out = sum of 4 bf16 partials (4096x1024) -> f32 ----------------
__global__ __launch_bounds__(256) void reduce_out(const u16* __restrict__ part, float* __restrict__ out)
{
  const size_t base = ((size_t)blockIdx.x * 256 + threadIdx.x) * 8;
  float s[8] = { 0.f, 0.f, 0.f, 0.f, 0.f, 0.f, 0.f, 0.f };
  #pragma unroll
  for (int zz = 0; zz < 4; ++zz) {
    const short8 v = *(const short8*)&part[(size_t)zz * 4194304 + base];
    #pragma unroll
    for (int i = 0; i < 8; ++i) s[i] += bf2f((u16)v[i]);
  }
  f32x4 lo = { s[0], s[1], s[2], s[3] };
  f32x4 hi = { s[4], s[5], s[6], s[7] };
  *(f32x4*)&out[base] = lo;
  *(f32x4*)&out[base + 4] = hi;
}

// ---------------- flash cross-attention (multi-query: 1 KV head) ----------------
__global__ __launch_bounds__(256) void attn_kernel(
    const u16* __restrict__ q, const u16* __restrict__ kv, u16* __restrict__ o)
{
  __shared__ u16 Ks[128 * 64];
  __shared__ u16 Vt[64 * 128];
  __shared__ u16 Ps[4][32 * 128];
  const int b = blockIdx.z, hb = blockIdx.y, qb = blockIdx.x;
  const int t = threadIdx.x, w = t >> 6, lane = t & 63;
  const int q32 = lane & 31, hl = lane >> 5;
  const int hd = hb * 4 + w;

  const size_t qbase = (size_t)b * 2048 + qb * 64;
  short8 qa[2][4];
  #pragma unroll
  for (int t32 = 0; t32 < 2; ++t32)
    #pragma unroll
    for (int dq = 0; dq < 4; ++dq)
      qa[t32][dq] = *(const short8*)&q[(qbase + t32 * 32 + q32) * 1024 + hd * 64 + dq * 16 + hl * 8];

  f32x16 oacc[2][2];
  #pragma unroll
  for (int i = 0; i < 2; ++i)
    #pragma unroll
    for (int j = 0; j < 2; ++j)
      #pragma unroll
      for (int r = 0; r < 16; ++r) oacc[i][j][r] = 0.f;
  float m_[2] = { -1e30f, -1e30f }, l_[2] = { 0.f, 0.f };

  const size_t kvb = (size_t)b * 2048 * 128;
  const int vd0 = (t & 7) * 8;
  const int vodd = (t >> 3) & 1;
  u16* Pw = &Ps[w][0];

  uint4 vhold[4];
  #pragma unroll
  for (int c = 0; c < 4; ++c) {
    const int vj = (c * 256 + t) >> 3;
    vhold[c] = *(const uint4*)&kv[kvb + (size_t)vj * 128 + 64 + vd0];
  }

  for (int jt = 0; jt < 16; ++jt) {
    __syncthreads();
    #pragma unroll
    for (int n = 0; n < 4; ++n) {
      const int cc = n * 256 + w * 64;
      const int ccl = cc + lane;
      const int row = ccl >> 3, lc = (ccl & 7) ^ (row & 7);
      GLDS16(&kv[kvb + (size_t)(jt * 128 + row) * 128 + lc * 8], Ks + (size_t)cc * 8);
    }
    #pragma unroll
    for (int c = 0; c < 4; ++c) {
      const int seg = c * 256 + t;
      const int vj = seg >> 3;
      const int jp = vj >> 1;
      const uint4 vv = vhold[c];
      uint4 pvv;
      pvv.x = __shfl_xor((int)vv.x, 8);
      pvv.y = __shfl_xor((int)vv.y, 8);
      pvv.z = __shfl_xor((int)vv.z, 8);
      pvv.w = __shfl_xor((int)vv.w, 8);
      const unsigned ow[4] = { vv.x, vv.y, vv.z, vv.w };
      const unsigned pw[4] = { pvv.x, pvv.y, pvv.z, pvv.w };
      if (!vodd) {
        #pragma unroll
        for (int u = 0; u < 4; ++u) {
          const int d = vd0 + u;
          const unsigned own = (u & 1) ? (ow[u >> 1] >> 16) : (ow[u >> 1] & 0xffffu);
          const unsigned par = (u & 1) ? (pw[u >> 1] >> 16) : (pw[u >> 1] & 0xffffu);
          const int byteoff = d * 256 + ((4 * jp) ^ (((d & 7) ^ ((d >> 3) & 7)) << 4));
          *(unsigned*)((char*)Vt + byteoff) = own | (par << 16);
        }
      } else {
        #pragma unroll
        for (int u = 0; u < 4; ++u) {
          const int ue = u + 4;
          const int d = vd0 + ue;
          const unsigned own = (ue & 1) ? (ow[ue >> 1] >> 16) : (ow[ue >> 1] & 0xffffu);
          const unsigned par = (ue & 1) ? (pw[ue >> 1] >> 16) : (pw[ue >> 1] & 0xffffu);
          const int byteoff = d * 256 + ((4 * jp) ^ (((d & 7) ^ ((d >> 3) & 7)) << 4));
          *(unsigned*)((char*)Vt + byteoff) = par | (own << 16);
        }
      }
    }
    __builtin_amdgcn_sched_barrier(0);
    if (jt < 15) {
      #pragma unroll
      for (int c = 0; c < 4; ++c) {
        const int vj = (c * 256 + t) >> 3;
        vhold[c] = *(const uint4*)&kv[kvb + (size_t)((jt + 1) * 128 + vj) * 128 + 64 + vd0];
      }
      asm volatile("s_waitcnt vmcnt(4) lgkmcnt(0)" ::: "memory");
    } else {
      asm volatile("s_waitcnt vmcnt(0) lgkmcnt(0)" ::: "memory");
    }
    __builtin_amdgcn_s_barrier();
    __builtin_amdgcn_sched_barrier(0);

    #pragma unroll
    for (int t32 = 0; t32 < 2; ++t32) {
      f32x16 s[4];
      #pragma unroll
      for (int j32 = 0; j32 < 4; ++j32)
        #pragma unroll
        for (int r = 0; r < 16; ++r) s[j32][r] = 0.f;
      __builtin_amdgcn_s_setprio(1);
      #pragma unroll
      for (int j32 = 0; j32 < 4; ++j32) {
        const int row = j32 * 32 + q32;
        #pragma unroll
        for (int dq = 0; dq < 4; ++dq) {
          const int slot = (dq * 2 + hl) ^ (row & 7);
          const short8 kf = *(const short8*)&Ks[row * 64 + slot * 8];
          s[j32] = __builtin_amdgcn_mfma_f32_32x32x16_bf16(kf, qa[t32][dq], s[j32], 0, 0, 0);
        }
      }
      __builtin_amdgcn_s_setprio(0);
      float mt = -1e30f;
      #pragma unroll
      for (int j32 = 0; j32 < 4; ++j32)
        #pragma unroll
        for (int r = 0; r < 16; ++r) mt = fmaxf(mt, s[j32][r]);
      mt = fmaxf(mt, __shfl_xor(mt, 32));
      const bool noresc = (bool)__all(mt <= m_[t32] + 8.0f);
      float nm = m_[t32];
      if (!noresc) {
        nm = fmaxf(m_[t32], mt);
        const float alpha = __expf(m_[t32] - nm);
        m_[t32] = nm;
        l_[t32] *= alpha;
        #pragma unroll
        for (int d32 = 0; d32 < 2; ++d32)
          #pragma unroll
          for (int r = 0; r < 16; ++r) oacc[t32][d32][r] *= alpha;
      }
      float lsum = 0.f;
      #pragma unroll
      for (int j32 = 0; j32 < 4; ++j32) {
        float p[16];
        #pragma unroll
        for (int r = 0; r < 16; ++r) { p[r] = __expf(s[j32][r] - nm); lsum += p[r]; }
        #pragma unroll
        for (int g = 0; g < 4; ++g) {
          const unsigned lo = cvtpk(p[4 * g + 0], p[4 * g + 1]);
          const unsigned hi = cvtpk(p[4 * g + 2], p[4 * g + 3]);
          const int j2 = j32 * 64 + 16 * g + 8 * hl;
          const int byteoff = q32 * 256 + (j2 ^ ((q32 & 7) << 4));
          uint2 wv; wv.x = lo; wv.y = hi;
          *(uint2*)((char*)Pw + byteoff) = wv;
        }
      }
      lsum += __shfl_xor(lsum, 32);
      l_[t32] += lsum;
      short8 pf[8];
      #pragma unroll
      for (int kk = 0; kk < 8; ++kk) {
        const int byteoff = q32 * 256 + ((kk * 32 + hl * 16) ^ ((q32 & 7) << 4));
        pf[kk] = *(const short8*)((const char*)Pw + byteoff);
      }
      __builtin_amdgcn_s_setprio(1);
      #pragma unroll
      for (int d32 = 0; d32 < 2; ++d32) {
        const int dr = d32 * 32 + q32;
        const int vswz = ((dr & 7) ^ ((dr >> 3) & 7)) << 4;
        #pragma unroll
        for (int kk = 0; kk < 8; ++kk) {
          const int byteoff = dr * 256 + ((kk * 32 + hl * 16) ^ vswz);
          const short8 vf = *(const short8*)((const char*)Vt + byteoff);
          oacc[t32][d32] = __builtin_amdgcn_mfma_f32_32x32x16_bf16(vf, pf[kk], oacc[t32][d32], 0, 0, 0);
        }
      }
      __builtin_amdgcn_s_setprio(0);
    }
  }

  float* Ot = (float*)Pw;
  #pragma unroll
  for (int t32 = 0; t32 < 2; ++t32) {
    const float inv = 1.0f / l_[t32];
    #pragma unroll
    for (int d32 = 0; d32 < 2; ++d32) {
      #pragma unroll
      for (int r = 0; r < 16; ++r) {
        const int d = (r & 3) + 8 * (r >> 2) + 4 * hl;
        const int byteoff = q32 * 128 + ((4 * d) ^ ((q32 & 7) << 4));
        *(float*)((char*)Ot + byteoff) = oacc[t32][d32][r] * inv;
      }
      const int qr = lane >> 1, dc = (lane & 1) * 16;
      union { u16 s[16]; uint4 v[2]; } ob;
      #pragma unroll
      for (int cch = 0; cch < 4; ++cch) {
        const int byteoff = qr * 128 + ((4 * (dc + 4 * cch)) ^ ((qr & 7) << 4));
        const f32x4 vv = *(const f32x4*)((const char*)Ot + byteoff);
        ob.s[cch * 4 + 0] = f2bf(vv[0]);
        ob.s[cch * 4 + 1] = f2bf(vv[1]);
        ob.s[cch * 4 + 2] = f2bf(vv[2]);
        ob.s[cch * 4 + 3] = f2bf(vv[3]);
      }
      u16* orow = &o[(qbase + t32 * 32 + qr) * 5120 + hd * 64 + d32 * 32 + dc];
      *(uint4*)orow = ob.v[0];
      *(uint4*)(orow + 8) = ob.v[1];
    }
  }
}

extern "C" void kernel_launch(void* const* d_in, const int* in_sizes, int n_in,
                              void* d_out, int out_size, void* d_ws, size_t ws_size,
                              hipStream_t stream)
{
  const float* x    = (const float*)d_in[0];
  const float* ctx  = (const float*)d_in[1];
  const float* ng   = (const float*)d_in[2];
  const float* nb   = (const float*)d_in[3];
  const float* cg   = (const float*)d_in[4];
  const float* cb   = (const float*)d_in[5];
  const float* Wq   = (const float*)d_in[6];
  const float* Wkv  = (const float*)d_in[7];
  const float* Wo   = (const float*)d_in[8];
  const float* Wff1 = (const float*)d_in[9];
  const float* Wff2 = (const float*)d_in[10];

  u16* p = (u16*)d_ws;
  u16* WqT   = p; p += (size_t)1024 * 1024;
  u16* W2T   = p; p += (size_t)8192 * 1024;   // Wff1 interleaved
  u16* WkvT  = p; p += (size_t)128 * 1024;
  u16* WcT   = p; p += (size_t)1024 * 5120;
  u16* kvbuf = p; p += (size_t)4096 * 128;
  u16* aoh   = p; p += (size_t)4096 * 5120;
  u16* xn    = p; p += (size_t)4096 * 1024;
  u16* cn    = p; p += (size_t)4096 * 1024;
  u16* qbuf  = p; p += (size_t)4096 * 1024;
  u16* kvpart = W2T;   // 8 MB bf16 over W2T (dead after ff GEMM)
  u16* ffpart = xn;    // 32 MB bf16 over xn|cn|qbuf + tail (dead by final GEMM)
  (void)in_sizes; (void)n_in; (void)out_size; (void)ws_size;

  ln_kernel<<<8192, 256, 0, stream>>>(x, ctx, ng, nb, cg, cb, xn, cn);

  transpose_k<<<dim3(16, 16),  256, 0, stream>>>(Wq,   WqT,        1024, 1024, 1024, 0.125f);
  transpose_ff1<<<dim3(128, 16), 256, 0, stream>>>(Wff1, W2T);
  transpose_k<<<dim3(2, 16),   256, 0, stream>>>(Wkv,  WkvT,       1024, 128,  1024, 1.0f);
  transpose_k<<<dim3(16, 16),  256, 0, stream>>>(Wo,   WcT,        1024, 1024, 5120, 1.0f);
  transpose_k<<<dim3(16, 64),  256, 0, stream>>>(Wff2, WcT + 1024, 4096, 1024, 5120, 1.0f);

  // ff: aoh[:,1024:] = silu(xn @ Wff1), N=8192 -> 512 blocks = exact 2/CU pack
  gemm32_ff<<<dim3(512), 512, 0, stream>>>(xn, W2T, aoh, 4096, 8192, 1024);
  // q = xn @ WqT (scale folded), 128^2 tile, 256 blocks = 1 round
  gemm_bt_sk<<<dim3(8, 32, 1), 256, 0, stream>>>(xn, WqT, qbuf, 4096, 1024, 1024, 1024);
  // kv = cn @ Wkv, split-K 8 (bf16 partials over dead W2T), reduce to bf16
  gemm_bt_sk<<<dim3(1, 32, 8), 256, 0, stream>>>(cn, WkvT, kvpart, 4096, 128, 128, 1024);
  reduce_kv<<<256, 256, 0, stream>>>(kvpart, kvbuf);
  // attention -> aoh[:,0:1024]
  attn_kernel<<<dim3(32, 4, 2), 256, 0, stream>>>(qbuf, kvbuf, aoh);
  // out = aoh @ [Wo ; Wff2], split-K 4, bf16 partials
  gemm64_sk<<<dim3(64, 4), 512, 0, stream>>>(aoh, WcT, ffpart, 4096, 1024, 5120, 1280);
  reduce_out<<<2048, 256, 0, stream>>>(ffpart, (float*)d_out);
}

// Round 16
// 263.468 us; speedup vs baseline: 5.1885x; 1.0833x over previous
//
#include <hip/hip_runtime.h>
#include <stdint.h>

typedef unsigned short u16;
typedef __attribute__((ext_vector_type(8))) short short8;
typedef __attribute__((ext_vector_type(4))) float f32x4;
typedef __attribute__((ext_vector_type(16))) float f32x16;

#define GPTR(p) ((const __attribute__((address_space(1))) void*)(p))
#define SPTR(p) ((__attribute__((address_space(3))) void*)(p))
#define GLDS16(g, l) __builtin_amdgcn_global_load_lds(GPTR(g), SPTR(l), 16, 0, 0)

static __device__ __forceinline__ float bf2f(u16 u) {
  union { unsigned int i; float f; } c; c.i = ((unsigned int)u) << 16; return c.f;
}
static __device__ __forceinline__ u16 f2bf(float f) {
  union { float f; unsigned int u; } c; c.f = f;
  unsigned int r = 0x7fffu + ((c.u >> 16) & 1u);
  return (u16)((c.u + r) >> 16);
}
static __device__ __forceinline__ unsigned cvtpk(float a, float b) {
  unsigned r;
  asm volatile("v_cvt_pk_bf16_f32 %0, %1, %2" : "=v"(r) : "v"(a), "v"(b));
  return r;
}
static __device__ __forceinline__ int swz4(int row, int c) { return c ^ ((row >> 1) & 3); }

// ---------------- LayerNorm: f32 (rows of 1024) -> bf16 ----------------
__global__ __launch_bounds__(256) void ln_kernel(
    const float* __restrict__ x, const float* __restrict__ ctx,
    const float* __restrict__ g, const float* __restrict__ b,
    const float* __restrict__ cg, const float* __restrict__ cb,
    u16* __restrict__ xn, u16* __restrict__ cn)
{
  const int row = blockIdx.x;
  const float* src; const float* gg; const float* bb; u16* dst;
  if (row < 4096) { src = x + (size_t)row * 1024; gg = g;  bb = b;  dst = xn + (size_t)row * 1024; }
  else            { src = ctx + (size_t)(row - 4096) * 1024; gg = cg; bb = cb; dst = cn + (size_t)(row - 4096) * 1024; }
  const int t = threadIdx.x;
  float4 v = *(const float4*)&src[t * 4];
  float s  = v.x + v.y + v.z + v.w;
  float s2 = v.x * v.x + v.y * v.y + v.z * v.z + v.w * v.w;
  #pragma unroll
  for (int off = 1; off < 64; off <<= 1) { s += __shfl_xor(s, off); s2 += __shfl_xor(s2, off); }
  __shared__ float ls[4], ls2[4];
  const int w = t >> 6;
  if ((t & 63) == 0) { ls[w] = s; ls2[w] = s2; }
  __syncthreads();
  s  = ls[0] + ls[1] + ls[2] + ls[3];
  s2 = ls2[0] + ls2[1] + ls2[2] + ls2[3];
  const float mu   = s * (1.0f / 1024.0f);
  const float var  = s2 * (1.0f / 1024.0f) - mu * mu;
  const float rstd = rsqrtf(var + 1e-5f);
  float xv[4] = { v.x, v.y, v.z, v.w };
  u16 o[4];
  #pragma unroll
  for (int i = 0; i < 4; ++i)
    o[i] = f2bf((xv[i] - mu) * rstd * gg[t * 4 + i] + bb[t * 4 + i]);
  uint2 pv;
  pv.x = (unsigned)o[0] | ((unsigned)o[1] << 16);
  pv.y = (unsigned)o[2] | ((unsigned)o[3] << 16);
  *(uint2*)&dst[t * 4] = pv;
}

// ---------------- transpose+convert: f32 (R,C) -> bf16 (C,R) with out leading dim ----------------
__global__ __launch_bounds__(256) void transpose_k(
    const float* __restrict__ in, u16* __restrict__ out, int R, int C, int ldo, float scale)
{
  __shared__ float tile[64][65];
  const int c0 = blockIdx.x * 64, r0 = blockIdx.y * 64;
  const int t = threadIdx.x;
  const int tr = t >> 4, tc = (t & 15) * 4;
  #pragma unroll
  for (int i = 0; i < 4; ++i) {
    int r = tr + i * 16;
    float4 v = *(const float4*)&in[(size_t)(r0 + r) * C + c0 + tc];
    tile[r][tc + 0] = v.x; tile[r][tc + 1] = v.y; tile[r][tc + 2] = v.z; tile[r][tc + 3] = v.w;
  }
  __syncthreads();
  #pragma unroll
  for (int i = 0; i < 2; ++i) {
    int c  = (t >> 3) + i * 32;
    int rb = (t & 7) * 8;
    union { u16 s[8]; uint4 v; } pk;
    #pragma unroll
    for (int u = 0; u < 8; ++u) pk.s[u] = f2bf(tile[rb + u][c] * scale);
    *(uint4*)&out[(size_t)(c0 + c) * ldo + r0 + rb] = pk.v;
  }
}

// ---------------- Wff1 transpose with (a,gate) fragment interleave -> W2T (8192 rows) ----------------
__global__ __launch_bounds__(256) void transpose_ff1(
    const float* __restrict__ in, u16* __restrict__ out)
{
  __shared__ float tile[64][65];
  const int c0 = blockIdx.x * 64, r0 = blockIdx.y * 64;
  const int t = threadIdx.x;
  const int tr = t >> 4, tc = (t & 15) * 4;
  #pragma unroll
  for (int i = 0; i < 4; ++i) {
    int r = tr + i * 16;
    float4 v = *(const float4*)&in[(size_t)(r0 + r) * 8192 + c0 + tc];
    tile[r][tc + 0] = v.x; tile[r][tc + 1] = v.y; tile[r][tc + 2] = v.z; tile[r][tc + 3] = v.w;
  }
  __syncthreads();
  #pragma unroll
  for (int i = 0; i < 2; ++i) {
    int c  = (t >> 3) + i * 32;
    int rb = (t & 7) * 8;
    const int gc = c0 + c;
    int j, add16;
    if (gc < 4096) { j = gc; add16 = 0; } else { j = gc - 4096; add16 = 16; }
    const int row = ((j >> 7) << 8) + (((j >> 5) & 3) << 6) + (((j >> 4) & 1) << 5) + add16 + (j & 15);
    union { u16 s[8]; uint4 v; } pk;
    #pragma unroll
    for (int u = 0; u < 8; ++u) pk.s[u] = f2bf(tile[rb + u][c]);
    *(uint4*)&out[(size_t)row * 1024 + r0 + rb] = pk.v;
  }
}

// =============== BK=32 4-phase 256x256 GEMM (ff: N=8192, 512 blocks = exact 2/CU pack) ===============
#define MM32(MQ, M, NN) acc[MQ][M][NN] = __builtin_amdgcn_mfma_f32_16x16x32_bf16(af##M, bf##NN, acc[MQ][M][NN], 0, 0, 0)
#define MFMA16_32(MQ) \
  MM32(MQ,0,0); MM32(MQ,0,1); MM32(MQ,0,2); MM32(MQ,0,3); \
  MM32(MQ,1,0); MM32(MQ,1,1); MM32(MQ,1,2); MM32(MQ,1,3); \
  MM32(MQ,2,0); MM32(MQ,2,1); MM32(MQ,2,2); MM32(MQ,2,3); \
  MM32(MQ,3,0); MM32(MQ,3,1); MM32(MQ,3,2); MM32(MQ,3,3)

#define SA32(SBUF, H, KT) GLDS16(gA32[H] + ((size_t)(KT) << 5), SBUF + (size_t)((H) * 64 + w16o) * 32)
#define SB32(SBUF, H, KT) GLDS16(gB32[H] + ((size_t)(KT) << 5), SBUF + (size_t)((H) * 128 + w16o2) * 32)

#define DSB32(PB_) do { \
  bf0 = *(const short8*)(PB_ + 0    + cks); bf1 = *(const short8*)(PB_ + 512  + cks); \
  bf2 = *(const short8*)(PB_ + 1024 + cks); bf3 = *(const short8*)(PB_ + 1536 + cks); \
} while (0)

#define PC32(PA_, MQ, STAGE_STMT, GATE_STMT) do { \
  af0 = *(const short8*)(PA_ + (MQ) * 2048 + 0    + cks); \
  af1 = *(const short8*)(PA_ + (MQ) * 2048 + 512  + cks); \
  af2 = *(const short8*)(PA_ + (MQ) * 2048 + 1024 + cks); \
  af3 = *(const short8*)(PA_ + (MQ) * 2048 + 1536 + cks); \
  STAGE_STMT; \
  __builtin_amdgcn_s_barrier(); \
  asm volatile("s_waitcnt lgkmcnt(0)" ::: "memory"); \
  __builtin_amdgcn_s_setprio(1); \
  MFMA16_32(MQ); \
  __builtin_amdgcn_s_setprio(0); \
  GATE_STMT; \
  __builtin_amdgcn_s_barrier(); \
} while (0)

#define GATE3 asm volatile("s_waitcnt vmcnt(3)" ::: "memory")
#define GATE0 asm volatile("s_waitcnt vmcnt(0)" ::: "memory")

__global__ __launch_bounds__(512, 2) void gemm32_ff(
    const u16* __restrict__ A, const u16* __restrict__ BT, u16* __restrict__ Ho,
    int M, int N, int Ktot)
{
  __shared__ u16 sh[2][2][8192]; // 64 KB
  const int nbm = M >> 8;
  const int nwg = gridDim.x;
  const int bid = blockIdx.x;
  const int o = (bid & 7) * (nwg >> 3) + (bid >> 3);
  const int bm = o % nbm, bn = o / nbm;   // B-strip per XCD
  const int NI = Ktot >> 6;

  const int t = threadIdx.x, w = t >> 6, lane = t & 63;
  const int wr = w >> 2, wc = w & 3;
  const int lr = lane & 15, lg = lane >> 4;
  const int l4 = lane >> 2, sl = lane & 3;
  const int w16o  = w * 16 + ((w >= 4) ? 64 : 0);
  const int w16o2 = w * 16;

  const u16* gA32[2]; const u16* gB32[2];
  #pragma unroll
  for (int h = 0; h < 2; ++h) {
    const int rowA = h * 64 + w16o + l4;
    gA32[h] = A + (size_t)(bm * 256 + rowA) * Ktot + (size_t)((sl ^ ((rowA >> 1) & 3)) * 8);
    const int rowB = h * 128 + w16o2 + l4;
    gB32[h] = BT + (size_t)(bn * 256 + rowB) * Ktot + (size_t)((sl ^ ((rowB >> 1) & 3)) * 8);
  }
  u16* sA0 = &sh[0][0][0]; u16* sA1 = &sh[1][0][0];
  u16* sB0 = &sh[0][1][0]; u16* sB1 = &sh[1][1][0];
  const int cks = (lg ^ ((lr >> 1) & 3)) * 8;
  const u16* pA_b0 = sA0 + (wr * 128 + lr) * 32;
  const u16* pA_b1 = sA1 + (wr * 128 + lr) * 32;
  const u16* pB_b0 = sB0 + (wc * 64 + lr) * 32;
  const u16* pB_b1 = sB1 + (wc * 64 + lr) * 32;

  f32x4 acc[2][4][4];
  const f32x4 z4 = { 0.f, 0.f, 0.f, 0.f };
  #pragma unroll
  for (int a = 0; a < 2; ++a)
    #pragma unroll
    for (int b = 0; b < 4; ++b)
      #pragma unroll
      for (int c = 0; c < 4; ++c) acc[a][b][c] = z4;
  short8 af0, af1, af2, af3;
  short8 bf0, bf1, bf2, bf3;

  SA32(sA0, 0, 0); SA32(sA0, 1, 0); SB32(sB0, 0, 0); SB32(sB0, 1, 0);
  SB32(sB1, 0, 1); SB32(sB1, 1, 1); SA32(sA1, 0, 1);
  GATE3;
  __builtin_amdgcn_s_barrier();

  for (int i = 0; i < NI; ++i) {
    const bool st = (i < NI - 1);
    const int X = 2 * i + 2, Y = 2 * i + 3;
    DSB32(pB_b0);
    PC32(pA_b0, 0, SA32(sA1, 1, 2 * i + 1), );
    PC32(pA_b0, 1,
         if (st) { SB32(sB0, 0, X); SB32(sB0, 1, X); SA32(sA0, 0, X); },
         if (st) { GATE3; } else { GATE0; });
    DSB32(pB_b1);
    PC32(pA_b1, 0, if (st) { SA32(sA0, 1, X); }, );
    PC32(pA_b1, 1,
         if (st) { SB32(sB1, 0, Y); SB32(sB1, 1, Y); SA32(sA1, 0, Y); },
         if (st) { GATE3; });
  }

  // silu(gate)*a pair-fused epilogue -> aoh cols 1024 + bn*128 .. (stride 5120)
  const int colb = 1024 + bn * 128 + wc * 32 + lr;
  #pragma unroll
  for (int mq = 0; mq < 2; ++mq)
    #pragma unroll
    for (int m = 0; m < 4; ++m)
      #pragma unroll
      for (int rr = 0; rr < 4; ++rr) {
        const int row = bm * 256 + wr * 128 + mq * 64 + m * 16 + lg * 4 + rr;
        #pragma unroll
        for (int n2 = 0; n2 < 2; ++n2) {
          const float a = acc[mq][m][2 * n2][rr];
          const float gt = acc[mq][m][2 * n2 + 1][rr];
          const float h = a * gt / (1.0f + __expf(-gt));
          Ho[(size_t)row * 5120 + colb + n2 * 16] = f2bf(h);
        }
      }
}

// =============== BK=64 8-phase 256x256 GEMM (final GEMM, split-K 4, bf16 partials) ===============
#define MM1(MQ, M, NN, BF) acc[MQ][M][NN] = __builtin_amdgcn_mfma_f32_16x16x32_bf16(af##M, BF, acc[MQ][M][NN], 0, 0, 0)
#define MFMA16(MQ, KS) \
  MM1(MQ,0,0,bf##KS##0); MM1(MQ,0,1,bf##KS##1); MM1(MQ,0,2,bf##KS##2); MM1(MQ,0,3,bf##KS##3); \
  MM1(MQ,1,0,bf##KS##0); MM1(MQ,1,1,bf##KS##1); MM1(MQ,1,2,bf##KS##2); MM1(MQ,1,3,bf##KS##3); \
  MM1(MQ,2,0,bf##KS##0); MM1(MQ,2,1,bf##KS##1); MM1(MQ,2,2,bf##KS##2); MM1(MQ,2,3,bf##KS##3); \
  MM1(MQ,3,0,bf##KS##0); MM1(MQ,3,1,bf##KS##1); MM1(MQ,3,2,bf##KS##2); MM1(MQ,3,3,bf##KS##3)

#define SG_A(SBUF, H, KT) do { \
    GLDS16(gA[H][0] + ((size_t)(KT) << 6), SBUF + ((H) * 64 + w16o) * 64); \
    GLDS16(gA[H][1] + ((size_t)(KT) << 6), SBUF + ((H) * 64 + w16o + 8) * 64); \
  } while (0)
#define SG_B(SBUF, H, KT) do { \
    GLDS16(gB[H][0] + ((size_t)(KT) << 6), SBUF + ((H) * 128 + w16o2) * 64); \
    GLDS16(gB[H][1] + ((size_t)(KT) << 6), SBUF + ((H) * 128 + w16o2 + 8) * 64); \
  } while (0)

#define DS_B(PB_) do { \
  bf00 = *(const short8*)(PB_ + 0    + cks0); bf01 = *(const short8*)(PB_ + 1024 + cks0); \
  bf02 = *(const short8*)(PB_ + 2048 + cks0); bf03 = *(const short8*)(PB_ + 3072 + cks0); \
  bf10 = *(const short8*)(PB_ + 0    + cks1); bf11 = *(const short8*)(PB_ + 1024 + cks1); \
  bf12 = *(const short8*)(PB_ + 2048 + cks1); bf13 = *(const short8*)(PB_ + 3072 + cks1); \
} while (0)

#define P_CORE(PA_, MQ, KS, STAGE_STMT, PREB_STMT, GATE_STMT) do { \
  af0 = *(const short8*)(PA_ + (MQ) * 4096 + 0    + cks##KS); \
  af1 = *(const short8*)(PA_ + (MQ) * 4096 + 1024 + cks##KS); \
  af2 = *(const short8*)(PA_ + (MQ) * 4096 + 2048 + cks##KS); \
  af3 = *(const short8*)(PA_ + (MQ) * 4096 + 3072 + cks##KS); \
  STAGE_STMT; \
  PREB_STMT; \
  __builtin_amdgcn_s_barrier(); \
  asm volatile("s_waitcnt lgkmcnt(0)" ::: "memory"); \
  __builtin_amdgcn_s_setprio(1); \
  MFMA16(MQ, KS); \
  __builtin_amdgcn_s_setprio(0); \
  GATE_STMT; \
  __builtin_amdgcn_s_barrier(); \
} while (0)

#define GATE6 asm volatile("s_waitcnt vmcnt(6)" ::: "memory")
#define HINT8 asm volatile("s_waitcnt lgkmcnt(8)" ::: "memory")

__global__ __launch_bounds__(512, 2) void gemm64_sk(
    const u16* __restrict__ A, const u16* __restrict__ BT, u16* __restrict__ C,
    int M, int N, int Ktot, int Kslice)
{
  __shared__ u16 sh[2][2][16384]; // 128 KB
  const int nbn = N >> 8;
  const int nwg = gridDim.x;
  const int bid = blockIdx.x;
  const int o = (bid & 7) * (nwg >> 3) + (bid >> 3);
  const int bn = o % nbn, bm = o / nbn;   // A-panels per XCD
  const int kbase = blockIdx.y * Kslice;
  const int NI = Kslice >> 7;

  const int t = threadIdx.x, w = t >> 6, lane = t & 63;
  const int wr = w >> 2, wc = w & 3;
  const int lr = lane & 15, lg = lane >> 4;
  const int r8 = lane >> 3, ch = lane & 7;
  const int clog = ch ^ r8;
  const int w16o  = w * 16 + ((w >= 4) ? 64 : 0);
  const int w16o2 = w * 16;

  const u16* gA[2][2]; const u16* gB[2][2];
  #pragma unroll
  for (int h = 0; h < 2; ++h)
    #pragma unroll
    for (int qq = 0; qq < 2; ++qq) {
      gA[h][qq] = A  + (size_t)(bm * 256 + h * 64  + w16o  + qq * 8 + r8) * Ktot + kbase + clog * 8;
      gB[h][qq] = BT + (size_t)(bn * 256 + h * 128 + w16o2 + qq * 8 + r8) * Ktot + kbase + clog * 8;
    }
  u16* sA0 = &sh[0][0][0]; u16* sA1 = &sh[1][0][0];
  u16* sB0 = &sh[0][1][0]; u16* sB1 = &sh[1][1][0];
  const int cks0 = ((0 + lg) ^ (lr & 7)) * 8;
  const int cks1 = ((4 + lg) ^ (lr & 7)) * 8;
  const u16* pA_b0 = sA0 + (wr * 128 + lr) * 64;
  const u16* pA_b1 = sA1 + (wr * 128 + lr) * 64;
  const u16* pB_b0 = sB0 + (wc * 64 + lr) * 64;
  const u16* pB_b1 = sB1 + (wc * 64 + lr) * 64;

  f32x4 acc[2][4][4];
  const f32x4 z4 = { 0.f, 0.f, 0.f, 0.f };
  #pragma unroll
  for (int a = 0; a < 2; ++a)
    #pragma unroll
    for (int b = 0; b < 4; ++b)
      #pragma unroll
      for (int c = 0; c < 4; ++c) acc[a][b][c] = z4;
  short8 af0, af1, af2, af3;
  short8 bf00, bf01, bf02, bf03, bf10, bf11, bf12, bf13;

  SG_B(sB0, 0, 0); SG_B(sB0, 1, 0); SG_A(sA0, 0, 0); SG_A(sA0, 1, 0);
  SG_B(sB1, 0, 1); SG_B(sB1, 1, 1); SG_A(sA1, 0, 1);
  GATE6;
  __builtin_amdgcn_s_barrier();

  for (int i = 0; i < NI; ++i) {
    const int k2 = 2 * i;
    const bool st = (i < NI - 1);
    DS_B(pB_b0);
    P_CORE(pA_b0, 0, 0, SG_A(sA1, 1, k2 + 1), HINT8, );
    P_CORE(pA_b0, 1, 0, if (st) SG_B(sB0, 0, k2 + 2), , );
    P_CORE(pA_b0, 0, 1, if (st) SG_B(sB0, 1, k2 + 2), , );
    P_CORE(pA_b0, 1, 1, if (st) SG_A(sA0, 0, k2 + 2), ,
           if (st) { GATE6; } else { GATE0; });
    DS_B(pB_b1);
    P_CORE(pA_b1, 0, 0, if (st) SG_A(sA0, 1, k2 + 2), HINT8, );
    P_CORE(pA_b1, 1, 0, if (st) SG_B(sB1, 0, k2 + 3), , );
    P_CORE(pA_b1, 0, 1, if (st) SG_B(sB1, 1, k2 + 3), , );
    P_CORE(pA_b1, 1, 1, if (st) SG_A(sA1, 0, k2 + 3), ,
           if (st) { GATE6; });
  }

  u16* Co = C + (size_t)blockIdx.y * M * N;
  #pragma unroll
  for (int mq = 0; mq < 2; ++mq)
    #pragma unroll
    for (int m = 0; m < 4; ++m)
      #pragma unroll
      for (int n = 0; n < 4; ++n)
        #pragma unroll
        for (int rr = 0; rr < 4; ++rr) {
          const int row = bm * 256 + wr * 128 + mq * 64 + m * 16 + lg * 4 + rr;
          const int col = bn * 256 + wc * 64 + n * 16 + lr;
          Co[(size_t)row * N + col] = f2bf(acc[mq][m][n][rr]);
        }
}

// ---------------- split-K / plain GEMM 128x128, bf16 out (q projection + kv projection) ----------------
__global__ __launch_bounds__(256) void gemm_bt_sk(
    const u16* __restrict__ A, const u16* __restrict__ BT, u16* __restrict__ Cp,
    int M, int N, int Kslice, int Ktot)
{
  __shared__ u16 As[128 * 32];
  __shared__ u16 Bs[128 * 32];
  const int bm = blockIdx.y, bn = blockIdx.x, z = blockIdx.z;
  const int t = threadIdx.x;
  const int w = t >> 6, lane = t & 63;
  const int wr = w >> 1, wc = w & 1;
  const int lr = lane & 15, lkc = lane >> 4;

  f32x4 acc[4][4];
  const f32x4 z4 = { 0.f, 0.f, 0.f, 0.f };
  #pragma unroll
  for (int mi = 0; mi < 4; ++mi)
    #pragma unroll
    for (int ni = 0; ni < 4; ++ni) acc[mi][ni] = z4;

  const int kbase = z * Kslice;
  const int i0 = t, i1 = t + 256;
  const int r0 = i0 >> 2, k0 = swz4(r0, i0 & 3) * 8;
  const int r1 = i1 >> 2, k1 = swz4(r1, i1 & 3) * 8;
  const u16* a0 = A + (size_t)(bm * 128 + r0) * Ktot + kbase + k0;
  const u16* a1 = A + (size_t)(bm * 128 + r1) * Ktot + kbase + k1;
  const u16* b0 = BT + (size_t)(bn * 128 + r0) * Ktot + kbase + k0;
  const u16* b1 = BT + (size_t)(bn * 128 + r1) * Ktot + kbase + k1;
  u16* As0 = As + (size_t)w * 512;
  u16* As1 = As + (size_t)(w + 4) * 512;
  u16* Bs0 = Bs + (size_t)w * 512;
  u16* Bs1 = Bs + (size_t)(w + 4) * 512;

  const int nk = Kslice >> 5;
  for (int kt = 0; kt < nk; ++kt) {
    __syncthreads();
    GLDS16(a0, As0); GLDS16(a1, As1); GLDS16(b0, Bs0); GLDS16(b1, Bs1);
    a0 += 32; a1 += 32; b0 += 32; b1 += 32;
    __syncthreads();
    short8 af[4], bf[4];
    #pragma unroll
    for (int mi = 0; mi < 4; ++mi) {
      int row = wr * 64 + mi * 16 + lr;
      af[mi] = *(const short8*)&As[row * 32 + swz4(row, lkc) * 8];
    }
    #pragma unroll
    for (int ni = 0; ni < 4; ++ni) {
      int row = wc * 64 + ni * 16 + lr;
      bf[ni] = *(const short8*)&Bs[row * 32 + swz4(row, lkc) * 8];
    }
    #pragma unroll
    for (int mi = 0; mi < 4; ++mi)
      #pragma unroll
      for (int ni = 0; ni < 4; ++ni)
        acc[mi][ni] = __builtin_amdgcn_mfma_f32_16x16x32_bf16(af[mi], bf[ni], acc[mi][ni], 0, 0, 0);
  }

  u16* Cz = Cp + (size_t)z * M * N;
  const int row0 = bm * 128 + wr * 64, col0 = bn * 128 + wc * 64;
  const int rsub = (lane >> 4) * 4;
  #pragma unroll
  for (int mi = 0; mi < 4; ++mi)
    #pragma unroll
    for (int ni = 0; ni < 4; ++ni)
      #pragma unroll
      for (int r = 0; r < 4; ++r)
        Cz[(size_t)(row0 + mi * 16 + rsub + r) * N + (col0 + ni * 16 + lr)] = f2bf(acc[mi][ni][r]);
}

// ---------------- reduce 8 bf16 partials (4096x128) -> bf16 ----------------
__global__ __launch_bounds__(256) void reduce_kv(const u16* __restrict__ part, u16* __restrict__ out)
{
  const size_t base = ((size_t)blockIdx.x * 256 + threadIdx.x) * 8;
  float s[8] = { 0.f, 0.f, 0.f, 0.f, 0.f, 0.f, 0.f, 0.f };
  #pragma unroll
  for (int zz = 0; zz < 8; ++zz) {
    const short8 v = *(const short8*)&part[(size_t)zz * 524288 + base];
    #pragma unroll
    for (int i = 0; i < 8; ++i) s[i] += bf2f((u16)v[i]);
  }
  union { u16 o[8]; uint4 v; } pk;
  #pragma unroll
  for (int i = 0; i < 8; ++i) pk.o[i] = f2bf(s[i]);
  *(uint4*)&out[base] = pk.v;
}

// ---------------- out = sum of 4 bf16 partials (4096x1024) -> f32 ----------------
__global__ __launch_bounds__(256) void reduce_out(const u16* __restrict__ part, float* __restrict__ out)
{
  const size_t base = ((size_t)blockIdx.x * 256 + threadIdx.x) * 8;
  float s[8] = { 0.f, 0.f, 0.f, 0.f, 0.f, 0.f, 0.f, 0.f };
  #pragma unroll
  for (int zz = 0; zz < 4; ++zz) {
    const short8 v = *(const short8*)&part[(size_t)zz * 4194304 + base];
    #pragma unroll
    for (int i = 0; i < 8; ++i) s[i] += bf2f((u16)v[i]);
  }
  f32x4 lo = { s[0], s[1], s[2], s[3] };
  f32x4 hi = { s[4], s[5], s[6], s[7] };
  *(f32x4*)&out[base] = lo;
  *(f32x4*)&out[base + 4] = hi;
}

// ---------------- flash cross-attention (multi-query: 1 KV head) ----------------
// 8 waves x 512 threads, 256 blocks: wave w -> head hb*4+(w>>1), q-half w&1 (32 rows).
// Staging per block unchanged (split across 8 waves); 2 waves/SIMD for TLP.
// T13 defer-max, T14 V-prefetch (vhold[2], gate vmcnt(2)), T5 setprio.
__global__ __launch_bounds__(512, 1) void attn_kernel(
    const u16* __restrict__ q, const u16* __restrict__ kv, u16* __restrict__ o)
{
  __shared__ u16 Ks[128 * 64];
  __shared__ u16 Vt[64 * 128];
  __shared__ u16 Ps[8][32 * 128];
  const int b = blockIdx.z, hb = blockIdx.y, qb = blockIdx.x;
  const int t = threadIdx.x, w = t >> 6, lane = t & 63;
  const int q32 = lane & 31, hl = lane >> 5;
  const int hd = hb * 4 + (w >> 1);
  const int t32 = w & 1;

  const size_t qbase = (size_t)b * 2048 + qb * 64;
  short8 qa[4];
  #pragma unroll
  for (int dq = 0; dq < 4; ++dq)
    qa[dq] = *(const short8*)&q[(qbase + t32 * 32 + q32) * 1024 + hd * 64 + dq * 16 + hl * 8];

  f32x16 oacc[2];
  #pragma unroll
  for (int j = 0; j < 2; ++j)
    #pragma unroll
    for (int r = 0; r < 16; ++r) oacc[j][r] = 0.f;
  float m_ = -1e30f, l_ = 0.f;

  const size_t kvb = (size_t)b * 2048 * 128;
  const int vd0 = (t & 7) * 8;
  const int vodd = (t >> 3) & 1;
  u16* Pw = &Ps[w][0];

  // T14 prologue: V(0) into held regs (2 per thread @ 512 threads)
  uint4 vhold[2];
  #pragma unroll
  for (int c = 0; c < 2; ++c) {
    const int vj = (c * 512 + t) >> 3;
    vhold[c] = *(const uint4*)&kv[kvb + (size_t)vj * 128 + 64 + vd0];
  }

  for (int jt = 0; jt < 16; ++jt) {
    __syncthreads();
    // stage K(jt) via GLDS: 2 wave-loads per wave (16 total = 16KB)
    #pragma unroll
    for (int n = 0; n < 2; ++n) {
      const int cc = n * 512 + w * 64;
      const int ccl = cc + lane;
      const int row = ccl >> 3, lc = (ccl & 7) ^ (row & 7);
      GLDS16(&kv[kvb + (size_t)(jt * 128 + row) * 128 + lc * 8], Ks + (size_t)cc * 8);
    }
    // write V(jt) from held regs (shfl pair-exchange + packed b32, swizzled)
    #pragma unroll
    for (int c = 0; c < 2; ++c) {
      const int seg = c * 512 + t;
      const int vj = seg >> 3;
      const int jp = vj >> 1;
      const uint4 vv = vhold[c];
      uint4 pvv;
      pvv.x = __shfl_xor((int)vv.x, 8);
      pvv.y = __shfl_xor((int)vv.y, 8);
      pvv.z = __shfl_xor((int)vv.z, 8);
      pvv.w = __shfl_xor((int)vv.w, 8);
      const unsigned ow[4] = { vv.x, vv.y, vv.z, vv.w };
      const unsigned pw[4] = { pvv.x, pvv.y, pvv.z, pvv.w };
      if (!vodd) {
        #pragma unroll
        for (int u = 0; u < 4; ++u) {
          const int d = vd0 + u;
          const unsigned own = (u & 1) ? (ow[u >> 1] >> 16) : (ow[u >> 1] & 0xffffu);
          const unsigned par = (u & 1) ? (pw[u >> 1] >> 16) : (pw[u >> 1] & 0xffffu);
          const int byteoff = d * 256 + ((4 * jp) ^ (((d & 7) ^ ((d >> 3) & 7)) << 4));
          *(unsigned*)((char*)Vt + byteoff) = own | (par << 16);
        }
      } else {
        #pragma unroll
        for (int u = 0; u < 4; ++u) {
          const int ue = u + 4;
          const int d = vd0 + ue;
          const unsigned own = (ue & 1) ? (ow[ue >> 1] >> 16) : (ow[ue >> 1] & 0xffffu);
          const unsigned par = (ue & 1) ? (pw[ue >> 1] >> 16) : (pw[ue >> 1] & 0xffffu);
          const int byteoff = d * 256 + ((4 * jp) ^ (((d & 7) ^ ((d >> 3) & 7)) << 4));
          *(unsigned*)((char*)Vt + byteoff) = par | (own << 16);
        }
      }
    }
    __builtin_amdgcn_sched_barrier(0);
    if (jt < 15) {
      #pragma unroll
      for (int c = 0; c < 2; ++c) {
        const int vj = (c * 512 + t) >> 3;
        vhold[c] = *(const uint4*)&kv[kvb + (size_t)((jt + 1) * 128 + vj) * 128 + 64 + vd0];
      }
      asm volatile("s_waitcnt vmcnt(2) lgkmcnt(0)" ::: "memory"); // K done + Vt writes done; V(jt+1) in flight
    } else {
      asm volatile("s_waitcnt vmcnt(0) lgkmcnt(0)" ::: "memory");
    }
    __builtin_amdgcn_s_barrier();
    __builtin_amdgcn_sched_barrier(0);

    // ----- compute (this wave's 32 q-rows) -----
    f32x16 s[4];
    #pragma unroll
    for (int j32 = 0; j32 < 4; ++j32)
      #pragma unroll
      for (int r = 0; r < 16; ++r) s[j32][r] = 0.f;
    __builtin_amdgcn_s_setprio(1);
    #pragma unroll
    for (int j32 = 0; j32 < 4; ++j32) {
      const int row = j32 * 32 + q32;
      #pragma unroll
      for (int dq = 0; dq < 4; ++dq) {
        const int slot = (dq * 2 + hl) ^ (row & 7);
        const short8 kf = *(const short8*)&Ks[row * 64 + slot * 8];
        s[j32] = __builtin_amdgcn_mfma_f32_32x32x16_bf16(kf, qa[dq], s[j32], 0, 0, 0);
      }
    }
    __builtin_amdgcn_s_setprio(0);
    float mt = -1e30f;
    #pragma unroll
    for (int j32 = 0; j32 < 4; ++j32)
      #pragma unroll
      for (int r = 0; r < 16; ++r) mt = fmaxf(mt, s[j32][r]);
    mt = fmaxf(mt, __shfl_xor(mt, 32));
    const bool noresc = (bool)__all(mt <= m_ + 8.0f);
    float nm = m_;
    if (!noresc) {
      nm = fmaxf(m_, mt);
      const float alpha = __expf(m_ - nm);
      m_ = nm;
      l_ *= alpha;
      #pragma unroll
      for (int d32 = 0; d32 < 2; ++d32)
        #pragma unroll
        for (int r = 0; r < 16; ++r) oacc[d32][r] *= alpha;
    }
    float lsum = 0.f;
    #pragma unroll
    for (int j32 = 0; j32 < 4; ++j32) {
      float p[16];
      #pragma unroll
      for (int r = 0; r < 16; ++r) { p[r] = __expf(s[j32][r] - nm); lsum += p[r]; }
      #pragma unroll
      for (int g = 0; g < 4; ++g) {
        const unsigned lo = cvtpk(p[4 * g + 0], p[4 * g + 1]);
        const unsigned hi = cvtpk(p[4 * g + 2], p[4 * g + 3]);
        const int j2 = j32 * 64 + 16 * g + 8 * hl;
        const int byteoff = q32 * 256 + (j2 ^ ((q32 & 7) << 4));
        uint2 wv; wv.x = lo; wv.y = hi;
        *(uint2*)((char*)Pw + byteoff) = wv;
      }
    }
    lsum += __shfl_xor(lsum, 32);
    l_ += lsum;
    short8 pf[8];
    #pragma unroll
    for (int kk = 0; kk < 8; ++kk) {
      const int byteoff = q32 * 256 + ((kk * 32 + hl * 16) ^ ((q32 & 7) << 4));
      pf[kk] = *(const short8*)((const char*)Pw + byteoff);
    }
    __builtin_amdgcn_s_setprio(1);
    #pragma unroll
    for (int d32 = 0; d32 < 2; ++d32) {
      const int dr = d32 * 32 + q32;
      const int vswz = ((dr & 7) ^ ((dr >> 3) & 7)) << 4;
      #pragma unroll
      for (int kk = 0; kk < 8; ++kk) {
        const int byteoff = dr * 256 + ((kk * 32 + hl * 16) ^ vswz);
        const short8 vf = *(const short8*)((const char*)Vt + byteoff);
        oacc[d32] = __builtin_amdgcn_mfma_f32_32x32x16_bf16(vf, pf[kk], oacc[d32], 0, 0, 0);
      }
    }
    __builtin_amdgcn_s_setprio(0);
  }

  // epilogue: normalize, transpose O^T -> O via wave-private Pw, store bf16
  float* Ot = (float*)Pw;
  const float inv = 1.0f / l_;
  #pragma unroll
  for (int d32 = 0; d32 < 2; ++d32) {
    #pragma unroll
    for (int r = 0; r < 16; ++r) {
      const int d = (r & 3) + 8 * (r >> 2) + 4 * hl;
      const int byteoff = q32 * 128 + ((4 * d) ^ ((q32 & 7) << 4));
      *(float*)((char*)Ot + byteoff) = oacc[d32][r] * inv;
    }
    const int qr = lane >> 1, dc = (lane & 1) * 16;
    union { u16 s[16]; uint4 v[2]; } ob;
    #pragma unroll
    for (int cch = 0; cch < 4; ++cch) {
      const int byteoff = qr * 128 + ((4 * (dc + 4 * cch)) ^ ((qr & 7) << 4));
      const f32x4 vv = *(const f32x4*)((const char*)Ot + byteoff);
      ob.s[cch * 4 + 0] = f2bf(vv[0]);
      ob.s[cch * 4 + 1] = f2bf(vv[1]);
      ob.s[cch * 4 + 2] = f2bf(vv[2]);
      ob.s[cch * 4 + 3] = f2bf(vv[3]);
    }
    u16* orow = &o[(qbase + t32 * 32 + qr) * 5120 + hd * 64 + d32 * 32 + dc];
    *(uint4*)orow = ob.v[0];
    *(uint4*)(orow + 8) = ob.v[1];
  }
}

extern "C" void kernel_launch(void* const* d_in, const int* in_sizes, int n_in,
                              void* d_out, int out_size, void* d_ws, size_t ws_size,
                              hipStream_t stream)
{
  const float* x    = (const float*)d_in[0];
  const float* ctx  = (const float*)d_in[1];
  const float* ng   = (const float*)d_in[2];
  const float* nb   = (const float*)d_in[3];
  const float* cg   = (const float*)d_in[4];
  const float* cb   = (const float*)d_in[5];
  const float* Wq   = (const float*)d_in[6];
  const float* Wkv  = (const float*)d_in[7];
  const float* Wo   = (const float*)d_in[8];
  const float* Wff1 = (const float*)d_in[9];
  const float* Wff2 = (const float*)d_in[10];

  u16* p = (u16*)d_ws;
  u16* WqT   = p; p += (size_t)1024 * 1024;
  u16* W2T   = p; p += (size_t)8192 * 1024;   // Wff1 interleaved
  u16* WkvT  = p; p += (size_t)128 * 1024;
  u16* WcT   = p; p += (size_t)1024 * 5120;
  u16* kvbuf = p; p += (size_t)4096 * 128;
  u16* aoh   = p; p += (size_t)4096 * 5120;
  u16* xn    = p; p += (size_t)4096 * 1024;
  u16* cn    = p; p += (size_t)4096 * 1024;
  u16* qbuf  = p; p += (size_t)4096 * 1024;
  u16* kvpart = W2T;   // 8 MB bf16 over W2T (dead after ff GEMM)
  u16* ffpart = xn;    // 32 MB bf16 over xn|cn|qbuf + tail (dead by final GEMM)
  (void)in_sizes; (void)n_in; (void)out_size; (void)ws_size;

  ln_kernel<<<8192, 256, 0, stream>>>(x, ctx, ng, nb, cg, cb, xn, cn);

  transpose_k<<<dim3(16, 16),  256, 0, stream>>>(Wq,   WqT,        1024, 1024, 1024, 0.125f);
  transpose_ff1<<<dim3(128, 16), 256, 0, stream>>>(Wff1, W2T);
  transpose_k<<<dim3(2, 16),   256, 0, stream>>>(Wkv,  WkvT,       1024, 128,  1024, 1.0f);
  transpose_k<<<dim3(16, 16),  256, 0, stream>>>(Wo,   WcT,        1024, 1024, 5120, 1.0f);
  transpose_k<<<dim3(16, 64),  256, 0, stream>>>(Wff2, WcT + 1024, 4096, 1024, 5120, 1.0f);

  // ff: aoh[:,1024:] = silu(xn @ Wff1), N=8192 -> 512 blocks = exact 2/CU pack
  gemm32_ff<<<dim3(512), 512, 0, stream>>>(xn, W2T, aoh, 4096, 8192, 1024);
  // q = xn @ WqT (scale folded), 128^2 tile, 256 blocks = 1 round
  gemm_bt_sk<<<dim3(8, 32, 1), 256, 0, stream>>>(xn, WqT, qbuf, 4096, 1024, 1024, 1024);
  // kv = cn @ Wkv, split-K 8 (bf16 partials over dead W2T), reduce to bf16
  gemm_bt_sk<<<dim3(1, 32, 8), 256, 0, stream>>>(cn, WkvT, kvpart, 4096, 128, 128, 1024);
  reduce_kv<<<256, 256, 0, stream>>>(kvpart, kvbuf);
  // attention -> aoh[:,0:1024]; 8 waves/block (2/SIMD TLP), staging unchanged
  attn_kernel<<<dim3(32, 4, 2), 512, 0, stream>>>(qbuf, kvbuf, aoh);
  // out = aoh @ [Wo ; Wff2], split-K 4, bf16 partials
  gemm64_sk<<<dim3(64, 4), 512, 0, stream>>>(aoh, WcT, ffpart, 4096, 1024, 5120, 1280);
  reduce_out<<<2048, 256, 0, stream>>>(ffpart, (float*)d_out);
}

// Round 17
// 250.656 us; speedup vs baseline: 5.4537x; 1.0511x over previous
//
#include <hip/hip_runtime.h>
#include <stdint.h>

typedef unsigned short u16;
typedef __attribute__((ext_vector_type(8))) short short8;
typedef __attribute__((ext_vector_type(4))) float f32x4;
typedef __attribute__((ext_vector_type(16))) float f32x16;

#define GPTR(p) ((const __attribute__((address_space(1))) void*)(p))
#define SPTR(p) ((__attribute__((address_space(3))) void*)(p))
#define GLDS16(g, l) __builtin_amdgcn_global_load_lds(GPTR(g), SPTR(l), 16, 0, 0)

static __device__ __forceinline__ float bf2f(u16 u) {
  union { unsigned int i; float f; } c; c.i = ((unsigned int)u) << 16; return c.f;
}
static __device__ __forceinline__ u16 f2bf(float f) {
  union { float f; unsigned int u; } c; c.f = f;
  unsigned int r = 0x7fffu + ((c.u >> 16) & 1u);
  return (u16)((c.u + r) >> 16);
}
static __device__ __forceinline__ unsigned cvtpk(float a, float b) {
  unsigned r;
  asm volatile("v_cvt_pk_bf16_f32 %0, %1, %2" : "=v"(r) : "v"(a), "v"(b));
  return r;
}
static __device__ __forceinline__ int swz4(int row, int c) { return c ^ ((row >> 1) & 3); }

// ---------------- LayerNorm: f32 (rows of 1024) -> bf16 ----------------
__global__ __launch_bounds__(256) void ln_kernel(
    const float* __restrict__ x, const float* __restrict__ ctx,
    const float* __restrict__ g, const float* __restrict__ b,
    const float* __restrict__ cg, const float* __restrict__ cb,
    u16* __restrict__ xn, u16* __restrict__ cn)
{
  const int row = blockIdx.x;
  const float* src; const float* gg; const float* bb; u16* dst;
  if (row < 4096) { src = x + (size_t)row * 1024; gg = g;  bb = b;  dst = xn + (size_t)row * 1024; }
  else            { src = ctx + (size_t)(row - 4096) * 1024; gg = cg; bb = cb; dst = cn + (size_t)(row - 4096) * 1024; }
  const int t = threadIdx.x;
  float4 v = *(const float4*)&src[t * 4];
  float s  = v.x + v.y + v.z + v.w;
  float s2 = v.x * v.x + v.y * v.y + v.z * v.z + v.w * v.w;
  #pragma unroll
  for (int off = 1; off < 64; off <<= 1) { s += __shfl_xor(s, off); s2 += __shfl_xor(s2, off); }
  __shared__ float ls[4], ls2[4];
  const int w = t >> 6;
  if ((t & 63) == 0) { ls[w] = s; ls2[w] = s2; }
  __syncthreads();
  s  = ls[0] + ls[1] + ls[2] + ls[3];
  s2 = ls2[0] + ls2[1] + ls2[2] + ls2[3];
  const float mu   = s * (1.0f / 1024.0f);
  const float var  = s2 * (1.0f / 1024.0f) - mu * mu;
  const float rstd = rsqrtf(var + 1e-5f);
  float xv[4] = { v.x, v.y, v.z, v.w };
  u16 o[4];
  #pragma unroll
  for (int i = 0; i < 4; ++i)
    o[i] = f2bf((xv[i] - mu) * rstd * gg[t * 4 + i] + bb[t * 4 + i]);
  uint2 pv;
  pv.x = (unsigned)o[0] | ((unsigned)o[1] << 16);
  pv.y = (unsigned)o[2] | ((unsigned)o[3] << 16);
  *(uint2*)&dst[t * 4] = pv;
}

// ---------------- merged transpose: Wq, Wkv, Wo, Wff2 in one dispatch ----------------
// blocks 0..255 Wq -> WqT (scale 0.125); 256..287 Wkv -> WkvT; 288..543 Wo -> WcT;
// 544..1567 Wff2 -> WcT+1024 (ldo 5120).
__global__ __launch_bounds__(256) void transpose_all(
    const float* __restrict__ Wq, const float* __restrict__ Wkv,
    const float* __restrict__ Wo, const float* __restrict__ Wff2,
    u16* __restrict__ WqT, u16* __restrict__ WkvT, u16* __restrict__ WcT)
{
  int id = blockIdx.x;
  const float* in; u16* out; int C, ldo, cx; float scale;
  if (id < 256)      {           in = Wq;   out = WqT;        C = 1024; ldo = 1024; scale = 0.125f; cx = 16; }
  else if (id < 288) { id -= 256; in = Wkv;  out = WkvT;       C = 128;  ldo = 1024; scale = 1.0f;   cx = 2;  }
  else if (id < 544) { id -= 288; in = Wo;   out = WcT;        C = 1024; ldo = 5120; scale = 1.0f;   cx = 16; }
  else               { id -= 544; in = Wff2; out = WcT + 1024; C = 1024; ldo = 5120; scale = 1.0f;   cx = 16; }
  const int c0 = (id % cx) * 64, r0 = (id / cx) * 64;

  __shared__ float tile[64][65];
  const int t = threadIdx.x;
  const int tr = t >> 4, tc = (t & 15) * 4;
  #pragma unroll
  for (int i = 0; i < 4; ++i) {
    int r = tr + i * 16;
    float4 v = *(const float4*)&in[(size_t)(r0 + r) * C + c0 + tc];
    tile[r][tc + 0] = v.x; tile[r][tc + 1] = v.y; tile[r][tc + 2] = v.z; tile[r][tc + 3] = v.w;
  }
  __syncthreads();
  #pragma unroll
  for (int i = 0; i < 2; ++i) {
    int c  = (t >> 3) + i * 32;
    int rb = (t & 7) * 8;
    union { u16 s[8]; uint4 v; } pk;
    #pragma unroll
    for (int u = 0; u < 8; ++u) pk.s[u] = f2bf(tile[rb + u][c] * scale);
    *(uint4*)&out[(size_t)(c0 + c) * ldo + r0 + rb] = pk.v;
  }
}

// ---------------- Wff1 transpose with (a,gate) fragment interleave -> W2T (8192 rows) ----------------
__global__ __launch_bounds__(256) void transpose_ff1(
    const float* __restrict__ in, u16* __restrict__ out)
{
  __shared__ float tile[64][65];
  const int c0 = blockIdx.x * 64, r0 = blockIdx.y * 64;
  const int t = threadIdx.x;
  const int tr = t >> 4, tc = (t & 15) * 4;
  #pragma unroll
  for (int i = 0; i < 4; ++i) {
    int r = tr + i * 16;
    float4 v = *(const float4*)&in[(size_t)(r0 + r) * 8192 + c0 + tc];
    tile[r][tc + 0] = v.x; tile[r][tc + 1] = v.y; tile[r][tc + 2] = v.z; tile[r][tc + 3] = v.w;
  }
  __syncthreads();
  #pragma unroll
  for (int i = 0; i < 2; ++i) {
    int c  = (t >> 3) + i * 32;
    int rb = (t & 7) * 8;
    const int gc = c0 + c;
    int j, add16;
    if (gc < 4096) { j = gc; add16 = 0; } else { j = gc - 4096; add16 = 16; }
    const int row = ((j >> 7) << 8) + (((j >> 5) & 3) << 6) + (((j >> 4) & 1) << 5) + add16 + (j & 15);
    union { u16 s[8]; uint4 v; } pk;
    #pragma unroll
    for (int u = 0; u < 8; ++u) pk.s[u] = f2bf(tile[rb + u][c]);
    *(uint4*)&out[(size_t)row * 1024 + r0 + rb] = pk.v;
  }
}

// =============== BK=32 4-phase 256x256 GEMM (ff: N=8192, 512 blocks = exact 2/CU pack) ===============
#define MM32(MQ, M, NN) acc[MQ][M][NN] = __builtin_amdgcn_mfma_f32_16x16x32_bf16(af##M, bf##NN, acc[MQ][M][NN], 0, 0, 0)
#define MFMA16_32(MQ) \
  MM32(MQ,0,0); MM32(MQ,0,1); MM32(MQ,0,2); MM32(MQ,0,3); \
  MM32(MQ,1,0); MM32(MQ,1,1); MM32(MQ,1,2); MM32(MQ,1,3); \
  MM32(MQ,2,0); MM32(MQ,2,1); MM32(MQ,2,2); MM32(MQ,2,3); \
  MM32(MQ,3,0); MM32(MQ,3,1); MM32(MQ,3,2); MM32(MQ,3,3)

#define SA32(SBUF, H, KT) GLDS16(gA32[H] + ((size_t)(KT) << 5), SBUF + (size_t)((H) * 64 + w16o) * 32)
#define SB32(SBUF, H, KT) GLDS16(gB32[H] + ((size_t)(KT) << 5), SBUF + (size_t)((H) * 128 + w16o2) * 32)

#define DSB32(PB_) do { \
  bf0 = *(const short8*)(PB_ + 0    + cks); bf1 = *(const short8*)(PB_ + 512  + cks); \
  bf2 = *(const short8*)(PB_ + 1024 + cks); bf3 = *(const short8*)(PB_ + 1536 + cks); \
} while (0)

#define PC32(PA_, MQ, STAGE_STMT, GATE_STMT) do { \
  af0 = *(const short8*)(PA_ + (MQ) * 2048 + 0    + cks); \
  af1 = *(const short8*)(PA_ + (MQ) * 2048 + 512  + cks); \
  af2 = *(const short8*)(PA_ + (MQ) * 2048 + 1024 + cks); \
  af3 = *(const short8*)(PA_ + (MQ) * 2048 + 1536 + cks); \
  STAGE_STMT; \
  __builtin_amdgcn_s_barrier(); \
  asm volatile("s_waitcnt lgkmcnt(0)" ::: "memory"); \
  __builtin_amdgcn_s_setprio(1); \
  MFMA16_32(MQ); \
  __builtin_amdgcn_s_setprio(0); \
  GATE_STMT; \
  __builtin_amdgcn_s_barrier(); \
} while (0)

#define GATE3 asm volatile("s_waitcnt vmcnt(3)" ::: "memory")
#define GATE0 asm volatile("s_waitcnt vmcnt(0)" ::: "memory")

__global__ __launch_bounds__(512, 2) void gemm32_ff(
    const u16* __restrict__ A, const u16* __restrict__ BT, u16* __restrict__ Ho,
    int M, int N, int Ktot)
{
  __shared__ u16 sh[2][2][8192]; // 64 KB
  const int nbm = M >> 8;
  const int nwg = gridDim.x;
  const int bid = blockIdx.x;
  const int o = (bid & 7) * (nwg >> 3) + (bid >> 3);
  const int bm = o % nbm, bn = o / nbm;   // B-strip per XCD
  const int NI = Ktot >> 6;

  const int t = threadIdx.x, w = t >> 6, lane = t & 63;
  const int wr = w >> 2, wc = w & 3;
  const int lr = lane & 15, lg = lane >> 4;
  const int l4 = lane >> 2, sl = lane & 3;
  const int w16o  = w * 16 + ((w >= 4) ? 64 : 0);
  const int w16o2 = w * 16;

  const u16* gA32[2]; const u16* gB32[2];
  #pragma unroll
  for (int h = 0; h < 2; ++h) {
    const int rowA = h * 64 + w16o + l4;
    gA32[h] = A + (size_t)(bm * 256 + rowA) * Ktot + (size_t)((sl ^ ((rowA >> 1) & 3)) * 8);
    const int rowB = h * 128 + w16o2 + l4;
    gB32[h] = BT + (size_t)(bn * 256 + rowB) * Ktot + (size_t)((sl ^ ((rowB >> 1) & 3)) * 8);
  }
  u16* sA0 = &sh[0][0][0]; u16* sA1 = &sh[1][0][0];
  u16* sB0 = &sh[0][1][0]; u16* sB1 = &sh[1][1][0];
  const int cks = (lg ^ ((lr >> 1) & 3)) * 8;
  const u16* pA_b0 = sA0 + (wr * 128 + lr) * 32;
  const u16* pA_b1 = sA1 + (wr * 128 + lr) * 32;
  const u16* pB_b0 = sB0 + (wc * 64 + lr) * 32;
  const u16* pB_b1 = sB1 + (wc * 64 + lr) * 32;

  f32x4 acc[2][4][4];
  const f32x4 z4 = { 0.f, 0.f, 0.f, 0.f };
  #pragma unroll
  for (int a = 0; a < 2; ++a)
    #pragma unroll
    for (int b = 0; b < 4; ++b)
      #pragma unroll
      for (int c = 0; c < 4; ++c) acc[a][b][c] = z4;
  short8 af0, af1, af2, af3;
  short8 bf0, bf1, bf2, bf3;

  SA32(sA0, 0, 0); SA32(sA0, 1, 0); SB32(sB0, 0, 0); SB32(sB0, 1, 0);
  SB32(sB1, 0, 1); SB32(sB1, 1, 1); SA32(sA1, 0, 1);
  GATE3;
  __builtin_amdgcn_s_barrier();

  for (int i = 0; i < NI; ++i) {
    const bool st = (i < NI - 1);
    const int X = 2 * i + 2, Y = 2 * i + 3;
    DSB32(pB_b0);
    PC32(pA_b0, 0, SA32(sA1, 1, 2 * i + 1), );
    PC32(pA_b0, 1,
         if (st) { SB32(sB0, 0, X); SB32(sB0, 1, X); SA32(sA0, 0, X); },
         if (st) { GATE3; } else { GATE0; });
    DSB32(pB_b1);
    PC32(pA_b1, 0, if (st) { SA32(sA0, 1, X); }, );
    PC32(pA_b1, 1,
         if (st) { SB32(sB1, 0, Y); SB32(sB1, 1, Y); SA32(sA1, 0, Y); },
         if (st) { GATE3; });
  }

  // silu(gate)*a pair-fused epilogue -> aoh cols 1024 + bn*128 .. (stride 5120)
  const int colb = 1024 + bn * 128 + wc * 32 + lr;
  #pragma unroll
  for (int mq = 0; mq < 2; ++mq)
    #pragma unroll
    for (int m = 0; m < 4; ++m)
      #pragma unroll
      for (int rr = 0; rr < 4; ++rr) {
        const int row = bm * 256 + wr * 128 + mq * 64 + m * 16 + lg * 4 + rr;
        #pragma unroll
        for (int n2 = 0; n2 < 2; ++n2) {
          const float a = acc[mq][m][2 * n2][rr];
          const float gt = acc[mq][m][2 * n2 + 1][rr];
          const float h = a * gt / (1.0f + __expf(-gt));
          Ho[(size_t)row * 5120 + colb + n2 * 16] = f2bf(h);
        }
      }
}

// =============== BK=64 8-phase 256x256 GEMM (final GEMM, split-K 4, bf16 partials) ===============
#define MM1(MQ, M, NN, BF) acc[MQ][M][NN] = __builtin_amdgcn_mfma_f32_16x16x32_bf16(af##M, BF, acc[MQ][M][NN], 0, 0, 0)
#define MFMA16(MQ, KS) \
  MM1(MQ,0,0,bf##KS##0); MM1(MQ,0,1,bf##KS##1); MM1(MQ,0,2,bf##KS##2); MM1(MQ,0,3,bf##KS##3); \
  MM1(MQ,1,0,bf##KS##0); MM1(MQ,1,1,bf##KS##1); MM1(MQ,1,2,bf##KS##2); MM1(MQ,1,3,bf##KS##3); \
  MM1(MQ,2,0,bf##KS##0); MM1(MQ,2,1,bf##KS##1); MM1(MQ,2,2,bf##KS##2); MM1(MQ,2,3,bf##KS##3); \
  MM1(MQ,3,0,bf##KS##0); MM1(MQ,3,1,bf##KS##1); MM1(MQ,3,2,bf##KS##2); MM1(MQ,3,3,bf##KS##3)

#define SG_A(SBUF, H, KT) do { \
    GLDS16(gA[H][0] + ((size_t)(KT) << 6), SBUF + ((H) * 64 + w16o) * 64); \
    GLDS16(gA[H][1] + ((size_t)(KT) << 6), SBUF + ((H) * 64 + w16o + 8) * 64); \
  } while (0)
#define SG_B(SBUF, H, KT) do { \
    GLDS16(gB[H][0] + ((size_t)(KT) << 6), SBUF + ((H) * 128 + w16o2) * 64); \
    GLDS16(gB[H][1] + ((size_t)(KT) << 6), SBUF + ((H) * 128 + w16o2 + 8) * 64); \
  } while (0)

#define DS_B(PB_) do { \
  bf00 = *(const short8*)(PB_ + 0    + cks0); bf01 = *(const short8*)(PB_ + 1024 + cks0); \
  bf02 = *(const short8*)(PB_ + 2048 + cks0); bf03 = *(const short8*)(PB_ + 3072 + cks0); \
  bf10 = *(const short8*)(PB_ + 0    + cks1); bf11 = *(const short8*)(PB_ + 1024 + cks1); \
  bf12 = *(const short8*)(PB_ + 2048 + cks1); bf13 = *(const short8*)(PB_ + 3072 + cks1); \
} while (0)

#define P_CORE(PA_, MQ, KS, STAGE_STMT, PREB_STMT, GATE_STMT) do { \
  af0 = *(const short8*)(PA_ + (MQ) * 4096 + 0    + cks##KS); \
  af1 = *(const short8*)(PA_ + (MQ) * 4096 + 1024 + cks##KS); \
  af2 = *(const short8*)(PA_ + (MQ) * 4096 + 2048 + cks##KS); \
  af3 = *(const short8*)(PA_ + (MQ) * 4096 + 3072 + cks##KS); \
  STAGE_STMT; \
  PREB_STMT; \
  __builtin_amdgcn_s_barrier(); \
  asm volatile("s_waitcnt lgkmcnt(0)" ::: "memory"); \
  __builtin_amdgcn_s_setprio(1); \
  MFMA16(MQ, KS); \
  __builtin_amdgcn_s_setprio(0); \
  GATE_STMT; \
  __builtin_amdgcn_s_barrier(); \
} while (0)

#define GATE6 asm volatile("s_waitcnt vmcnt(6)" ::: "memory")
#define HINT8 asm volatile("s_waitcnt lgkmcnt(8)" ::: "memory")

__global__ __launch_bounds__(512, 2) void gemm64_sk(
    const u16* __restrict__ A, const u16* __restrict__ BT, u16* __restrict__ C,
    int M, int N, int Ktot, int Kslice)
{
  __shared__ u16 sh[2][2][16384]; // 128 KB
  const int nbn = N >> 8;
  const int nwg = gridDim.x;
  const int bid = blockIdx.x;
  const int o = (bid & 7) * (nwg >> 3) + (bid >> 3);
  const int bn = o % nbn, bm = o / nbn;   // A-panels per XCD
  const int kbase = blockIdx.y * Kslice;
  const int NI = Kslice >> 7;

  const int t = threadIdx.x, w = t >> 6, lane = t & 63;
  const int wr = w >> 2, wc = w & 3;
  const int lr = lane & 15, lg = lane >> 4;
  const int r8 = lane >> 3, ch = lane & 7;
  const int clog = ch ^ r8;
  const int w16o  = w * 16 + ((w >= 4) ? 64 : 0);
  const int w16o2 = w * 16;

  const u16* gA[2][2]; const u16* gB[2][2];
  #pragma unroll
  for (int h = 0; h < 2; ++h)
    #pragma unroll
    for (int qq = 0; qq < 2; ++qq) {
      gA[h][qq] = A  + (size_t)(bm * 256 + h * 64  + w16o  + qq * 8 + r8) * Ktot + kbase + clog * 8;
      gB[h][qq] = BT + (size_t)(bn * 256 + h * 128 + w16o2 + qq * 8 + r8) * Ktot + kbase + clog * 8;
    }
  u16* sA0 = &sh[0][0][0]; u16* sA1 = &sh[1][0][0];
  u16* sB0 = &sh[0][1][0]; u16* sB1 = &sh[1][1][0];
  const int cks0 = ((0 + lg) ^ (lr & 7)) * 8;
  const int cks1 = ((4 + lg) ^ (lr & 7)) * 8;
  const u16* pA_b0 = sA0 + (wr * 128 + lr) * 64;
  const u16* pA_b1 = sA1 + (wr * 128 + lr) * 64;
  const u16* pB_b0 = sB0 + (wc * 64 + lr) * 64;
  const u16* pB_b1 = sB1 + (wc * 64 + lr) * 64;

  f32x4 acc[2][4][4];
  const f32x4 z4 = { 0.f, 0.f, 0.f, 0.f };
  #pragma unroll
  for (int a = 0; a < 2; ++a)
    #pragma unroll
    for (int b = 0; b < 4; ++b)
      #pragma unroll
      for (int c = 0; c < 4; ++c) acc[a][b][c] = z4;
  short8 af0, af1, af2, af3;
  short8 bf00, bf01, bf02, bf03, bf10, bf11, bf12, bf13;

  SG_B(sB0, 0, 0); SG_B(sB0, 1, 0); SG_A(sA0, 0, 0); SG_A(sA0, 1, 0);
  SG_B(sB1, 0, 1); SG_B(sB1, 1, 1); SG_A(sA1, 0, 1);
  GATE6;
  __builtin_amdgcn_s_barrier();

  for (int i = 0; i < NI; ++i) {
    const int k2 = 2 * i;
    const bool st = (i < NI - 1);
    DS_B(pB_b0);
    P_CORE(pA_b0, 0, 0, SG_A(sA1, 1, k2 + 1), HINT8, );
    P_CORE(pA_b0, 1, 0, if (st) SG_B(sB0, 0, k2 + 2), , );
    P_CORE(pA_b0, 0, 1, if (st) SG_B(sB0, 1, k2 + 2), , );
    P_CORE(pA_b0, 1, 1, if (st) SG_A(sA0, 0, k2 + 2), ,
           if (st) { GATE6; } else { GATE0; });
    DS_B(pB_b1);
    P_CORE(pA_b1, 0, 0, if (st) SG_A(sA0, 1, k2 + 2), HINT8, );
    P_CORE(pA_b1, 1, 0, if (st) SG_B(sB1, 0, k2 + 3), , );
    P_CORE(pA_b1, 0, 1, if (st) SG_B(sB1, 1, k2 + 3), , );
    P_CORE(pA_b1, 1, 1, if (st) SG_A(sA1, 0, k2 + 3), ,
           if (st) { GATE6; });
  }

  u16* Co = C + (size_t)blockIdx.y * M * N;
  #pragma unroll
  for (int mq = 0; mq < 2; ++mq)
    #pragma unroll
    for (int m = 0; m < 4; ++m)
      #pragma unroll
      for (int n = 0; n < 4; ++n)
        #pragma unroll
        for (int rr = 0; rr < 4; ++rr) {
          const int row = bm * 256 + wr * 128 + mq * 64 + m * 16 + lg * 4 + rr;
          const int col = bn * 256 + wc * 64 + n * 16 + lr;
          Co[(size_t)row * N + col] = f2bf(acc[mq][m][n][rr]);
        }
}

// ---------------- combined q + kv projection (one dispatch, 512 blocks = 2/CU) ----------------
// z=0: qbuf = xn @ WqT (bn = blockIdx.x, Kslice=1024); z=1: kvpart[z=blockIdx.x] = cn @ WkvT slice.
__global__ __launch_bounds__(256) void qkv_proj(
    const u16* __restrict__ xn, const u16* __restrict__ WqT, u16* __restrict__ qbuf,
    const u16* __restrict__ cn, const u16* __restrict__ WkvT, u16* __restrict__ kvpart)
{
  __shared__ u16 As[128 * 32];
  __shared__ u16 Bs[128 * 32];
  const int bm = blockIdx.y;
  const u16* A; const u16* BT; u16* Cp;
  int N, Kslice, bn, z;
  if (blockIdx.z == 0) { A = xn; BT = WqT;  Cp = qbuf;   N = 1024; Kslice = 1024; bn = blockIdx.x; z = 0; }
  else                 { A = cn; BT = WkvT; Cp = kvpart; N = 128;  Kslice = 128;  bn = 0; z = blockIdx.x; }
  const int Ktot = 1024, M = 4096;

  const int t = threadIdx.x;
  const int w = t >> 6, lane = t & 63;
  const int wr = w >> 1, wc = w & 1;
  const int lr = lane & 15, lkc = lane >> 4;

  f32x4 acc[4][4];
  const f32x4 z4 = { 0.f, 0.f, 0.f, 0.f };
  #pragma unroll
  for (int mi = 0; mi < 4; ++mi)
    #pragma unroll
    for (int ni = 0; ni < 4; ++ni) acc[mi][ni] = z4;

  const int kbase = z * Kslice;
  const int i0 = t, i1 = t + 256;
  const int r0 = i0 >> 2, k0 = swz4(r0, i0 & 3) * 8;
  const int r1 = i1 >> 2, k1 = swz4(r1, i1 & 3) * 8;
  const u16* a0 = A + (size_t)(bm * 128 + r0) * Ktot + kbase + k0;
  const u16* a1 = A + (size_t)(bm * 128 + r1) * Ktot + kbase + k1;
  const u16* b0 = BT + (size_t)(bn * 128 + r0) * Ktot + kbase + k0;
  const u16* b1 = BT + (size_t)(bn * 128 + r1) * Ktot + kbase + k1;
  u16* As0 = As + (size_t)w * 512;
  u16* As1 = As + (size_t)(w + 4) * 512;
  u16* Bs0 = Bs + (size_t)w * 512;
  u16* Bs1 = Bs + (size_t)(w + 4) * 512;

  const int nk = Kslice >> 5;
  for (int kt = 0; kt < nk; ++kt) {
    __syncthreads();
    GLDS16(a0, As0); GLDS16(a1, As1); GLDS16(b0, Bs0); GLDS16(b1, Bs1);
    a0 += 32; a1 += 32; b0 += 32; b1 += 32;
    __syncthreads();
    short8 af[4], bf[4];
    #pragma unroll
    for (int mi = 0; mi < 4; ++mi) {
      int row = wr * 64 + mi * 16 + lr;
      af[mi] = *(const short8*)&As[row * 32 + swz4(row, lkc) * 8];
    }
    #pragma unroll
    for (int ni = 0; ni < 4; ++ni) {
      int row = wc * 64 + ni * 16 + lr;
      bf[ni] = *(const short8*)&Bs[row * 32 + swz4(row, lkc) * 8];
    }
    #pragma unroll
    for (int mi = 0; mi < 4; ++mi)
      #pragma unroll
      for (int ni = 0; ni < 4; ++ni)
        acc[mi][ni] = __builtin_amdgcn_mfma_f32_16x16x32_bf16(af[mi], bf[ni], acc[mi][ni], 0, 0, 0);
  }

  u16* Cz = Cp + (size_t)z * M * N;
  const int row0 = bm * 128 + wr * 64, col0 = bn * 128 + wc * 64;
  const int rsub = (lane >> 4) * 4;
  #pragma unroll
  for (int mi = 0; mi < 4; ++mi)
    #pragma unroll
    for (int ni = 0; ni < 4; ++ni)
      #pragma unroll
      for (int r = 0; r < 4; ++r)
        Cz[(size_t)(row0 + mi * 16 + rsub + r) * N + (col0 + ni * 16 + lr)] = f2bf(acc[mi][ni][r]);
}

// ---------------- reduce 8 bf16 partials (4096x128) -> bf16 ----------------
__global__ __launch_bounds__(256) void reduce_kv(const u16* __restrict__ part, u16* __restrict__ out)
{
  const size_t base = ((size_t)blockIdx.x * 256 + threadIdx.x) * 8;
  float s[8] = { 0.f, 0.f, 0.f, 0.f, 0.f, 0.f, 0.f, 0.f };
  #pragma unroll
  for (int zz = 0; zz < 8; ++zz) {
    const short8 v = *(const short8*)&part[(size_t)zz * 524288 + base];
    #pragma unroll
    for (int i = 0; i < 8; ++i) s[i] += bf2f((u16)v[i]);
  }
  union { u16 o[8]; uint4 v; } pk;
  #pragma unroll
  for (int i = 0; i < 8; ++i) pk.o[i] = f2bf(s[i]);
  *(uint4*)&out[base] = pk.v;
}

// ---------------- out = sum of 4 bf16 partials (4096x1024) -> f32 ----------------
__global__ __launch_bounds__(256) void reduce_out(const u16* __restrict__ part, float* __restrict__ out)
{
  const size_t base = ((size_t)blockIdx.x * 256 + threadIdx.x) * 8;
  float s[8] = { 0.f, 0.f, 0.f, 0.f, 0.f, 0.f, 0.f, 0.f };
  #pragma unroll
  for (int zz = 0; zz < 4; ++zz) {
    const short8 v = *(const short8*)&part[(size_t)zz * 4194304 + base];
    #pragma unroll
    for (int i = 0; i < 8; ++i) s[i] += bf2f((u16)v[i]);
  }
  f32x4 lo = { s[0], s[1], s[2], s[3] };
  f32x4 hi = { s[4], s[5], s[6], s[7] };
  *(f32x4*)&out[base] = lo;
  *(f32x4*)&out[base + 4] = hi;
}

// ---------------- flash cross-attention (multi-query: 1 KV head) ----------------
// 8 waves x 512 threads, 256 blocks: wave w -> head hb*4+(w>>1), q-half w&1 (32 rows).
__global__ __launch_bounds__(512, 1) void attn_kernel(
    const u16* __restrict__ q, const u16* __restrict__ kv, u16* __restrict__ o)
{
  __shared__ u16 Ks[128 * 64];
  __shared__ u16 Vt[64 * 128];
  __shared__ u16 Ps[8][32 * 128];
  const int b = blockIdx.z, hb = blockIdx.y, qb = blockIdx.x;
  const int t = threadIdx.x, w = t >> 6, lane = t & 63;
  const int q32 = lane & 31, hl = lane >> 5;
  const int hd = hb * 4 + (w >> 1);
  const int t32 = w & 1;

  const size_t qbase = (size_t)b * 2048 + qb * 64;
  short8 qa[4];
  #pragma unroll
  for (int dq = 0; dq < 4; ++dq)
    qa[dq] = *(const short8*)&q[(qbase + t32 * 32 + q32) * 1024 + hd * 64 + dq * 16 + hl * 8];

  f32x16 oacc[2];
  #pragma unroll
  for (int j = 0; j < 2; ++j)
    #pragma unroll
    for (int r = 0; r < 16; ++r) oacc[j][r] = 0.f;
  float m_ = -1e30f, l_ = 0.f;

  const size_t kvb = (size_t)b * 2048 * 128;
  const int vd0 = (t & 7) * 8;
  const int vodd = (t >> 3) & 1;
  u16* Pw = &Ps[w][0];

  uint4 vhold[2];
  #pragma unroll
  for (int c = 0; c < 2; ++c) {
    const int vj = (c * 512 + t) >> 3;
    vhold[c] = *(const uint4*)&kv[kvb + (size_t)vj * 128 + 64 + vd0];
  }

  for (int jt = 0; jt < 16; ++jt) {
    __syncthreads();
    #pragma unroll
    for (int n = 0; n < 2; ++n) {
      const int cc = n * 512 + w * 64;
      const int ccl = cc + lane;
      const int row = ccl >> 3, lc = (ccl & 7) ^ (row & 7);
      GLDS16(&kv[kvb + (size_t)(jt * 128 + row) * 128 + lc * 8], Ks + (size_t)cc * 8);
    }
    #pragma unroll
    for (int c = 0; c < 2; ++c) {
      const int seg = c * 512 + t;
      const int vj = seg >> 3;
      const int jp = vj >> 1;
      const uint4 vv = vhold[c];
      uint4 pvv;
      pvv.x = __shfl_xor((int)vv.x, 8);
      pvv.y = __shfl_xor((int)vv.y, 8);
      pvv.z = __shfl_xor((int)vv.z, 8);
      pvv.w = __shfl_xor((int)vv.w, 8);
      const unsigned ow[4] = { vv.x, vv.y, vv.z, vv.w };
      const unsigned pw[4] = { pvv.x, pvv.y, pvv.z, pvv.w };
      if (!vodd) {
        #pragma unroll
        for (int u = 0; u < 4; ++u) {
          const int d = vd0 + u;
          const unsigned own = (u & 1) ? (ow[u >> 1] >> 16) : (ow[u >> 1] & 0xffffu);
          const unsigned par = (u & 1) ? (pw[u >> 1] >> 16) : (pw[u >> 1] & 0xffffu);
          const int byteoff = d * 256 + ((4 * jp) ^ (((d & 7) ^ ((d >> 3) & 7)) << 4));
          *(unsigned*)((char*)Vt + byteoff) = own | (par << 16);
        }
      } else {
        #pragma unroll
        for (int u = 0; u < 4; ++u) {
          const int ue = u + 4;
          const int d = vd0 + ue;
          const unsigned own = (ue & 1) ? (ow[ue >> 1] >> 16) : (ow[ue >> 1] & 0xffffu);
          const unsigned par = (ue & 1) ? (pw[ue >> 1] >> 16) : (pw[ue >> 1] & 0xffffu);
          const int byteoff = d * 256 + ((4 * jp) ^ (((d & 7) ^ ((d >> 3) & 7)) << 4));
          *(unsigned*)((char*)Vt + byteoff) = par | (own << 16);
        }
      }
    }
    __builtin_amdgcn_sched_barrier(0);
    if (jt < 15) {
      #pragma unroll
      for (int c = 0; c < 2; ++c) {
        const int vj = (c * 512 + t) >> 3;
        vhold[c] = *(const uint4*)&kv[kvb + (size_t)((jt + 1) * 128 + vj) * 128 + 64 + vd0];
      }
      asm volatile("s_waitcnt vmcnt(2) lgkmcnt(0)" ::: "memory");
    } else {
      asm volatile("s_waitcnt vmcnt(0) lgkmcnt(0)" ::: "memory");
    }
    __builtin_amdgcn_s_barrier();
    __builtin_amdgcn_sched_barrier(0);

    f32x16 s[4];
    #pragma unroll
    for (int j32 = 0; j32 < 4; ++j32)
      #pragma unroll
      for (int r = 0; r < 16; ++r) s[j32][r] = 0.f;
    __builtin_amdgcn_s_setprio(1);
    #pragma unroll
    for (int j32 = 0; j32 < 4; ++j32) {
      const int row = j32 * 32 + q32;
      #pragma unroll
      for (int dq = 0; dq < 4; ++dq) {
        const int slot = (dq * 2 + hl) ^ (row & 7);
        const short8 kf = *(const short8*)&Ks[row * 64 + slot * 8];
        s[j32] = __builtin_amdgcn_mfma_f32_32x32x16_bf16(kf, qa[dq], s[j32], 0, 0, 0);
      }
    }
    __builtin_amdgcn_s_setprio(0);
    float mt = -1e30f;
    #pragma unroll
    for (int j32 = 0; j32 < 4; ++j32)
      #pragma unroll
      for (int r = 0; r < 16; ++r) mt = fmaxf(mt, s[j32][r]);
    mt = fmaxf(mt, __shfl_xor(mt, 32));
    const bool noresc = (bool)__all(mt <= m_ + 8.0f);
    float nm = m_;
    if (!noresc) {
      nm = fmaxf(m_, mt);
      const float alpha = __expf(m_ - nm);
      m_ = nm;
      l_ *= alpha;
      #pragma unroll
      for (int d32 = 0; d32 < 2; ++d32)
        #pragma unroll
        for (int r = 0; r < 16; ++r) oacc[d32][r] *= alpha;
    }
    float lsum = 0.f;
    #pragma unroll
    for (int j32 = 0; j32 < 4; ++j32) {
      float p[16];
      #pragma unroll
      for (int r = 0; r < 16; ++r) { p[r] = __expf(s[j32][r] - nm); lsum += p[r]; }
      #pragma unroll
      for (int g = 0; g < 4; ++g) {
        const unsigned lo = cvtpk(p[4 * g + 0], p[4 * g + 1]);
        const unsigned hi = cvtpk(p[4 * g + 2], p[4 * g + 3]);
        const int j2 = j32 * 64 + 16 * g + 8 * hl;
        const int byteoff = q32 * 256 + (j2 ^ ((q32 & 7) << 4));
        uint2 wv; wv.x = lo; wv.y = hi;
        *(uint2*)((char*)Pw + byteoff) = wv;
      }
    }
    lsum += __shfl_xor(lsum, 32);
    l_ += lsum;
    short8 pf[8];
    #pragma unroll
    for (int kk = 0; kk < 8; ++kk) {
      const int byteoff = q32 * 256 + ((kk * 32 + hl * 16) ^ ((q32 & 7) << 4));
      pf[kk] = *(const short8*)((const char*)Pw + byteoff);
    }
    __builtin_amdgcn_s_setprio(1);
    #pragma unroll
    for (int d32 = 0; d32 < 2; ++d32) {
      const int dr = d32 * 32 + q32;
      const int vswz = ((dr & 7) ^ ((dr >> 3) & 7)) << 4;
      #pragma unroll
      for (int kk = 0; kk < 8; ++kk) {
        const int byteoff = dr * 256 + ((kk * 32 + hl * 16) ^ vswz);
        const short8 vf = *(const short8*)((const char*)Vt + byteoff);
        oacc[d32] = __builtin_amdgcn_mfma_f32_32x32x16_bf16(vf, pf[kk], oacc[d32], 0, 0, 0);
      }
    }
    __builtin_amdgcn_s_setprio(0);
  }

  float* Ot = (float*)Pw;
  const float inv = 1.0f / l_;
  #pragma unroll
  for (int d32 = 0; d32 < 2; ++d32) {
    #pragma unroll
    for (int r = 0; r < 16; ++r) {
      const int d = (r & 3) + 8 * (r >> 2) + 4 * hl;
      const int byteoff = q32 * 128 + ((4 * d) ^ ((q32 & 7) << 4));
      *(float*)((char*)Ot + byteoff) = oacc[d32][r] * inv;
    }
    const int qr = lane >> 1, dc = (lane & 1) * 16;
    union { u16 s[16]; uint4 v[2]; } ob;
    #pragma unroll
    for (int cch = 0; cch < 4; ++cch) {
      const int byteoff = qr * 128 + ((4 * (dc + 4 * cch)) ^ ((qr & 7) << 4));
      const f32x4 vv = *(const f32x4*)((const char*)Ot + byteoff);
      ob.s[cch * 4 + 0] = f2bf(vv[0]);
      ob.s[cch * 4 + 1] = f2bf(vv[1]);
      ob.s[cch * 4 + 2] = f2bf(vv[2]);
      ob.s[cch * 4 + 3] = f2bf(vv[3]);
    }
    u16* orow = &o[(qbase + t32 * 32 + qr) * 5120 + hd * 64 + d32 * 32 + dc];
    *(uint4*)orow = ob.v[0];
    *(uint4*)(orow + 8) = ob.v[1];
  }
}

extern "C" void kernel_launch(void* const* d_in, const int* in_sizes, int n_in,
                              void* d_out, int out_size, void* d_ws, size_t ws_size,
                              hipStream_t stream)
{
  const float* x    = (const float*)d_in[0];
  const float* ctx  = (const float*)d_in[1];
  const float* ng   = (const float*)d_in[2];
  const float* nb   = (const float*)d_in[3];
  const float* cg   = (const float*)d_in[4];
  const float* cb   = (const float*)d_in[5];
  const float* Wq   = (const float*)d_in[6];
  const float* Wkv  = (const float*)d_in[7];
  const float* Wo   = (const float*)d_in[8];
  const float* Wff1 = (const float*)d_in[9];
  const float* Wff2 = (const float*)d_in[10];

  u16* p = (u16*)d_ws;
  u16* WqT   = p; p += (size_t)1024 * 1024;
  u16* W2T   = p; p += (size_t)8192 * 1024;   // Wff1 interleaved
  u16* WkvT  = p; p += (size_t)128 * 1024;
  u16* WcT   = p; p += (size_t)1024 * 5120;
  u16* kvbuf = p; p += (size_t)4096 * 128;
  u16* aoh   = p; p += (size_t)4096 * 5120;
  u16* xn    = p; p += (size_t)4096 * 1024;
  u16* cn    = p; p += (size_t)4096 * 1024;
  u16* qbuf  = p; p += (size_t)4096 * 1024;
  u16* kvpart = p; p += (size_t)8 * 4096 * 128;  // 8 MB dedicated (qkv runs concurrent with nothing dead)
  u16* ffpart = xn;    // 32 MB bf16 over xn|cn|qbuf + tail (dead by final GEMM)
  (void)in_sizes; (void)n_in; (void)out_size; (void)ws_size;

  ln_kernel<<<8192, 256, 0, stream>>>(x, ctx, ng, nb, cg, cb, xn, cn);

  transpose_ff1<<<dim3(128, 16), 256, 0, stream>>>(Wff1, W2T);
  transpose_all<<<1568, 256, 0, stream>>>(Wq, Wkv, Wo, Wff2, WqT, WkvT, WcT);

  // ff: aoh[:,1024:] = silu(xn @ Wff1), N=8192 -> 512 blocks = exact 2/CU pack
  gemm32_ff<<<dim3(512), 512, 0, stream>>>(xn, W2T, aoh, 4096, 8192, 1024);
  // q + kv projections in one dispatch (512 blocks): z=0 q tiles, z=1 kv split-K partials
  qkv_proj<<<dim3(8, 32, 2), 256, 0, stream>>>(xn, WqT, qbuf, cn, WkvT, kvpart);
  reduce_kv<<<256, 256, 0, stream>>>(kvpart, kvbuf);
  // attention -> aoh[:,0:1024]; 8 waves/block (2/SIMD TLP)
  attn_kernel<<<dim3(32, 4, 2), 512, 0, stream>>>(qbuf, kvbuf, aoh);
  // out = aoh @ [Wo ; Wff2], split-K 4, bf16 partials
  gemm64_sk<<<dim3(64, 4), 512, 0, stream>>>(aoh, WcT, ffpart, 4096, 1024, 5120, 1280);
  reduce_out<<<2048, 256, 0, stream>>>(ffpart, (float*)d_out);
}

// Round 18
// 249.951 us; speedup vs baseline: 5.4691x; 1.0028x over previous
//
#include <hip/hip_runtime.h>
#include <stdint.h>

typedef unsigned short u16;
typedef __attribute__((ext_vector_type(8))) short short8;
typedef __attribute__((ext_vector_type(4))) float f32x4;
typedef __attribute__((ext_vector_type(16))) float f32x16;

#define GPTR(p) ((const __attribute__((address_space(1))) void*)(p))
#define SPTR(p) ((__attribute__((address_space(3))) void*)(p))
#define GLDS16(g, l) __builtin_amdgcn_global_load_lds(GPTR(g), SPTR(l), 16, 0, 0)

static __device__ __forceinline__ float bf2f(u16 u) {
  union { unsigned int i; float f; } c; c.i = ((unsigned int)u) << 16; return c.f;
}
static __device__ __forceinline__ u16 f2bf(float f) {
  union { float f; unsigned int u; } c; c.f = f;
  unsigned int r = 0x7fffu + ((c.u >> 16) & 1u);
  return (u16)((c.u + r) >> 16);
}
static __device__ __forceinline__ unsigned cvtpk(float a, float b) {
  unsigned r;
  asm volatile("v_cvt_pk_bf16_f32 %0, %1, %2" : "=v"(r) : "v"(a), "v"(b));
  return r;
}
static __device__ __forceinline__ int swz4(int row, int c) { return c ^ ((row >> 1) & 3); }

// ---------------- LayerNorm: f32 (rows of 1024) -> bf16 ----------------
__global__ __launch_bounds__(256) void ln_kernel(
    const float* __restrict__ x, const float* __restrict__ ctx,
    const float* __restrict__ g, const float* __restrict__ b,
    const float* __restrict__ cg, const float* __restrict__ cb,
    u16* __restrict__ xn, u16* __restrict__ cn)
{
  const int row = blockIdx.x;
  const float* src; const float* gg; const float* bb; u16* dst;
  if (row < 4096) { src = x + (size_t)row * 1024; gg = g;  bb = b;  dst = xn + (size_t)row * 1024; }
  else            { src = ctx + (size_t)(row - 4096) * 1024; gg = cg; bb = cb; dst = cn + (size_t)(row - 4096) * 1024; }
  const int t = threadIdx.x;
  float4 v = *(const float4*)&src[t * 4];
  float s  = v.x + v.y + v.z + v.w;
  float s2 = v.x * v.x + v.y * v.y + v.z * v.z + v.w * v.w;
  #pragma unroll
  for (int off = 1; off < 64; off <<= 1) { s += __shfl_xor(s, off); s2 += __shfl_xor(s2, off); }
  __shared__ float ls[4], ls2[4];
  const int w = t >> 6;
  if ((t & 63) == 0) { ls[w] = s; ls2[w] = s2; }
  __syncthreads();
  s  = ls[0] + ls[1] + ls[2] + ls[3];
  s2 = ls2[0] + ls2[1] + ls2[2] + ls2[3];
  const float mu   = s * (1.0f / 1024.0f);
  const float var  = s2 * (1.0f / 1024.0f) - mu * mu;
  const float rstd = rsqrtf(var + 1e-5f);
  float xv[4] = { v.x, v.y, v.z, v.w };
  u16 o[4];
  #pragma unroll
  for (int i = 0; i < 4; ++i)
    o[i] = f2bf((xv[i] - mu) * rstd * gg[t * 4 + i] + bb[t * 4 + i]);
  uint2 pv;
  pv.x = (unsigned)o[0] | ((unsigned)o[1] << 16);
  pv.y = (unsigned)o[2] | ((unsigned)o[3] << 16);
  *(uint2*)&dst[t * 4] = pv;
}

// ---------------- merged transpose: Wq, Wkv, Wo, Wff2 in one dispatch ----------------
__global__ __launch_bounds__(256) void transpose_all(
    const float* __restrict__ Wq, const float* __restrict__ Wkv,
    const float* __restrict__ Wo, const float* __restrict__ Wff2,
    u16* __restrict__ WqT, u16* __restrict__ WkvT, u16* __restrict__ WcT)
{
  int id = blockIdx.x;
  const float* in; u16* out; int C, ldo, cx; float scale;
  if (id < 256)      {           in = Wq;   out = WqT;        C = 1024; ldo = 1024; scale = 0.125f; cx = 16; }
  else if (id < 288) { id -= 256; in = Wkv;  out = WkvT;       C = 128;  ldo = 1024; scale = 1.0f;   cx = 2;  }
  else if (id < 544) { id -= 288; in = Wo;   out = WcT;        C = 1024; ldo = 5120; scale = 1.0f;   cx = 16; }
  else               { id -= 544; in = Wff2; out = WcT + 1024; C = 1024; ldo = 5120; scale = 1.0f;   cx = 16; }
  const int c0 = (id % cx) * 64, r0 = (id / cx) * 64;

  __shared__ float tile[64][65];
  const int t = threadIdx.x;
  const int tr = t >> 4, tc = (t & 15) * 4;
  #pragma unroll
  for (int i = 0; i < 4; ++i) {
    int r = tr + i * 16;
    float4 v = *(const float4*)&in[(size_t)(r0 + r) * C + c0 + tc];
    tile[r][tc + 0] = v.x; tile[r][tc + 1] = v.y; tile[r][tc + 2] = v.z; tile[r][tc + 3] = v.w;
  }
  __syncthreads();
  #pragma unroll
  for (int i = 0; i < 2; ++i) {
    int c  = (t >> 3) + i * 32;
    int rb = (t & 7) * 8;
    union { u16 s[8]; uint4 v; } pk;
    #pragma unroll
    for (int u = 0; u < 8; ++u) pk.s[u] = f2bf(tile[rb + u][c] * scale);
    *(uint4*)&out[(size_t)(c0 + c) * ldo + r0 + rb] = pk.v;
  }
}

// ---------------- Wff1 transpose with (a,gate) fragment interleave -> W2T (8192 rows) ----------------
__global__ __launch_bounds__(256) void transpose_ff1(
    const float* __restrict__ in, u16* __restrict__ out)
{
  __shared__ float tile[64][65];
  const int c0 = blockIdx.x * 64, r0 = blockIdx.y * 64;
  const int t = threadIdx.x;
  const int tr = t >> 4, tc = (t & 15) * 4;
  #pragma unroll
  for (int i = 0; i < 4; ++i) {
    int r = tr + i * 16;
    float4 v = *(const float4*)&in[(size_t)(r0 + r) * 8192 + c0 + tc];
    tile[r][tc + 0] = v.x; tile[r][tc + 1] = v.y; tile[r][tc + 2] = v.z; tile[r][tc + 3] = v.w;
  }
  __syncthreads();
  #pragma unroll
  for (int i = 0; i < 2; ++i) {
    int c  = (t >> 3) + i * 32;
    int rb = (t & 7) * 8;
    const int gc = c0 + c;
    int j, add16;
    if (gc < 4096) { j = gc; add16 = 0; } else { j = gc - 4096; add16 = 16; }
    const int row = ((j >> 7) << 8) + (((j >> 5) & 3) << 6) + (((j >> 4) & 1) << 5) + add16 + (j & 15);
    union { u16 s[8]; uint4 v; } pk;
    #pragma unroll
    for (int u = 0; u < 8; ++u) pk.s[u] = f2bf(tile[rb + u][c]);
    *(uint4*)&out[(size_t)row * 1024 + r0 + rb] = pk.v;
  }
}

// =============== BK=32 4-phase 256x256 GEMM (ff: N=8192, 512 blocks = exact 2/CU pack) ===============
#define MM32(MQ, M, NN) acc[MQ][M][NN] = __builtin_amdgcn_mfma_f32_16x16x32_bf16(af##M, bf##NN, acc[MQ][M][NN], 0, 0, 0)
#define MFMA16_32(MQ) \
  MM32(MQ,0,0); MM32(MQ,0,1); MM32(MQ,0,2); MM32(MQ,0,3); \
  MM32(MQ,1,0); MM32(MQ,1,1); MM32(MQ,1,2); MM32(MQ,1,3); \
  MM32(MQ,2,0); MM32(MQ,2,1); MM32(MQ,2,2); MM32(MQ,2,3); \
  MM32(MQ,3,0); MM32(MQ,3,1); MM32(MQ,3,2); MM32(MQ,3,3)

#define SA32(SBUF, H, KT) GLDS16(gA32[H] + ((size_t)(KT) << 5), SBUF + (size_t)((H) * 64 + w16o) * 32)
#define SB32(SBUF, H, KT) GLDS16(gB32[H] + ((size_t)(KT) << 5), SBUF + (size_t)((H) * 128 + w16o2) * 32)

#define DSB32(PB_) do { \
  bf0 = *(const short8*)(PB_ + 0    + cks); bf1 = *(const short8*)(PB_ + 512  + cks); \
  bf2 = *(const short8*)(PB_ + 1024 + cks); bf3 = *(const short8*)(PB_ + 1536 + cks); \
} while (0)

#define PC32(PA_, MQ, STAGE_STMT, GATE_STMT) do { \
  af0 = *(const short8*)(PA_ + (MQ) * 2048 + 0    + cks); \
  af1 = *(const short8*)(PA_ + (MQ) * 2048 + 512  + cks); \
  af2 = *(const short8*)(PA_ + (MQ) * 2048 + 1024 + cks); \
  af3 = *(const short8*)(PA_ + (MQ) * 2048 + 1536 + cks); \
  STAGE_STMT; \
  __builtin_amdgcn_s_barrier(); \
  asm volatile("s_waitcnt lgkmcnt(0)" ::: "memory"); \
  __builtin_amdgcn_s_setprio(1); \
  MFMA16_32(MQ); \
  __builtin_amdgcn_s_setprio(0); \
  GATE_STMT; \
  __builtin_amdgcn_s_barrier(); \
} while (0)

#define GATE3 asm volatile("s_waitcnt vmcnt(3)" ::: "memory")
#define GATE0 asm volatile("s_waitcnt vmcnt(0)" ::: "memory")

__global__ __launch_bounds__(512, 2) void gemm32_ff(
    const u16* __restrict__ A, const u16* __restrict__ BT, u16* __restrict__ Ho,
    int M, int N, int Ktot)
{
  __shared__ u16 sh[2][2][8192]; // 64 KB
  const int nbm = M >> 8;
  const int nwg = gridDim.x;
  const int bid = blockIdx.x;
  const int o = (bid & 7) * (nwg >> 3) + (bid >> 3);
  const int bm = o % nbm, bn = o / nbm;   // B-strip per XCD
  const int NI = Ktot >> 6;

  const int t = threadIdx.x, w = t >> 6, lane = t & 63;
  const int wr = w >> 2, wc = w & 3;
  const int lr = lane & 15, lg = lane >> 4;
  const int l4 = lane >> 2, sl = lane & 3;
  const int w16o  = w * 16 + ((w >= 4) ? 64 : 0);
  const int w16o2 = w * 16;

  const u16* gA32[2]; const u16* gB32[2];
  #pragma unroll
  for (int h = 0; h < 2; ++h) {
    const int rowA = h * 64 + w16o + l4;
    gA32[h] = A + (size_t)(bm * 256 + rowA) * Ktot + (size_t)((sl ^ ((rowA >> 1) & 3)) * 8);
    const int rowB = h * 128 + w16o2 + l4;
    gB32[h] = BT + (size_t)(bn * 256 + rowB) * Ktot + (size_t)((sl ^ ((rowB >> 1) & 3)) * 8);
  }
  u16* sA0 = &sh[0][0][0]; u16* sA1 = &sh[1][0][0];
  u16* sB0 = &sh[0][1][0]; u16* sB1 = &sh[1][1][0];
  const int cks = (lg ^ ((lr >> 1) & 3)) * 8;
  const u16* pA_b0 = sA0 + (wr * 128 + lr) * 32;
  const u16* pA_b1 = sA1 + (wr * 128 + lr) * 32;
  const u16* pB_b0 = sB0 + (wc * 64 + lr) * 32;
  const u16* pB_b1 = sB1 + (wc * 64 + lr) * 32;

  f32x4 acc[2][4][4];
  const f32x4 z4 = { 0.f, 0.f, 0.f, 0.f };
  #pragma unroll
  for (int a = 0; a < 2; ++a)
    #pragma unroll
    for (int b = 0; b < 4; ++b)
      #pragma unroll
      for (int c = 0; c < 4; ++c) acc[a][b][c] = z4;
  short8 af0, af1, af2, af3;
  short8 bf0, bf1, bf2, bf3;

  SA32(sA0, 0, 0); SA32(sA0, 1, 0); SB32(sB0, 0, 0); SB32(sB0, 1, 0);
  SB32(sB1, 0, 1); SB32(sB1, 1, 1); SA32(sA1, 0, 1);
  GATE3;
  __builtin_amdgcn_s_barrier();

  for (int i = 0; i < NI; ++i) {
    const bool st = (i < NI - 1);
    const int X = 2 * i + 2, Y = 2 * i + 3;
    DSB32(pB_b0);
    PC32(pA_b0, 0, SA32(sA1, 1, 2 * i + 1), );
    PC32(pA_b0, 1,
         if (st) { SB32(sB0, 0, X); SB32(sB0, 1, X); SA32(sA0, 0, X); },
         if (st) { GATE3; } else { GATE0; });
    DSB32(pB_b1);
    PC32(pA_b1, 0, if (st) { SA32(sA0, 1, X); }, );
    PC32(pA_b1, 1,
         if (st) { SB32(sB1, 0, Y); SB32(sB1, 1, Y); SA32(sA1, 0, Y); },
         if (st) { GATE3; });
  }

  const int colb = 1024 + bn * 128 + wc * 32 + lr;
  #pragma unroll
  for (int mq = 0; mq < 2; ++mq)
    #pragma unroll
    for (int m = 0; m < 4; ++m)
      #pragma unroll
      for (int rr = 0; rr < 4; ++rr) {
        const int row = bm * 256 + wr * 128 + mq * 64 + m * 16 + lg * 4 + rr;
        #pragma unroll
        for (int n2 = 0; n2 < 2; ++n2) {
          const float a = acc[mq][m][2 * n2][rr];
          const float gt = acc[mq][m][2 * n2 + 1][rr];
          const float h = a * gt / (1.0f + __expf(-gt));
          Ho[(size_t)row * 5120 + colb + n2 * 16] = f2bf(h);
        }
      }
}

// =============== BK=64 8-phase 256x256 GEMM (final GEMM, split-K 4, bf16 partials) ===============
#define MM1(MQ, M, NN, BF) acc[MQ][M][NN] = __builtin_amdgcn_mfma_f32_16x16x32_bf16(af##M, BF, acc[MQ][M][NN], 0, 0, 0)
#define MFMA16(MQ, KS) \
  MM1(MQ,0,0,bf##KS##0); MM1(MQ,0,1,bf##KS##1); MM1(MQ,0,2,bf##KS##2); MM1(MQ,0,3,bf##KS##3); \
  MM1(MQ,1,0,bf##KS##0); MM1(MQ,1,1,bf##KS##1); MM1(MQ,1,2,bf##KS##2); MM1(MQ,1,3,bf##KS##3); \
  MM1(MQ,2,0,bf##KS##0); MM1(MQ,2,1,bf##KS##1); MM1(MQ,2,2,bf##KS##2); MM1(MQ,2,3,bf##KS##3); \
  MM1(MQ,3,0,bf##KS##0); MM1(MQ,3,1,bf##KS##1); MM1(MQ,3,2,bf##KS##2); MM1(MQ,3,3,bf##KS##3)

#define SG_A(SBUF, H, KT) do { \
    GLDS16(gA[H][0] + ((size_t)(KT) << 6), SBUF + ((H) * 64 + w16o) * 64); \
    GLDS16(gA[H][1] + ((size_t)(KT) << 6), SBUF + ((H) * 64 + w16o + 8) * 64); \
  } while (0)
#define SG_B(SBUF, H, KT) do { \
    GLDS16(gB[H][0] + ((size_t)(KT) << 6), SBUF + ((H) * 128 + w16o2) * 64); \
    GLDS16(gB[H][1] + ((size_t)(KT) << 6), SBUF + ((H) * 128 + w16o2 + 8) * 64); \
  } while (0)

#define DS_B(PB_) do { \
  bf00 = *(const short8*)(PB_ + 0    + cks0); bf01 = *(const short8*)(PB_ + 1024 + cks0); \
  bf02 = *(const short8*)(PB_ + 2048 + cks0); bf03 = *(const short8*)(PB_ + 3072 + cks0); \
  bf10 = *(const short8*)(PB_ + 0    + cks1); bf11 = *(const short8*)(PB_ + 1024 + cks1); \
  bf12 = *(const short8*)(PB_ + 2048 + cks1); bf13 = *(const short8*)(PB_ + 3072 + cks1); \
} while (0)

#define P_CORE(PA_, MQ, KS, STAGE_STMT, PREB_STMT, GATE_STMT) do { \
  af0 = *(const short8*)(PA_ + (MQ) * 4096 + 0    + cks##KS); \
  af1 = *(const short8*)(PA_ + (MQ) * 4096 + 1024 + cks##KS); \
  af2 = *(const short8*)(PA_ + (MQ) * 4096 + 2048 + cks##KS); \
  af3 = *(const short8*)(PA_ + (MQ) * 4096 + 3072 + cks##KS); \
  STAGE_STMT; \
  PREB_STMT; \
  __builtin_amdgcn_s_barrier(); \
  asm volatile("s_waitcnt lgkmcnt(0)" ::: "memory"); \
  __builtin_amdgcn_s_setprio(1); \
  MFMA16(MQ, KS); \
  __builtin_amdgcn_s_setprio(0); \
  GATE_STMT; \
  __builtin_amdgcn_s_barrier(); \
} while (0)

#define GATE6 asm volatile("s_waitcnt vmcnt(6)" ::: "memory")
#define HINT8 asm volatile("s_waitcnt lgkmcnt(8)" ::: "memory")

__global__ __launch_bounds__(512, 2) void gemm64_sk(
    const u16* __restrict__ A, const u16* __restrict__ BT, u16* __restrict__ C,
    int M, int N, int Ktot, int Kslice)
{
  __shared__ u16 sh[2][2][16384]; // 128 KB
  const int nbn = N >> 8;
  const int nwg = gridDim.x;
  const int bid = blockIdx.x;
  const int o = (bid & 7) * (nwg >> 3) + (bid >> 3);
  const int bn = o % nbn, bm = o / nbn;   // A-panels per XCD
  const int kbase = blockIdx.y * Kslice;
  const int NI = Kslice >> 7;

  const int t = threadIdx.x, w = t >> 6, lane = t & 63;
  const int wr = w >> 2, wc = w & 3;
  const int lr = lane & 15, lg = lane >> 4;
  const int r8 = lane >> 3, ch = lane & 7;
  const int clog = ch ^ r8;
  const int w16o  = w * 16 + ((w >= 4) ? 64 : 0);
  const int w16o2 = w * 16;

  const u16* gA[2][2]; const u16* gB[2][2];
  #pragma unroll
  for (int h = 0; h < 2; ++h)
    #pragma unroll
    for (int qq = 0; qq < 2; ++qq) {
      gA[h][qq] = A  + (size_t)(bm * 256 + h * 64  + w16o  + qq * 8 + r8) * Ktot + kbase + clog * 8;
      gB[h][qq] = BT + (size_t)(bn * 256 + h * 128 + w16o2 + qq * 8 + r8) * Ktot + kbase + clog * 8;
    }
  u16* sA0 = &sh[0][0][0]; u16* sA1 = &sh[1][0][0];
  u16* sB0 = &sh[0][1][0]; u16* sB1 = &sh[1][1][0];
  const int cks0 = ((0 + lg) ^ (lr & 7)) * 8;
  const int cks1 = ((4 + lg) ^ (lr & 7)) * 8;
  const u16* pA_b0 = sA0 + (wr * 128 + lr) * 64;
  const u16* pA_b1 = sA1 + (wr * 128 + lr) * 64;
  const u16* pB_b0 = sB0 + (wc * 64 + lr) * 64;
  const u16* pB_b1 = sB1 + (wc * 64 + lr) * 64;

  f32x4 acc[2][4][4];
  const f32x4 z4 = { 0.f, 0.f, 0.f, 0.f };
  #pragma unroll
  for (int a = 0; a < 2; ++a)
    #pragma unroll
    for (int b = 0; b < 4; ++b)
      #pragma unroll
      for (int c = 0; c < 4; ++c) acc[a][b][c] = z4;
  short8 af0, af1, af2, af3;
  short8 bf00, bf01, bf02, bf03, bf10, bf11, bf12, bf13;

  SG_B(sB0, 0, 0); SG_B(sB0, 1, 0); SG_A(sA0, 0, 0); SG_A(sA0, 1, 0);
  SG_B(sB1, 0, 1); SG_B(sB1, 1, 1); SG_A(sA1, 0, 1);
  GATE6;
  __builtin_amdgcn_s_barrier();

  for (int i = 0; i < NI; ++i) {
    const int k2 = 2 * i;
    const bool st = (i < NI - 1);
    DS_B(pB_b0);
    P_CORE(pA_b0, 0, 0, SG_A(sA1, 1, k2 + 1), HINT8, );
    P_CORE(pA_b0, 1, 0, if (st) SG_B(sB0, 0, k2 + 2), , );
    P_CORE(pA_b0, 0, 1, if (st) SG_B(sB0, 1, k2 + 2), , );
    P_CORE(pA_b0, 1, 1, if (st) SG_A(sA0, 0, k2 + 2), ,
           if (st) { GATE6; } else { GATE0; });
    DS_B(pB_b1);
    P_CORE(pA_b1, 0, 0, if (st) SG_A(sA0, 1, k2 + 2), HINT8, );
    P_CORE(pA_b1, 1, 0, if (st) SG_B(sB1, 0, k2 + 3), , );
    P_CORE(pA_b1, 0, 1, if (st) SG_B(sB1, 1, k2 + 3), , );
    P_CORE(pA_b1, 1, 1, if (st) SG_A(sA1, 0, k2 + 3), ,
           if (st) { GATE6; });
  }

  u16* Co = C + (size_t)blockIdx.y * M * N;
  #pragma unroll
  for (int mq = 0; mq < 2; ++mq)
    #pragma unroll
    for (int m = 0; m < 4; ++m)
      #pragma unroll
      for (int n = 0; n < 4; ++n)
        #pragma unroll
        for (int rr = 0; rr < 4; ++rr) {
          const int row = bm * 256 + wr * 128 + mq * 64 + m * 16 + lg * 4 + rr;
          const int col = bn * 256 + wc * 64 + n * 16 + lr;
          Co[(size_t)row * N + col] = f2bf(acc[mq][m][n][rr]);
        }
}

// ---------------- combined q + kv projection (one dispatch, 512 blocks = 2/CU) ----------------
__global__ __launch_bounds__(256) void qkv_proj(
    const u16* __restrict__ xn, const u16* __restrict__ WqT, u16* __restrict__ qbuf,
    const u16* __restrict__ cn, const u16* __restrict__ WkvT, u16* __restrict__ kvpart)
{
  __shared__ u16 As[128 * 32];
  __shared__ u16 Bs[128 * 32];
  const int bm = blockIdx.y;
  const u16* A; const u16* BT; u16* Cp;
  int N, Kslice, bn, z;
  if (blockIdx.z == 0) { A = xn; BT = WqT;  Cp = qbuf;   N = 1024; Kslice = 1024; bn = blockIdx.x; z = 0; }
  else                 { A = cn; BT = WkvT; Cp = kvpart; N = 128;  Kslice = 128;  bn = 0; z = blockIdx.x; }
  const int Ktot = 1024, M = 4096;

  const int t = threadIdx.x;
  const int w = t >> 6, lane = t & 63;
  const int wr = w >> 1, wc = w & 1;
  const int lr = lane & 15, lkc = lane >> 4;

  f32x4 acc[4][4];
  const f32x4 z4 = { 0.f, 0.f, 0.f, 0.f };
  #pragma unroll
  for (int mi = 0; mi < 4; ++mi)
    #pragma unroll
    for (int ni = 0; ni < 4; ++ni) acc[mi][ni] = z4;

  const int kbase = z * Kslice;
  const int i0 = t, i1 = t + 256;
  const int r0 = i0 >> 2, k0 = swz4(r0, i0 & 3) * 8;
  const int r1 = i1 >> 2, k1 = swz4(r1, i1 & 3) * 8;
  const u16* a0 = A + (size_t)(bm * 128 + r0) * Ktot + kbase + k0;
  const u16* a1 = A + (size_t)(bm * 128 + r1) * Ktot + kbase + k1;
  const u16* b0 = BT + (size_t)(bn * 128 + r0) * Ktot + kbase + k0;
  const u16* b1 = BT + (size_t)(bn * 128 + r1) * Ktot + kbase + k1;
  u16* As0 = As + (size_t)w * 512;
  u16* As1 = As + (size_t)(w + 4) * 512;
  u16* Bs0 = Bs + (size_t)w * 512;
  u16* Bs1 = Bs + (size_t)(w + 4) * 512;

  const int nk = Kslice >> 5;
  for (int kt = 0; kt < nk; ++kt) {
    __syncthreads();
    GLDS16(a0, As0); GLDS16(a1, As1); GLDS16(b0, Bs0); GLDS16(b1, Bs1);
    a0 += 32; a1 += 32; b0 += 32; b1 += 32;
    __syncthreads();
    short8 af[4], bf[4];
    #pragma unroll
    for (int mi = 0; mi < 4; ++mi) {
      int row = wr * 64 + mi * 16 + lr;
      af[mi] = *(const short8*)&As[row * 32 + swz4(row, lkc) * 8];
    }
    #pragma unroll
    for (int ni = 0; ni < 4; ++ni) {
      int row = wc * 64 + ni * 16 + lr;
      bf[ni] = *(const short8*)&Bs[row * 32 + swz4(row, lkc) * 8];
    }
    #pragma unroll
    for (int mi = 0; mi < 4; ++mi)
      #pragma unroll
      for (int ni = 0; ni < 4; ++ni)
        acc[mi][ni] = __builtin_amdgcn_mfma_f32_16x16x32_bf16(af[mi], bf[ni], acc[mi][ni], 0, 0, 0);
  }

  u16* Cz = Cp + (size_t)z * M * N;
  const int row0 = bm * 128 + wr * 64, col0 = bn * 128 + wc * 64;
  const int rsub = (lane >> 4) * 4;
  #pragma unroll
  for (int mi = 0; mi < 4; ++mi)
    #pragma unroll
    for (int ni = 0; ni < 4; ++ni)
      #pragma unroll
      for (int r = 0; r < 4; ++r)
        Cz[(size_t)(row0 + mi * 16 + rsub + r) * N + (col0 + ni * 16 + lr)] = f2bf(acc[mi][ni][r]);
}

// ---------------- reduce 8 bf16 partials (4096x128) -> bf16 ----------------
__global__ __launch_bounds__(256) void reduce_kv(const u16* __restrict__ part, u16* __restrict__ out)
{
  const size_t base = ((size_t)blockIdx.x * 256 + threadIdx.x) * 8;
  float s[8] = { 0.f, 0.f, 0.f, 0.f, 0.f, 0.f, 0.f, 0.f };
  #pragma unroll
  for (int zz = 0; zz < 8; ++zz) {
    const short8 v = *(const short8*)&part[(size_t)zz * 524288 + base];
    #pragma unroll
    for (int i = 0; i < 8; ++i) s[i] += bf2f((u16)v[i]);
  }
  union { u16 o[8]; uint4 v; } pk;
  #pragma unroll
  for (int i = 0; i < 8; ++i) pk.o[i] = f2bf(s[i]);
  *(uint4*)&out[base] = pk.v;
}

// ---------------- out = sum of 4 bf16 partials (4096x1024) -> f32 ----------------
__global__ __launch_bounds__(256) void reduce_out(const u16* __restrict__ part, float* __restrict__ out)
{
  const size_t base = ((size_t)blockIdx.x * 256 + threadIdx.x) * 8;
  float s[8] = { 0.f, 0.f, 0.f, 0.f, 0.f, 0.f, 0.f, 0.f };
  #pragma unroll
  for (int zz = 0; zz < 4; ++zz) {
    const short8 v = *(const short8*)&part[(size_t)zz * 4194304 + base];
    #pragma unroll
    for (int i = 0; i < 8; ++i) s[i] += bf2f((u16)v[i]);
  }
  f32x4 lo = { s[0], s[1], s[2], s[3] };
  f32x4 hi = { s[4], s[5], s[6], s[7] };
  *(f32x4*)&out[base] = lo;
  *(f32x4*)&out[base + 4] = hi;
}

// ---------------- flash cross-attention (multi-query: 1 KV head) ----------------
// 8 waves x 512 threads, 256 blocks. T12 in-register P: P never touches LDS.
// Swapped QK^T: s[j32][r] = S[q=lane&31][j = j32*32 + (r&3)+8*(r>>2)+4*hl].
// B-operand frag for PV k-slot kk needs P[j = kk*16 + hl*8 + i][q], i=0..7.
//   c[i] = cvtpk(p[2i],p[2i+1]) (own pairs), x[i] = shfl_xor(c[i],32) (partner pairs).
//   kk=2*j32:   hl=0 -> {c0,c1,x0,x1};  hl=1 -> {x2,x3,c2,c3}
//   kk=2*j32+1: hl=0 -> {c4,c5,x4,x5};  hl=1 -> {x6,x7,c6,c7}
__global__ __launch_bounds__(512, 1) void attn_kernel(
    const u16* __restrict__ q, const u16* __restrict__ kv, u16* __restrict__ o)
{
  __shared__ u16 Ks[128 * 64];
  __shared__ u16 Vt[64 * 128];
  __shared__ u16 Es[8][2048];   // per-wave epilogue scratch (4 KB each)
  const int b = blockIdx.z, hb = blockIdx.y, qb = blockIdx.x;
  const int t = threadIdx.x, w = t >> 6, lane = t & 63;
  const int q32 = lane & 31, hl = lane >> 5;
  const int hd = hb * 4 + (w >> 1);
  const int t32 = w & 1;

  const size_t qbase = (size_t)b * 2048 + qb * 64;
  short8 qa[4];
  #pragma unroll
  for (int dq = 0; dq < 4; ++dq)
    qa[dq] = *(const short8*)&q[(qbase + t32 * 32 + q32) * 1024 + hd * 64 + dq * 16 + hl * 8];

  f32x16 oacc[2];
  #pragma unroll
  for (int j = 0; j < 2; ++j)
    #pragma unroll
    for (int r = 0; r < 16; ++r) oacc[j][r] = 0.f;
  float m_ = -1e30f, l_ = 0.f;

  const size_t kvb = (size_t)b * 2048 * 128;
  const int vd0 = (t & 7) * 8;
  const int vodd = (t >> 3) & 1;

  uint4 vhold[2];
  #pragma unroll
  for (int c = 0; c < 2; ++c) {
    const int vj = (c * 512 + t) >> 3;
    vhold[c] = *(const uint4*)&kv[kvb + (size_t)vj * 128 + 64 + vd0];
  }

  for (int jt = 0; jt < 16; ++jt) {
    __syncthreads();
    #pragma unroll
    for (int n = 0; n < 2; ++n) {
      const int cc = n * 512 + w * 64;
      const int ccl = cc + lane;
      const int row = ccl >> 3, lc = (ccl & 7) ^ (row & 7);
      GLDS16(&kv[kvb + (size_t)(jt * 128 + row) * 128 + lc * 8], Ks + (size_t)cc * 8);
    }
    #pragma unroll
    for (int c = 0; c < 2; ++c) {
      const int seg = c * 512 + t;
      const int vj = seg >> 3;
      const int jp = vj >> 1;
      const uint4 vv = vhold[c];
      uint4 pvv;
      pvv.x = __shfl_xor((int)vv.x, 8);
      pvv.y = __shfl_xor((int)vv.y, 8);
      pvv.z = __shfl_xor((int)vv.z, 8);
      pvv.w = __shfl_xor((int)vv.w, 8);
      const unsigned ow[4] = { vv.x, vv.y, vv.z, vv.w };
      const unsigned pw[4] = { pvv.x, pvv.y, pvv.z, pvv.w };
      if (!vodd) {
        #pragma unroll
        for (int u = 0; u < 4; ++u) {
          const int d = vd0 + u;
          const unsigned own = (u & 1) ? (ow[u >> 1] >> 16) : (ow[u >> 1] & 0xffffu);
          const unsigned par = (u & 1) ? (pw[u >> 1] >> 16) : (pw[u >> 1] & 0xffffu);
          const int byteoff = d * 256 + ((4 * jp) ^ (((d & 7) ^ ((d >> 3) & 7)) << 4));
          *(unsigned*)((char*)Vt + byteoff) = own | (par << 16);
        }
      } else {
        #pragma unroll
        for (int u = 0; u < 4; ++u) {
          const int ue = u + 4;
          const int d = vd0 + ue;
          const unsigned own = (ue & 1) ? (ow[ue >> 1] >> 16) : (ow[ue >> 1] & 0xffffu);
          const unsigned par = (ue & 1) ? (pw[ue >> 1] >> 16) : (pw[ue >> 1] & 0xffffu);
          const int byteoff = d * 256 + ((4 * jp) ^ (((d & 7) ^ ((d >> 3) & 7)) << 4));
          *(unsigned*)((char*)Vt + byteoff) = par | (own << 16);
        }
      }
    }
    __builtin_amdgcn_sched_barrier(0);
    if (jt < 15) {
      #pragma unroll
      for (int c = 0; c < 2; ++c) {
        const int vj = (c * 512 + t) >> 3;
        vhold[c] = *(const uint4*)&kv[kvb + (size_t)((jt + 1) * 128 + vj) * 128 + 64 + vd0];
      }
      asm volatile("s_waitcnt vmcnt(2) lgkmcnt(0)" ::: "memory");
    } else {
      asm volatile("s_waitcnt vmcnt(0) lgkmcnt(0)" ::: "memory");
    }
    __builtin_amdgcn_s_barrier();
    __builtin_amdgcn_sched_barrier(0);

    // QK^T
    f32x16 s[4];
    #pragma unroll
    for (int j32 = 0; j32 < 4; ++j32)
      #pragma unroll
      for (int r = 0; r < 16; ++r) s[j32][r] = 0.f;
    __builtin_amdgcn_s_setprio(1);
    #pragma unroll
    for (int j32 = 0; j32 < 4; ++j32) {
      const int row = j32 * 32 + q32;
      #pragma unroll
      for (int dq = 0; dq < 4; ++dq) {
        const int slot = (dq * 2 + hl) ^ (row & 7);
        const short8 kf = *(const short8*)&Ks[row * 64 + slot * 8];
        s[j32] = __builtin_amdgcn_mfma_f32_32x32x16_bf16(kf, qa[dq], s[j32], 0, 0, 0);
      }
    }
    __builtin_amdgcn_s_setprio(0);
    // online softmax (T13 defer-max)
    float mt = -1e30f;
    #pragma unroll
    for (int j32 = 0; j32 < 4; ++j32)
      #pragma unroll
      for (int r = 0; r < 16; ++r) mt = fmaxf(mt, s[j32][r]);
    mt = fmaxf(mt, __shfl_xor(mt, 32));
    const bool noresc = (bool)__all(mt <= m_ + 8.0f);
    float nm = m_;
    if (!noresc) {
      nm = fmaxf(m_, mt);
      const float alpha = __expf(m_ - nm);
      m_ = nm;
      l_ *= alpha;
      #pragma unroll
      for (int d32 = 0; d32 < 2; ++d32)
        #pragma unroll
        for (int r = 0; r < 16; ++r) oacc[d32][r] *= alpha;
    }
    // T12: P -> bf16 fragments fully in registers (cvtpk pairs + shfl_xor(32) + hl-select)
    float lsum = 0.f;
    short8 pfr[8];
    #pragma unroll
    for (int j32 = 0; j32 < 4; ++j32) {
      float p[16];
      #pragma unroll
      for (int r = 0; r < 16; ++r) { p[r] = __expf(s[j32][r] - nm); lsum += p[r]; }
      unsigned c[8], xx[8];
      #pragma unroll
      for (int i = 0; i < 8; ++i) c[i] = cvtpk(p[2 * i], p[2 * i + 1]);
      #pragma unroll
      for (int i = 0; i < 8; ++i) xx[i] = (unsigned)__shfl_xor((int)c[i], 32);
      union { unsigned u[4]; short8 s8; } f0, f1;
      f0.u[0] = hl ? xx[2] : c[0];
      f0.u[1] = hl ? xx[3] : c[1];
      f0.u[2] = hl ? c[2]  : xx[0];
      f0.u[3] = hl ? c[3]  : xx[1];
      f1.u[0] = hl ? xx[6] : c[4];
      f1.u[1] = hl ? xx[7] : c[5];
      f1.u[2] = hl ? c[6]  : xx[4];
      f1.u[3] = hl ? c[7]  : xx[5];
      pfr[2 * j32]     = f0.s8;
      pfr[2 * j32 + 1] = f1.s8;
    }
    lsum += __shfl_xor(lsum, 32);
    l_ += lsum;
    // PV
    __builtin_amdgcn_s_setprio(1);
    #pragma unroll
    for (int d32 = 0; d32 < 2; ++d32) {
      const int dr = d32 * 32 + q32;
      const int vswz = ((dr & 7) ^ ((dr >> 3) & 7)) << 4;
      #pragma unroll
      for (int kk = 0; kk < 8; ++kk) {
        const int byteoff = dr * 256 + ((kk * 32 + hl * 16) ^ vswz);
        const short8 vf = *(const short8*)((const char*)Vt + byteoff);
        oacc[d32] = __builtin_amdgcn_mfma_f32_32x32x16_bf16(vf, pfr[kk], oacc[d32], 0, 0, 0);
      }
    }
    __builtin_amdgcn_s_setprio(0);
  }

  // epilogue: normalize, transpose O^T -> O via per-wave scratch, store bf16
  float* Ot = (float*)&Es[w][0];
  const float inv = 1.0f / l_;
  #pragma unroll
  for (int d32 = 0; d32 < 2; ++d32) {
    #pragma unroll
    for (int r = 0; r < 16; ++r) {
      const int d = (r & 3) + 8 * (r >> 2) + 4 * hl;
      const int byteoff = q32 * 128 + ((4 * d) ^ ((q32 & 7) << 4));
      *(float*)((char*)Ot + byteoff) = oacc[d32][r] * inv;
    }
    const int qr = lane >> 1, dc = (lane & 1) * 16;
    union { u16 s[16]; uint4 v[2]; } ob;
    #pragma unroll
    for (int cch = 0; cch < 4; ++cch) {
      const int byteoff = qr * 128 + ((4 * (dc + 4 * cch)) ^ ((qr & 7) << 4));
      const f32x4 vv = *(const f32x4*)((const char*)Ot + byteoff);
      ob.s[cch * 4 + 0] = f2bf(vv[0]);
      ob.s[cch * 4 + 1] = f2bf(vv[1]);
      ob.s[cch * 4 + 2] = f2bf(vv[2]);
      ob.s[cch * 4 + 3] = f2bf(vv[3]);
    }
    u16* orow = &o[(qbase + t32 * 32 + qr) * 5120 + hd * 64 + d32 * 32 + dc];
    *(uint4*)orow = ob.v[0];
    *(uint4*)(orow + 8) = ob.v[1];
  }
}

extern "C" void kernel_launch(void* const* d_in, const int* in_sizes, int n_in,
                              void* d_out, int out_size, void* d_ws, size_t ws_size,
                              hipStream_t stream)
{
  const float* x    = (const float*)d_in[0];
  const float* ctx  = (const float*)d_in[1];
  const float* ng   = (const float*)d_in[2];
  const float* nb   = (const float*)d_in[3];
  const float* cg   = (const float*)d_in[4];
  const float* cb   = (const float*)d_in[5];
  const float* Wq   = (const float*)d_in[6];
  const float* Wkv  = (const float*)d_in[7];
  const float* Wo   = (const float*)d_in[8];
  const float* Wff1 = (const float*)d_in[9];
  const float* Wff2 = (const float*)d_in[10];

  u16* p = (u16*)d_ws;
  u16* WqT   = p; p += (size_t)1024 * 1024;
  u16* W2T   = p; p += (size_t)8192 * 1024;   // Wff1 interleaved
  u16* WkvT  = p; p += (size_t)128 * 1024;
  u16* WcT   = p; p += (size_t)1024 * 5120;
  u16* kvbuf = p; p += (size_t)4096 * 128;
  u16* aoh   = p; p += (size_t)4096 * 5120;
  u16* xn    = p; p += (size_t)4096 * 1024;
  u16* cn    = p; p += (size_t)4096 * 1024;
  u16* qbuf  = p; p += (size_t)4096 * 1024;
  u16* kvpart = p; p += (size_t)8 * 4096 * 128;
  u16* ffpart = xn;    // 32 MB bf16 over xn|cn|qbuf + tail (dead by final GEMM)
  (void)in_sizes; (void)n_in; (void)out_size; (void)ws_size;

  ln_kernel<<<8192, 256, 0, stream>>>(x, ctx, ng, nb, cg, cb, xn, cn);

  transpose_ff1<<<dim3(128, 16), 256, 0, stream>>>(Wff1, W2T);
  transpose_all<<<1568, 256, 0, stream>>>(Wq, Wkv, Wo, Wff2, WqT, WkvT, WcT);

  // ff: aoh[:,1024:] = silu(xn @ Wff1), N=8192 -> 512 blocks = exact 2/CU pack
  gemm32_ff<<<dim3(512), 512, 0, stream>>>(xn, W2T, aoh, 4096, 8192, 1024);
  // q + kv projections in one dispatch (512 blocks)
  qkv_proj<<<dim3(8, 32, 2), 256, 0, stream>>>(xn, WqT, qbuf, cn, WkvT, kvpart);
  reduce_kv<<<256, 256, 0, stream>>>(kvpart, kvbuf);
  // attention -> aoh[:,0:1024]; in-register P (T12)
  attn_kernel<<<dim3(32, 4, 2), 512, 0, stream>>>(qbuf, kvbuf, aoh);
  // out = aoh @ [Wo ; Wff2], split-K 4, bf16 partials
  gemm64_sk<<<dim3(64, 4), 512, 0, stream>>>(aoh, WcT, ffpart, 4096, 1024, 5120, 1280);
  reduce_out<<<2048, 256, 0, stream>>>(ffpart, (float*)d_out);
}

// Round 19
// 247.345 us; speedup vs baseline: 5.5267x; 1.0105x over previous
//
#include <hip/hip_runtime.h>
#include <stdint.h>

typedef unsigned short u16;
typedef __attribute__((ext_vector_type(8))) short short8;
typedef __attribute__((ext_vector_type(4))) float f32x4;
typedef __attribute__((ext_vector_type(16))) float f32x16;

#define GPTR(p) ((const __attribute__((address_space(1))) void*)(p))
#define SPTR(p) ((__attribute__((address_space(3))) void*)(p))
#define GLDS16(g, l) __builtin_amdgcn_global_load_lds(GPTR(g), SPTR(l), 16, 0, 0)

static __device__ __forceinline__ float bf2f(u16 u) {
  union { unsigned int i; float f; } c; c.i = ((unsigned int)u) << 16; return c.f;
}
static __device__ __forceinline__ u16 f2bf(float f) {
  union { float f; unsigned int u; } c; c.f = f;
  unsigned int r = 0x7fffu + ((c.u >> 16) & 1u);
  return (u16)((c.u + r) >> 16);
}
static __device__ __forceinline__ unsigned cvtpk(float a, float b) {
  unsigned r;
  asm volatile("v_cvt_pk_bf16_f32 %0, %1, %2" : "=v"(r) : "v"(a), "v"(b));
  return r;
}
static __device__ __forceinline__ int swz4(int row, int c) { return c ^ ((row >> 1) & 3); }

// ---------------- merged prep: LN (x,ctx) + Wff1 interleave-T + {Wq,Wkv,Wo,Wff2} T ----------------
// ids 0..8191: LN row; 8192..10239: transpose_ff1; 10240..11807: transpose_all.
__global__ __launch_bounds__(256) void prep_kernel(
    const float* __restrict__ x, const float* __restrict__ ctx,
    const float* __restrict__ g, const float* __restrict__ b,
    const float* __restrict__ cg, const float* __restrict__ cb,
    u16* __restrict__ xn, u16* __restrict__ cn,
    const float* __restrict__ Wff1, u16* __restrict__ W2T,
    const float* __restrict__ Wq, const float* __restrict__ Wkv,
    const float* __restrict__ Wo, const float* __restrict__ Wff2,
    u16* __restrict__ WqT, u16* __restrict__ WkvT, u16* __restrict__ WcT)
{
  const int bid = blockIdx.x;
  const int t = threadIdx.x;

  if (bid < 8192) {
    // ---- LayerNorm ----
    const int row = bid;
    const float* src; const float* gg; const float* bb; u16* dst;
    if (row < 4096) { src = x + (size_t)row * 1024; gg = g;  bb = b;  dst = xn + (size_t)row * 1024; }
    else            { src = ctx + (size_t)(row - 4096) * 1024; gg = cg; bb = cb; dst = cn + (size_t)(row - 4096) * 1024; }
    float4 v = *(const float4*)&src[t * 4];
    float s  = v.x + v.y + v.z + v.w;
    float s2 = v.x * v.x + v.y * v.y + v.z * v.z + v.w * v.w;
    #pragma unroll
    for (int off = 1; off < 64; off <<= 1) { s += __shfl_xor(s, off); s2 += __shfl_xor(s2, off); }
    __shared__ float ls[4], ls2[4];
    const int w = t >> 6;
    if ((t & 63) == 0) { ls[w] = s; ls2[w] = s2; }
    __syncthreads();
    s  = ls[0] + ls[1] + ls[2] + ls[3];
    s2 = ls2[0] + ls2[1] + ls2[2] + ls2[3];
    const float mu   = s * (1.0f / 1024.0f);
    const float var  = s2 * (1.0f / 1024.0f) - mu * mu;
    const float rstd = rsqrtf(var + 1e-5f);
    float xv[4] = { v.x, v.y, v.z, v.w };
    u16 o[4];
    #pragma unroll
    for (int i = 0; i < 4; ++i)
      o[i] = f2bf((xv[i] - mu) * rstd * gg[t * 4 + i] + bb[t * 4 + i]);
    uint2 pv;
    pv.x = (unsigned)o[0] | ((unsigned)o[1] << 16);
    pv.y = (unsigned)o[2] | ((unsigned)o[3] << 16);
    *(uint2*)&dst[t * 4] = pv;
    return;
  }

  __shared__ float tile[64][65];
  const int tr = t >> 4, tc = (t & 15) * 4;

  if (bid < 10240) {
    // ---- transpose_ff1 with (a,gate) interleave ----
    const int id = bid - 8192;
    const int c0 = (id & 127) * 64, r0 = (id >> 7) * 64;
    #pragma unroll
    for (int i = 0; i < 4; ++i) {
      int r = tr + i * 16;
      float4 v = *(const float4*)&Wff1[(size_t)(r0 + r) * 8192 + c0 + tc];
      tile[r][tc + 0] = v.x; tile[r][tc + 1] = v.y; tile[r][tc + 2] = v.z; tile[r][tc + 3] = v.w;
    }
    __syncthreads();
    #pragma unroll
    for (int i = 0; i < 2; ++i) {
      int c  = (t >> 3) + i * 32;
      int rb = (t & 7) * 8;
      const int gc = c0 + c;
      int j, add16;
      if (gc < 4096) { j = gc; add16 = 0; } else { j = gc - 4096; add16 = 16; }
      const int row = ((j >> 7) << 8) + (((j >> 5) & 3) << 6) + (((j >> 4) & 1) << 5) + add16 + (j & 15);
      union { u16 s[8]; uint4 v; } pk;
      #pragma unroll
      for (int u = 0; u < 8; ++u) pk.s[u] = f2bf(tile[rb + u][c]);
      *(uint4*)&W2T[(size_t)row * 1024 + r0 + rb] = pk.v;
    }
    return;
  }

  // ---- transpose_all ----
  int id = bid - 10240;
  const float* in; u16* out; int C, ldo, cx; float scale;
  if (id < 256)      {           in = Wq;   out = WqT;        C = 1024; ldo = 1024; scale = 0.125f; cx = 16; }
  else if (id < 288) { id -= 256; in = Wkv;  out = WkvT;       C = 128;  ldo = 1024; scale = 1.0f;   cx = 2;  }
  else if (id < 544) { id -= 288; in = Wo;   out = WcT;        C = 1024; ldo = 5120; scale = 1.0f;   cx = 16; }
  else               { id -= 544; in = Wff2; out = WcT + 1024; C = 1024; ldo = 5120; scale = 1.0f;   cx = 16; }
  const int c0 = (id % cx) * 64, r0 = (id / cx) * 64;
  #pragma unroll
  for (int i = 0; i < 4; ++i) {
    int r = tr + i * 16;
    float4 v = *(const float4*)&in[(size_t)(r0 + r) * C + c0 + tc];
    tile[r][tc + 0] = v.x; tile[r][tc + 1] = v.y; tile[r][tc + 2] = v.z; tile[r][tc + 3] = v.w;
  }
  __syncthreads();
  #pragma unroll
  for (int i = 0; i < 2; ++i) {
    int c  = (t >> 3) + i * 32;
    int rb = (t & 7) * 8;
    union { u16 s[8]; uint4 v; } pk;
    #pragma unroll
    for (int u = 0; u < 8; ++u) pk.s[u] = f2bf(tile[rb + u][c] * scale);
    *(uint4*)&out[(size_t)(c0 + c) * ldo + r0 + rb] = pk.v;
  }
}

// =============== BK=32 4-phase 256x256 GEMM (ff: N=8192, 512 blocks = exact 2/CU pack) ===============
#define MM32(MQ, M, NN) acc[MQ][M][NN] = __builtin_amdgcn_mfma_f32_16x16x32_bf16(af##M, bf##NN, acc[MQ][M][NN], 0, 0, 0)
#define MFMA16_32(MQ) \
  MM32(MQ,0,0); MM32(MQ,0,1); MM32(MQ,0,2); MM32(MQ,0,3); \
  MM32(MQ,1,0); MM32(MQ,1,1); MM32(MQ,1,2); MM32(MQ,1,3); \
  MM32(MQ,2,0); MM32(MQ,2,1); MM32(MQ,2,2); MM32(MQ,2,3); \
  MM32(MQ,3,0); MM32(MQ,3,1); MM32(MQ,3,2); MM32(MQ,3,3)

#define SA32(SBUF, H, KT) GLDS16(gA32[H] + ((size_t)(KT) << 5), SBUF + (size_t)((H) * 64 + w16o) * 32)
#define SB32(SBUF, H, KT) GLDS16(gB32[H] + ((size_t)(KT) << 5), SBUF + (size_t)((H) * 128 + w16o2) * 32)

#define DSB32(PB_) do { \
  bf0 = *(const short8*)(PB_ + 0    + cks); bf1 = *(const short8*)(PB_ + 512  + cks); \
  bf2 = *(const short8*)(PB_ + 1024 + cks); bf3 = *(const short8*)(PB_ + 1536 + cks); \
} while (0)

#define PC32(PA_, MQ, STAGE_STMT, GATE_STMT) do { \
  af0 = *(const short8*)(PA_ + (MQ) * 2048 + 0    + cks); \
  af1 = *(const short8*)(PA_ + (MQ) * 2048 + 512  + cks); \
  af2 = *(const short8*)(PA_ + (MQ) * 2048 + 1024 + cks); \
  af3 = *(const short8*)(PA_ + (MQ) * 2048 + 1536 + cks); \
  STAGE_STMT; \
  __builtin_amdgcn_s_barrier(); \
  asm volatile("s_waitcnt lgkmcnt(0)" ::: "memory"); \
  __builtin_amdgcn_s_setprio(1); \
  MFMA16_32(MQ); \
  __builtin_amdgcn_s_setprio(0); \
  GATE_STMT; \
  __builtin_amdgcn_s_barrier(); \
} while (0)

#define GATE3 asm volatile("s_waitcnt vmcnt(3)" ::: "memory")
#define GATE0 asm volatile("s_waitcnt vmcnt(0)" ::: "memory")

__global__ __launch_bounds__(512, 2) void gemm32_ff(
    const u16* __restrict__ A, const u16* __restrict__ BT, u16* __restrict__ Ho,
    int M, int N, int Ktot)
{
  __shared__ u16 sh[2][2][8192]; // 64 KB
  const int nbm = M >> 8;
  const int nwg = gridDim.x;
  const int bid = blockIdx.x;
  const int o = (bid & 7) * (nwg >> 3) + (bid >> 3);
  const int bm = o % nbm, bn = o / nbm;   // B-strip per XCD
  const int NI = Ktot >> 6;

  const int t = threadIdx.x, w = t >> 6, lane = t & 63;
  const int wr = w >> 2, wc = w & 3;
  const int lr = lane & 15, lg = lane >> 4;
  const int l4 = lane >> 2, sl = lane & 3;
  const int w16o  = w * 16 + ((w >= 4) ? 64 : 0);
  const int w16o2 = w * 16;

  const u16* gA32[2]; const u16* gB32[2];
  #pragma unroll
  for (int h = 0; h < 2; ++h) {
    const int rowA = h * 64 + w16o + l4;
    gA32[h] = A + (size_t)(bm * 256 + rowA) * Ktot + (size_t)((sl ^ ((rowA >> 1) & 3)) * 8);
    const int rowB = h * 128 + w16o2 + l4;
    gB32[h] = BT + (size_t)(bn * 256 + rowB) * Ktot + (size_t)((sl ^ ((rowB >> 1) & 3)) * 8);
  }
  u16* sA0 = &sh[0][0][0]; u16* sA1 = &sh[1][0][0];
  u16* sB0 = &sh[0][1][0]; u16* sB1 = &sh[1][1][0];
  const int cks = (lg ^ ((lr >> 1) & 3)) * 8;
  const u16* pA_b0 = sA0 + (wr * 128 + lr) * 32;
  const u16* pA_b1 = sA1 + (wr * 128 + lr) * 32;
  const u16* pB_b0 = sB0 + (wc * 64 + lr) * 32;
  const u16* pB_b1 = sB1 + (wc * 64 + lr) * 32;

  f32x4 acc[2][4][4];
  const f32x4 z4 = { 0.f, 0.f, 0.f, 0.f };
  #pragma unroll
  for (int a = 0; a < 2; ++a)
    #pragma unroll
    for (int b = 0; b < 4; ++b)
      #pragma unroll
      for (int c = 0; c < 4; ++c) acc[a][b][c] = z4;
  short8 af0, af1, af2, af3;
  short8 bf0, bf1, bf2, bf3;

  SA32(sA0, 0, 0); SA32(sA0, 1, 0); SB32(sB0, 0, 0); SB32(sB0, 1, 0);
  SB32(sB1, 0, 1); SB32(sB1, 1, 1); SA32(sA1, 0, 1);
  GATE3;
  __builtin_amdgcn_s_barrier();

  for (int i = 0; i < NI; ++i) {
    const bool st = (i < NI - 1);
    const int X = 2 * i + 2, Y = 2 * i + 3;
    DSB32(pB_b0);
    PC32(pA_b0, 0, SA32(sA1, 1, 2 * i + 1), );
    PC32(pA_b0, 1,
         if (st) { SB32(sB0, 0, X); SB32(sB0, 1, X); SA32(sA0, 0, X); },
         if (st) { GATE3; } else { GATE0; });
    DSB32(pB_b1);
    PC32(pA_b1, 0, if (st) { SA32(sA0, 1, X); }, );
    PC32(pA_b1, 1,
         if (st) { SB32(sB1, 0, Y); SB32(sB1, 1, Y); SA32(sA1, 0, Y); },
         if (st) { GATE3; });
  }

  const int colb = 1024 + bn * 128 + wc * 32 + lr;
  #pragma unroll
  for (int mq = 0; mq < 2; ++mq)
    #pragma unroll
    for (int m = 0; m < 4; ++m)
      #pragma unroll
      for (int rr = 0; rr < 4; ++rr) {
        const int row = bm * 256 + wr * 128 + mq * 64 + m * 16 + lg * 4 + rr;
        #pragma unroll
        for (int n2 = 0; n2 < 2; ++n2) {
          const float a = acc[mq][m][2 * n2][rr];
          const float gt = acc[mq][m][2 * n2 + 1][rr];
          const float h = a * gt / (1.0f + __expf(-gt));
          Ho[(size_t)row * 5120 + colb + n2 * 16] = f2bf(h);
        }
      }
}

// =============== BK=64 8-phase 256x256 GEMM (final GEMM, split-K 4, bf16 partials) ===============
#define MM1(MQ, M, NN, BF) acc[MQ][M][NN] = __builtin_amdgcn_mfma_f32_16x16x32_bf16(af##M, BF, acc[MQ][M][NN], 0, 0, 0)
#define MFMA16(MQ, KS) \
  MM1(MQ,0,0,bf##KS##0); MM1(MQ,0,1,bf##KS##1); MM1(MQ,0,2,bf##KS##2); MM1(MQ,0,3,bf##KS##3); \
  MM1(MQ,1,0,bf##KS##0); MM1(MQ,1,1,bf##KS##1); MM1(MQ,1,2,bf##KS##2); MM1(MQ,1,3,bf##KS##3); \
  MM1(MQ,2,0,bf##KS##0); MM1(MQ,2,1,bf##KS##1); MM1(MQ,2,2,bf##KS##2); MM1(MQ,2,3,bf##KS##3); \
  MM1(MQ,3,0,bf##KS##0); MM1(MQ,3,1,bf##KS##1); MM1(MQ,3,2,bf##KS##2); MM1(MQ,3,3,bf##KS##3)

#define SG_A(SBUF, H, KT) do { \
    GLDS16(gA[H][0] + ((size_t)(KT) << 6), SBUF + ((H) * 64 + w16o) * 64); \
    GLDS16(gA[H][1] + ((size_t)(KT) << 6), SBUF + ((H) * 64 + w16o + 8) * 64); \
  } while (0)
#define SG_B(SBUF, H, KT) do { \
    GLDS16(gB[H][0] + ((size_t)(KT) << 6), SBUF + ((H) * 128 + w16o2) * 64); \
    GLDS16(gB[H][1] + ((size_t)(KT) << 6), SBUF + ((H) * 128 + w16o2 + 8) * 64); \
  } while (0)

#define DS_B(PB_) do { \
  bf00 = *(const short8*)(PB_ + 0    + cks0); bf01 = *(const short8*)(PB_ + 1024 + cks0); \
  bf02 = *(const short8*)(PB_ + 2048 + cks0); bf03 = *(const short8*)(PB_ + 3072 + cks0); \
  bf10 = *(const short8*)(PB_ + 0    + cks1); bf11 = *(const short8*)(PB_ + 1024 + cks1); \
  bf12 = *(const short8*)(PB_ + 2048 + cks1); bf13 = *(const short8*)(PB_ + 3072 + cks1); \
} while (0)

#define P_CORE(PA_, MQ, KS, STAGE_STMT, PREB_STMT, GATE_STMT) do { \
  af0 = *(const short8*)(PA_ + (MQ) * 4096 + 0    + cks##KS); \
  af1 = *(const short8*)(PA_ + (MQ) * 4096 + 1024 + cks##KS); \
  af2 = *(const short8*)(PA_ + (MQ) * 4096 + 2048 + cks##KS); \
  af3 = *(const short8*)(PA_ + (MQ) * 4096 + 3072 + cks##KS); \
  STAGE_STMT; \
  PREB_STMT; \
  __builtin_amdgcn_s_barrier(); \
  asm volatile("s_waitcnt lgkmcnt(0)" ::: "memory"); \
  __builtin_amdgcn_s_setprio(1); \
  MFMA16(MQ, KS); \
  __builtin_amdgcn_s_setprio(0); \
  GATE_STMT; \
  __builtin_amdgcn_s_barrier(); \
} while (0)

#define GATE6 asm volatile("s_waitcnt vmcnt(6)" ::: "memory")
#define HINT8 asm volatile("s_waitcnt lgkmcnt(8)" ::: "memory")

__global__ __launch_bounds__(512, 2) void gemm64_sk(
    const u16* __restrict__ A, const u16* __restrict__ BT, u16* __restrict__ C,
    int M, int N, int Ktot, int Kslice)
{
  __shared__ u16 sh[2][2][16384]; // 128 KB
  const int nbn = N >> 8;
  const int nwg = gridDim.x;
  const int bid = blockIdx.x;
  const int o = (bid & 7) * (nwg >> 3) + (bid >> 3);
  const int bn = o % nbn, bm = o / nbn;   // A-panels per XCD
  const int kbase = blockIdx.y * Kslice;
  const int NI = Kslice >> 7;

  const int t = threadIdx.x, w = t >> 6, lane = t & 63;
  const int wr = w >> 2, wc = w & 3;
  const int lr = lane & 15, lg = lane >> 4;
  const int r8 = lane >> 3, ch = lane & 7;
  const int clog = ch ^ r8;
  const int w16o  = w * 16 + ((w >= 4) ? 64 : 0);
  const int w16o2 = w * 16;

  const u16* gA[2][2]; const u16* gB[2][2];
  #pragma unroll
  for (int h = 0; h < 2; ++h)
    #pragma unroll
    for (int qq = 0; qq < 2; ++qq) {
      gA[h][qq] = A  + (size_t)(bm * 256 + h * 64  + w16o  + qq * 8 + r8) * Ktot + kbase + clog * 8;
      gB[h][qq] = BT + (size_t)(bn * 256 + h * 128 + w16o2 + qq * 8 + r8) * Ktot + kbase + clog * 8;
    }
  u16* sA0 = &sh[0][0][0]; u16* sA1 = &sh[1][0][0];
  u16* sB0 = &sh[0][1][0]; u16* sB1 = &sh[1][1][0];
  const int cks0 = ((0 + lg) ^ (lr & 7)) * 8;
  const int cks1 = ((4 + lg) ^ (lr & 7)) * 8;
  const u16* pA_b0 = sA0 + (wr * 128 + lr) * 64;
  const u16* pA_b1 = sA1 + (wr * 128 + lr) * 64;
  const u16* pB_b0 = sB0 + (wc * 64 + lr) * 64;
  const u16* pB_b1 = sB1 + (wc * 64 + lr) * 64;

  f32x4 acc[2][4][4];
  const f32x4 z4 = { 0.f, 0.f, 0.f, 0.f };
  #pragma unroll
  for (int a = 0; a < 2; ++a)
    #pragma unroll
    for (int b = 0; b < 4; ++b)
      #pragma unroll
      for (int c = 0; c < 4; ++c) acc[a][b][c] = z4;
  short8 af0, af1, af2, af3;
  short8 bf00, bf01, bf02, bf03, bf10, bf11, bf12, bf13;

  SG_B(sB0, 0, 0); SG_B(sB0, 1, 0); SG_A(sA0, 0, 0); SG_A(sA0, 1, 0);
  SG_B(sB1, 0, 1); SG_B(sB1, 1, 1); SG_A(sA1, 0, 1);
  GATE6;
  __builtin_amdgcn_s_barrier();

  for (int i = 0; i < NI; ++i) {
    const int k2 = 2 * i;
    const bool st = (i < NI - 1);
    DS_B(pB_b0);
    P_CORE(pA_b0, 0, 0, SG_A(sA1, 1, k2 + 1), HINT8, );
    P_CORE(pA_b0, 1, 0, if (st) SG_B(sB0, 0, k2 + 2), , );
    P_CORE(pA_b0, 0, 1, if (st) SG_B(sB0, 1, k2 + 2), , );
    P_CORE(pA_b0, 1, 1, if (st) SG_A(sA0, 0, k2 + 2), ,
           if (st) { GATE6; } else { GATE0; });
    DS_B(pB_b1);
    P_CORE(pA_b1, 0, 0, if (st) SG_A(sA0, 1, k2 + 2), HINT8, );
    P_CORE(pA_b1, 1, 0, if (st) SG_B(sB1, 0, k2 + 3), , );
    P_CORE(pA_b1, 0, 1, if (st) SG_B(sB1, 1, k2 + 3), , );
    P_CORE(pA_b1, 1, 1, if (st) SG_A(sA1, 0, k2 + 3), ,
           if (st) { GATE6; });
  }

  u16* Co = C + (size_t)blockIdx.y * M * N;
  #pragma unroll
  for (int mq = 0; mq < 2; ++mq)
    #pragma unroll
    for (int m = 0; m < 4; ++m)
      #pragma unroll
      for (int n = 0; n < 4; ++n)
        #pragma unroll
        for (int rr = 0; rr < 4; ++rr) {
          const int row = bm * 256 + wr * 128 + mq * 64 + m * 16 + lg * 4 + rr;
          const int col = bn * 256 + wc * 64 + n * 16 + lr;
          Co[(size_t)row * N + col] = f2bf(acc[mq][m][n][rr]);
        }
}

// ---------------- combined q + kv projection (one dispatch, 512 blocks = 2/CU) ----------------
__global__ __launch_bounds__(256) void qkv_proj(
    const u16* __restrict__ xn, const u16* __restrict__ WqT, u16* __restrict__ qbuf,
    const u16* __restrict__ cn, const u16* __restrict__ WkvT, u16* __restrict__ kvpart)
{
  __shared__ u16 As[128 * 32];
  __shared__ u16 Bs[128 * 32];
  const int bm = blockIdx.y;
  const u16* A; const u16* BT; u16* Cp;
  int N, Kslice, bn, z;
  if (blockIdx.z == 0) { A = xn; BT = WqT;  Cp = qbuf;   N = 1024; Kslice = 1024; bn = blockIdx.x; z = 0; }
  else                 { A = cn; BT = WkvT; Cp = kvpart; N = 128;  Kslice = 128;  bn = 0; z = blockIdx.x; }
  const int Ktot = 1024, M = 4096;

  const int t = threadIdx.x;
  const int w = t >> 6, lane = t & 63;
  const int wr = w >> 1, wc = w & 1;
  const int lr = lane & 15, lkc = lane >> 4;

  f32x4 acc[4][4];
  const f32x4 z4 = { 0.f, 0.f, 0.f, 0.f };
  #pragma unroll
  for (int mi = 0; mi < 4; ++mi)
    #pragma unroll
    for (int ni = 0; ni < 4; ++ni) acc[mi][ni] = z4;

  const int kbase = z * Kslice;
  const int i0 = t, i1 = t + 256;
  const int r0 = i0 >> 2, k0 = swz4(r0, i0 & 3) * 8;
  const int r1 = i1 >> 2, k1 = swz4(r1, i1 & 3) * 8;
  const u16* a0 = A + (size_t)(bm * 128 + r0) * Ktot + kbase + k0;
  const u16* a1 = A + (size_t)(bm * 128 + r1) * Ktot + kbase + k1;
  const u16* b0 = BT + (size_t)(bn * 128 + r0) * Ktot + kbase + k0;
  const u16* b1 = BT + (size_t)(bn * 128 + r1) * Ktot + kbase + k1;
  u16* As0 = As + (size_t)w * 512;
  u16* As1 = As + (size_t)(w + 4) * 512;
  u16* Bs0 = Bs + (size_t)w * 512;
  u16* Bs1 = Bs + (size_t)(w + 4) * 512;

  const int nk = Kslice >> 5;
  for (int kt = 0; kt < nk; ++kt) {
    __syncthreads();
    GLDS16(a0, As0); GLDS16(a1, As1); GLDS16(b0, Bs0); GLDS16(b1, Bs1);
    a0 += 32; a1 += 32; b0 += 32; b1 += 32;
    __syncthreads();
    short8 af[4], bf[4];
    #pragma unroll
    for (int mi = 0; mi < 4; ++mi) {
      int row = wr * 64 + mi * 16 + lr;
      af[mi] = *(const short8*)&As[row * 32 + swz4(row, lkc) * 8];
    }
    #pragma unroll
    for (int ni = 0; ni < 4; ++ni) {
      int row = wc * 64 + ni * 16 + lr;
      bf[ni] = *(const short8*)&Bs[row * 32 + swz4(row, lkc) * 8];
    }
    #pragma unroll
    for (int mi = 0; mi < 4; ++mi)
      #pragma unroll
      for (int ni = 0; ni < 4; ++ni)
        acc[mi][ni] = __builtin_amdgcn_mfma_f32_16x16x32_bf16(af[mi], bf[ni], acc[mi][ni], 0, 0, 0);
  }

  u16* Cz = Cp + (size_t)z * M * N;
  const int row0 = bm * 128 + wr * 64, col0 = bn * 128 + wc * 64;
  const int rsub = (lane >> 4) * 4;
  #pragma unroll
  for (int mi = 0; mi < 4; ++mi)
    #pragma unroll
    for (int ni = 0; ni < 4; ++ni)
      #pragma unroll
      for (int r = 0; r < 4; ++r)
        Cz[(size_t)(row0 + mi * 16 + rsub + r) * N + (col0 + ni * 16 + lr)] = f2bf(acc[mi][ni][r]);
}

// ---------------- reduce 8 bf16 partials (4096x128) -> bf16 ----------------
__global__ __launch_bounds__(256) void reduce_kv(const u16* __restrict__ part, u16* __restrict__ out)
{
  const size_t base = ((size_t)blockIdx.x * 256 + threadIdx.x) * 8;
  float s[8] = { 0.f, 0.f, 0.f, 0.f, 0.f, 0.f, 0.f, 0.f };
  #pragma unroll
  for (int zz = 0; zz < 8; ++zz) {
    const short8 v = *(const short8*)&part[(size_t)zz * 524288 + base];
    #pragma unroll
    for (int i = 0; i < 8; ++i) s[i] += bf2f((u16)v[i]);
  }
  union { u16 o[8]; uint4 v; } pk;
  #pragma unroll
  for (int i = 0; i < 8; ++i) pk.o[i] = f2bf(s[i]);
  *(uint4*)&out[base] = pk.v;
}

// ---------------- out = sum of 4 bf16 partials (4096x1024) -> f32 ----------------
__global__ __launch_bounds__(256) void reduce_out(const u16* __restrict__ part, float* __restrict__ out)
{
  const size_t base = ((size_t)blockIdx.x * 256 + threadIdx.x) * 8;
  float s[8] = { 0.f, 0.f, 0.f, 0.f, 0.f, 0.f, 0.f, 0.f };
  #pragma unroll
  for (int zz = 0; zz < 4; ++zz) {
    const short8 v = *(const short8*)&part[(size_t)zz * 4194304 + base];
    #pragma unroll
    for (int i = 0; i < 8; ++i) s[i] += bf2f((u16)v[i]);
  }
  f32x4 lo = { s[0], s[1], s[2], s[3] };
  f32x4 hi = { s[4], s[5], s[6], s[7] };
  *(f32x4*)&out[base] = lo;
  *(f32x4*)&out[base + 4] = hi;
}

// ---------------- flash cross-attention (multi-query: 1 KV head) ----------------
// 8 waves x 512 threads, 256 blocks. T12 in-register P.
__global__ __launch_bounds__(512, 1) void attn_kernel(
    const u16* __restrict__ q, const u16* __restrict__ kv, u16* __restrict__ o)
{
  __shared__ u16 Ks[128 * 64];
  __shared__ u16 Vt[64 * 128];
  __shared__ u16 Es[8][2048];   // per-wave epilogue scratch
  const int b = blockIdx.z, hb = blockIdx.y, qb = blockIdx.x;
  const int t = threadIdx.x, w = t >> 6, lane = t & 63;
  const int q32 = lane & 31, hl = lane >> 5;
  const int hd = hb * 4 + (w >> 1);
  const int t32 = w & 1;

  const size_t qbase = (size_t)b * 2048 + qb * 64;
  short8 qa[4];
  #pragma unroll
  for (int dq = 0; dq < 4; ++dq)
    qa[dq] = *(const short8*)&q[(qbase + t32 * 32 + q32) * 1024 + hd * 64 + dq * 16 + hl * 8];

  f32x16 oacc[2];
  #pragma unroll
  for (int j = 0; j < 2; ++j)
    #pragma unroll
    for (int r = 0; r < 16; ++r) oacc[j][r] = 0.f;
  float m_ = -1e30f, l_ = 0.f;

  const size_t kvb = (size_t)b * 2048 * 128;
  const int vd0 = (t & 7) * 8;
  const int vodd = (t >> 3) & 1;

  uint4 vhold[2];
  #pragma unroll
  for (int c = 0; c < 2; ++c) {
    const int vj = (c * 512 + t) >> 3;
    vhold[c] = *(const uint4*)&kv[kvb + (size_t)vj * 128 + 64 + vd0];
  }

  for (int jt = 0; jt < 16; ++jt) {
    __syncthreads();
    #pragma unroll
    for (int n = 0; n < 2; ++n) {
      const int cc = n * 512 + w * 64;
      const int ccl = cc + lane;
      const int row = ccl >> 3, lc = (ccl & 7) ^ (row & 7);
      GLDS16(&kv[kvb + (size_t)(jt * 128 + row) * 128 + lc * 8], Ks + (size_t)cc * 8);
    }
    #pragma unroll
    for (int c = 0; c < 2; ++c) {
      const int seg = c * 512 + t;
      const int vj = seg >> 3;
      const int jp = vj >> 1;
      const uint4 vv = vhold[c];
      uint4 pvv;
      pvv.x = __shfl_xor((int)vv.x, 8);
      pvv.y = __shfl_xor((int)vv.y, 8);
      pvv.z = __shfl_xor((int)vv.z, 8);
      pvv.w = __shfl_xor((int)vv.w, 8);
      const unsigned ow[4] = { vv.x, vv.y, vv.z, vv.w };
      const unsigned pw[4] = { pvv.x, pvv.y, pvv.z, pvv.w };
      if (!vodd) {
        #pragma unroll
        for (int u = 0; u < 4; ++u) {
          const int d = vd0 + u;
          const unsigned own = (u & 1) ? (ow[u >> 1] >> 16) : (ow[u >> 1] & 0xffffu);
          const unsigned par = (u & 1) ? (pw[u >> 1] >> 16) : (pw[u >> 1] & 0xffffu);
          const int byteoff = d * 256 + ((4 * jp) ^ (((d & 7) ^ ((d >> 3) & 7)) << 4));
          *(unsigned*)((char*)Vt + byteoff) = own | (par << 16);
        }
      } else {
        #pragma unroll
        for (int u = 0; u < 4; ++u) {
          const int ue = u + 4;
          const int d = vd0 + ue;
          const unsigned own = (ue & 1) ? (ow[ue >> 1] >> 16) : (ow[ue >> 1] & 0xffffu);
          const unsigned par = (ue & 1) ? (pw[ue >> 1] >> 16) : (pw[ue >> 1] & 0xffffu);
          const int byteoff = d * 256 + ((4 * jp) ^ (((d & 7) ^ ((d >> 3) & 7)) << 4));
          *(unsigned*)((char*)Vt + byteoff) = par | (own << 16);
        }
      }
    }
    __builtin_amdgcn_sched_barrier(0);
    if (jt < 15) {
      #pragma unroll
      for (int c = 0; c < 2; ++c) {
        const int vj = (c * 512 + t) >> 3;
        vhold[c] = *(const uint4*)&kv[kvb + (size_t)((jt + 1) * 128 + vj) * 128 + 64 + vd0];
      }
      asm volatile("s_waitcnt vmcnt(2) lgkmcnt(0)" ::: "memory");
    } else {
      asm volatile("s_waitcnt vmcnt(0) lgkmcnt(0)" ::: "memory");
    }
    __builtin_amdgcn_s_barrier();
    __builtin_amdgcn_sched_barrier(0);

    f32x16 s[4];
    #pragma unroll
    for (int j32 = 0; j32 < 4; ++j32)
      #pragma unroll
      for (int r = 0; r < 16; ++r) s[j32][r] = 0.f;
    __builtin_amdgcn_s_setprio(1);
    #pragma unroll
    for (int j32 = 0; j32 < 4; ++j32) {
      const int row = j32 * 32 + q32;
      #pragma unroll
      for (int dq = 0; dq < 4; ++dq) {
        const int slot = (dq * 2 + hl) ^ (row & 7);
        const short8 kf = *(const short8*)&Ks[row * 64 + slot * 8];
        s[j32] = __builtin_amdgcn_mfma_f32_32x32x16_bf16(kf, qa[dq], s[j32], 0, 0, 0);
      }
    }
    __builtin_amdgcn_s_setprio(0);
    float mt = -1e30f;
    #pragma unroll
    for (int j32 = 0; j32 < 4; ++j32)
      #pragma unroll
      for (int r = 0; r < 16; ++r) mt = fmaxf(mt, s[j32][r]);
    mt = fmaxf(mt, __shfl_xor(mt, 32));
    const bool noresc = (bool)__all(mt <= m_ + 8.0f);
    float nm = m_;
    if (!noresc) {
      nm = fmaxf(m_, mt);
      const float alpha = __expf(m_ - nm);
      m_ = nm;
      l_ *= alpha;
      #pragma unroll
      for (int d32 = 0; d32 < 2; ++d32)
        #pragma unroll
        for (int r = 0; r < 16; ++r) oacc[d32][r] *= alpha;
    }
    float lsum = 0.f;
    short8 pfr[8];
    #pragma unroll
    for (int j32 = 0; j32 < 4; ++j32) {
      float p[16];
      #pragma unroll
      for (int r = 0; r < 16; ++r) { p[r] = __expf(s[j32][r] - nm); lsum += p[r]; }
      unsigned c[8], xx[8];
      #pragma unroll
      for (int i = 0; i < 8; ++i) c[i] = cvtpk(p[2 * i], p[2 * i + 1]);
      #pragma unroll
      for (int i = 0; i < 8; ++i) xx[i] = (unsigned)__shfl_xor((int)c[i], 32);
      union { unsigned u[4]; short8 s8; } f0, f1;
      f0.u[0] = hl ? xx[2] : c[0];
      f0.u[1] = hl ? xx[3] : c[1];
      f0.u[2] = hl ? c[2]  : xx[0];
      f0.u[3] = hl ? c[3]  : xx[1];
      f1.u[0] = hl ? xx[6] : c[4];
      f1.u[1] = hl ? xx[7] : c[5];
      f1.u[2] = hl ? c[6]  : xx[4];
      f1.u[3] = hl ? c[7]  : xx[5];
      pfr[2 * j32]     = f0.s8;
      pfr[2 * j32 + 1] = f1.s8;
    }
    lsum += __shfl_xor(lsum, 32);
    l_ += lsum;
    __builtin_amdgcn_s_setprio(1);
    #pragma unroll
    for (int d32 = 0; d32 < 2; ++d32) {
      const int dr = d32 * 32 + q32;
      const int vswz = ((dr & 7) ^ ((dr >> 3) & 7)) << 4;
      #pragma unroll
      for (int kk = 0; kk < 8; ++kk) {
        const int byteoff = dr * 256 + ((kk * 32 + hl * 16) ^ vswz);
        const short8 vf = *(const short8*)((const char*)Vt + byteoff);
        oacc[d32] = __builtin_amdgcn_mfma_f32_32x32x16_bf16(vf, pfr[kk], oacc[d32], 0, 0, 0);
      }
    }
    __builtin_amdgcn_s_setprio(0);
  }

  float* Ot = (float*)&Es[w][0];
  const float inv = 1.0f / l_;
  #pragma unroll
  for (int d32 = 0; d32 < 2; ++d32) {
    #pragma unroll
    for (int r = 0; r < 16; ++r) {
      const int d = (r & 3) + 8 * (r >> 2) + 4 * hl;
      const int byteoff = q32 * 128 + ((4 * d) ^ ((q32 & 7) << 4));
      *(float*)((char*)Ot + byteoff) = oacc[d32][r] * inv;
    }
    const int qr = lane >> 1, dc = (lane & 1) * 16;
    union { u16 s[16]; uint4 v[2]; } ob;
    #pragma unroll
    for (int cch = 0; cch < 4; ++cch) {
      const int byteoff = qr * 128 + ((4 * (dc + 4 * cch)) ^ ((qr & 7) << 4));
      const f32x4 vv = *(const f32x4*)((const char*)Ot + byteoff);
      ob.s[cch * 4 + 0] = f2bf(vv[0]);
      ob.s[cch * 4 + 1] = f2bf(vv[1]);
      ob.s[cch * 4 + 2] = f2bf(vv[2]);
      ob.s[cch * 4 + 3] = f2bf(vv[3]);
    }
    u16* orow = &o[(qbase + t32 * 32 + qr) * 5120 + hd * 64 + d32 * 32 + dc];
    *(uint4*)orow = ob.v[0];
    *(uint4*)(orow + 8) = ob.v[1];
  }
}

extern "C" void kernel_launch(void* const* d_in, const int* in_sizes, int n_in,
                              void* d_out, int out_size, void* d_ws, size_t ws_size,
                              hipStream_t stream)
{
  const float* x    = (const float*)d_in[0];
  const float* ctx  = (const float*)d_in[1];
  const float* ng   = (const float*)d_in[2];
  const float* nb   = (const float*)d_in[3];
  const float* cg   = (const float*)d_in[4];
  const float* cb   = (const float*)d_in[5];
  const float* Wq   = (const float*)d_in[6];
  const float* Wkv  = (const float*)d_in[7];
  const float* Wo   = (const float*)d_in[8];
  const float* Wff1 = (const float*)d_in[9];
  const float* Wff2 = (const float*)d_in[10];

  u16* p = (u16*)d_ws;
  u16* WqT   = p; p += (size_t)1024 * 1024;
  u16* W2T   = p; p += (size_t)8192 * 1024;   // Wff1 interleaved
  u16* WkvT  = p; p += (size_t)128 * 1024;
  u16* WcT   = p; p += (size_t)1024 * 5120;
  u16* kvbuf = p; p += (size_t)4096 * 128;
  u16* aoh   = p; p += (size_t)4096 * 5120;
  u16* xn    = p; p += (size_t)4096 * 1024;
  u16* cn    = p; p += (size_t)4096 * 1024;
  u16* qbuf  = p; p += (size_t)4096 * 1024;
  u16* kvpart = p; p += (size_t)8 * 4096 * 128;
  u16* ffpart = xn;    // 32 MB bf16 over xn|cn|qbuf + tail (dead by final GEMM)
  (void)in_sizes; (void)n_in; (void)out_size; (void)ws_size;

  // merged prep: LN + all weight transposes in one dispatch (11808 blocks)
  prep_kernel<<<11808, 256, 0, stream>>>(x, ctx, ng, nb, cg, cb, xn, cn,
                                         Wff1, W2T, Wq, Wkv, Wo, Wff2, WqT, WkvT, WcT);

  // ff: aoh[:,1024:] = silu(xn @ Wff1), N=8192 -> 512 blocks = exact 2/CU pack
  gemm32_ff<<<dim3(512), 512, 0, stream>>>(xn, W2T, aoh, 4096, 8192, 1024);
  // q + kv projections in one dispatch (512 blocks)
  qkv_proj<<<dim3(8, 32, 2), 256, 0, stream>>>(xn, WqT, qbuf, cn, WkvT, kvpart);
  reduce_kv<<<256, 256, 0, stream>>>(kvpart, kvbuf);
  // attention -> aoh[:,0:1024]; in-register P (T12)
  attn_kernel<<<dim3(32, 4, 2), 512, 0, stream>>>(qbuf, kvbuf, aoh);
  // out = aoh @ [Wo ; Wff2], split-K 4, bf16 partials
  gemm64_sk<<<dim3(64, 4), 512, 0, stream>>>(aoh, WcT, ffpart, 4096, 1024, 5120, 1280);
  reduce_out<<<2048, 256, 0, stream>>>(ffpart, (float*)d_out);
}

// Round 20
// 241.579 us; speedup vs baseline: 5.6586x; 1.0239x over previous
//
#include <hip/hip_runtime.h>
#include <stdint.h>

typedef unsigned short u16;
typedef __attribute__((ext_vector_type(8))) short short8;
typedef __attribute__((ext_vector_type(4))) float f32x4;
typedef __attribute__((ext_vector_type(16))) float f32x16;

#define GPTR(p) ((const __attribute__((address_space(1))) void*)(p))
#define SPTR(p) ((__attribute__((address_space(3))) void*)(p))
#define GLDS16(g, l) __builtin_amdgcn_global_load_lds(GPTR(g), SPTR(l), 16, 0, 0)

static __device__ __forceinline__ float bf2f(u16 u) {
  union { unsigned int i; float f; } c; c.i = ((unsigned int)u) << 16; return c.f;
}
static __device__ __forceinline__ u16 f2bf(float f) {
  union { float f; unsigned int u; } c; c.f = f;
  unsigned int r = 0x7fffu + ((c.u >> 16) & 1u);
  return (u16)((c.u + r) >> 16);
}
static __device__ __forceinline__ unsigned cvtpk(float a, float b) {
  unsigned r;
  asm volatile("v_cvt_pk_bf16_f32 %0, %1, %2" : "=v"(r) : "v"(a), "v"(b));
  return r;
}
static __device__ __forceinline__ int swz4(int row, int c) { return c ^ ((row >> 1) & 3); }

// ---------------- merged prep: LN (x,ctx) + Wff1 interleave-T + {Wq,Wkv,Wo,Wff2} T ----------------
__global__ __launch_bounds__(256) void prep_kernel(
    const float* __restrict__ x, const float* __restrict__ ctx,
    const float* __restrict__ g, const float* __restrict__ b,
    const float* __restrict__ cg, const float* __restrict__ cb,
    u16* __restrict__ xn, u16* __restrict__ cn,
    const float* __restrict__ Wff1, u16* __restrict__ W2T,
    const float* __restrict__ Wq, const float* __restrict__ Wkv,
    const float* __restrict__ Wo, const float* __restrict__ Wff2,
    u16* __restrict__ WqT, u16* __restrict__ WkvT, u16* __restrict__ WcT)
{
  const int bid = blockIdx.x;
  const int t = threadIdx.x;

  if (bid < 8192) {
    const int row = bid;
    const float* src; const float* gg; const float* bb; u16* dst;
    if (row < 4096) { src = x + (size_t)row * 1024; gg = g;  bb = b;  dst = xn + (size_t)row * 1024; }
    else            { src = ctx + (size_t)(row - 4096) * 1024; gg = cg; bb = cb; dst = cn + (size_t)(row - 4096) * 1024; }
    float4 v = *(const float4*)&src[t * 4];
    float s  = v.x + v.y + v.z + v.w;
    float s2 = v.x * v.x + v.y * v.y + v.z * v.z + v.w * v.w;
    #pragma unroll
    for (int off = 1; off < 64; off <<= 1) { s += __shfl_xor(s, off); s2 += __shfl_xor(s2, off); }
    __shared__ float ls[4], ls2[4];
    const int w = t >> 6;
    if ((t & 63) == 0) { ls[w] = s; ls2[w] = s2; }
    __syncthreads();
    s  = ls[0] + ls[1] + ls[2] + ls[3];
    s2 = ls2[0] + ls2[1] + ls2[2] + ls2[3];
    const float mu   = s * (1.0f / 1024.0f);
    const float var  = s2 * (1.0f / 1024.0f) - mu * mu;
    const float rstd = rsqrtf(var + 1e-5f);
    float xv[4] = { v.x, v.y, v.z, v.w };
    u16 o[4];
    #pragma unroll
    for (int i = 0; i < 4; ++i)
      o[i] = f2bf((xv[i] - mu) * rstd * gg[t * 4 + i] + bb[t * 4 + i]);
    uint2 pv;
    pv.x = (unsigned)o[0] | ((unsigned)o[1] << 16);
    pv.y = (unsigned)o[2] | ((unsigned)o[3] << 16);
    *(uint2*)&dst[t * 4] = pv;
    return;
  }

  __shared__ float tile[64][65];
  const int tr = t >> 4, tc = (t & 15) * 4;

  if (bid < 10240) {
    const int id = bid - 8192;
    const int c0 = (id & 127) * 64, r0 = (id >> 7) * 64;
    #pragma unroll
    for (int i = 0; i < 4; ++i) {
      int r = tr + i * 16;
      float4 v = *(const float4*)&Wff1[(size_t)(r0 + r) * 8192 + c0 + tc];
      tile[r][tc + 0] = v.x; tile[r][tc + 1] = v.y; tile[r][tc + 2] = v.z; tile[r][tc + 3] = v.w;
    }
    __syncthreads();
    #pragma unroll
    for (int i = 0; i < 2; ++i) {
      int c  = (t >> 3) + i * 32;
      int rb = (t & 7) * 8;
      const int gc = c0 + c;
      int j, add16;
      if (gc < 4096) { j = gc; add16 = 0; } else { j = gc - 4096; add16 = 16; }
      const int row = ((j >> 7) << 8) + (((j >> 5) & 3) << 6) + (((j >> 4) & 1) << 5) + add16 + (j & 15);
      union { u16 s[8]; uint4 v; } pk;
      #pragma unroll
      for (int u = 0; u < 8; ++u) pk.s[u] = f2bf(tile[rb + u][c]);
      *(uint4*)&W2T[(size_t)row * 1024 + r0 + rb] = pk.v;
    }
    return;
  }

  int id = bid - 10240;
  const float* in; u16* out; int C, ldo, cx; float scale;
  if (id < 256)      {           in = Wq;   out = WqT;        C = 1024; ldo = 1024; scale = 0.125f; cx = 16; }
  else if (id < 288) { id -= 256; in = Wkv;  out = WkvT;       C = 128;  ldo = 1024; scale = 1.0f;   cx = 2;  }
  else if (id < 544) { id -= 288; in = Wo;   out = WcT;        C = 1024; ldo = 5120; scale = 1.0f;   cx = 16; }
  else               { id -= 544; in = Wff2; out = WcT + 1024; C = 1024; ldo = 5120; scale = 1.0f;   cx = 16; }
  const int c0 = (id % cx) * 64, r0 = (id / cx) * 64;
  #pragma unroll
  for (int i = 0; i < 4; ++i) {
    int r = tr + i * 16;
    float4 v = *(const float4*)&in[(size_t)(r0 + r) * C + c0 + tc];
    tile[r][tc + 0] = v.x; tile[r][tc + 1] = v.y; tile[r][tc + 2] = v.z; tile[r][tc + 3] = v.w;
  }
  __syncthreads();
  #pragma unroll
  for (int i = 0; i < 2; ++i) {
    int c  = (t >> 3) + i * 32;
    int rb = (t & 7) * 8;
    union { u16 s[8]; uint4 v; } pk;
    #pragma unroll
    for (int u = 0; u < 8; ++u) pk.s[u] = f2bf(tile[rb + u][c] * scale);
    *(uint4*)&out[(size_t)(c0 + c) * ldo + r0 + rb] = pk.v;
  }
}

// =============== BK=32 4-phase 256x256 GEMM (ff: N=8192, 512 blocks = exact 2/CU pack) ===============
#define MM32(MQ, M, NN) acc[MQ][M][NN] = __builtin_amdgcn_mfma_f32_16x16x32_bf16(af##M, bf##NN, acc[MQ][M][NN], 0, 0, 0)
#define MFMA16_32(MQ) \
  MM32(MQ,0,0); MM32(MQ,0,1); MM32(MQ,0,2); MM32(MQ,0,3); \
  MM32(MQ,1,0); MM32(MQ,1,1); MM32(MQ,1,2); MM32(MQ,1,3); \
  MM32(MQ,2,0); MM32(MQ,2,1); MM32(MQ,2,2); MM32(MQ,2,3); \
  MM32(MQ,3,0); MM32(MQ,3,1); MM32(MQ,3,2); MM32(MQ,3,3)

#define SA32(SBUF, H, KT) GLDS16(gA32[H] + ((size_t)(KT) << 5), SBUF + (size_t)((H) * 64 + w16o) * 32)
#define SB32(SBUF, H, KT) GLDS16(gB32[H] + ((size_t)(KT) << 5), SBUF + (size_t)((H) * 128 + w16o2) * 32)

#define DSB32(PB_) do { \
  bf0 = *(const short8*)(PB_ + 0    + cks); bf1 = *(const short8*)(PB_ + 512  + cks); \
  bf2 = *(const short8*)(PB_ + 1024 + cks); bf3 = *(const short8*)(PB_ + 1536 + cks); \
} while (0)

#define PC32(PA_, MQ, STAGE_STMT, GATE_STMT) do { \
  af0 = *(const short8*)(PA_ + (MQ) * 2048 + 0    + cks); \
  af1 = *(const short8*)(PA_ + (MQ) * 2048 + 512  + cks); \
  af2 = *(const short8*)(PA_ + (MQ) * 2048 + 1024 + cks); \
  af3 = *(const short8*)(PA_ + (MQ) * 2048 + 1536 + cks); \
  STAGE_STMT; \
  __builtin_amdgcn_s_barrier(); \
  asm volatile("s_waitcnt lgkmcnt(0)" ::: "memory"); \
  __builtin_amdgcn_s_setprio(1); \
  MFMA16_32(MQ); \
  __builtin_amdgcn_s_setprio(0); \
  GATE_STMT; \
  __builtin_amdgcn_s_barrier(); \
} while (0)

#define GATE3 asm volatile("s_waitcnt vmcnt(3)" ::: "memory")
#define GATE0 asm volatile("s_waitcnt vmcnt(0)" ::: "memory")

__global__ __launch_bounds__(512, 2) void gemm32_ff(
    const u16* __restrict__ A, const u16* __restrict__ BT, u16* __restrict__ Ho,
    int M, int N, int Ktot)
{
  __shared__ u16 sh[2][2][8192]; // 64 KB
  const int nbm = M >> 8;
  const int nwg = gridDim.x;
  const int bid = blockIdx.x;
  const int o = (bid & 7) * (nwg >> 3) + (bid >> 3);
  const int bm = o % nbm, bn = o / nbm;   // B-strip per XCD
  const int NI = Ktot >> 6;

  const int t = threadIdx.x, w = t >> 6, lane = t & 63;
  const int wr = w >> 2, wc = w & 3;
  const int lr = lane & 15, lg = lane >> 4;
  const int l4 = lane >> 2, sl = lane & 3;
  const int w16o  = w * 16 + ((w >= 4) ? 64 : 0);
  const int w16o2 = w * 16;

  const u16* gA32[2]; const u16* gB32[2];
  #pragma unroll
  for (int h = 0; h < 2; ++h) {
    const int rowA = h * 64 + w16o + l4;
    gA32[h] = A + (size_t)(bm * 256 + rowA) * Ktot + (size_t)((sl ^ ((rowA >> 1) & 3)) * 8);
    const int rowB = h * 128 + w16o2 + l4;
    gB32[h] = BT + (size_t)(bn * 256 + rowB) * Ktot + (size_t)((sl ^ ((rowB >> 1) & 3)) * 8);
  }
  u16* sA0 = &sh[0][0][0]; u16* sA1 = &sh[1][0][0];
  u16* sB0 = &sh[0][1][0]; u16* sB1 = &sh[1][1][0];
  const int cks = (lg ^ ((lr >> 1) & 3)) * 8;
  const u16* pA_b0 = sA0 + (wr * 128 + lr) * 32;
  const u16* pA_b1 = sA1 + (wr * 128 + lr) * 32;
  const u16* pB_b0 = sB0 + (wc * 64 + lr) * 32;
  const u16* pB_b1 = sB1 + (wc * 64 + lr) * 32;

  f32x4 acc[2][4][4];
  const f32x4 z4 = { 0.f, 0.f, 0.f, 0.f };
  #pragma unroll
  for (int a = 0; a < 2; ++a)
    #pragma unroll
    for (int b = 0; b < 4; ++b)
      #pragma unroll
      for (int c = 0; c < 4; ++c) acc[a][b][c] = z4;
  short8 af0, af1, af2, af3;
  short8 bf0, bf1, bf2, bf3;

  SA32(sA0, 0, 0); SA32(sA0, 1, 0); SB32(sB0, 0, 0); SB32(sB0, 1, 0);
  SB32(sB1, 0, 1); SB32(sB1, 1, 1); SA32(sA1, 0, 1);
  GATE3;
  __builtin_amdgcn_s_barrier();

  for (int i = 0; i < NI; ++i) {
    const bool st = (i < NI - 1);
    const int X = 2 * i + 2, Y = 2 * i + 3;
    DSB32(pB_b0);
    PC32(pA_b0, 0, SA32(sA1, 1, 2 * i + 1), );
    PC32(pA_b0, 1,
         if (st) { SB32(sB0, 0, X); SB32(sB0, 1, X); SA32(sA0, 0, X); },
         if (st) { GATE3; } else { GATE0; });
    DSB32(pB_b1);
    PC32(pA_b1, 0, if (st) { SA32(sA0, 1, X); }, );
    PC32(pA_b1, 1,
         if (st) { SB32(sB1, 0, Y); SB32(sB1, 1, Y); SA32(sA1, 0, Y); },
         if (st) { GATE3; });
  }

  const int colb = 1024 + bn * 128 + wc * 32 + lr;
  #pragma unroll
  for (int mq = 0; mq < 2; ++mq)
    #pragma unroll
    for (int m = 0; m < 4; ++m)
      #pragma unroll
      for (int rr = 0; rr < 4; ++rr) {
        const int row = bm * 256 + wr * 128 + mq * 64 + m * 16 + lg * 4 + rr;
        #pragma unroll
        for (int n2 = 0; n2 < 2; ++n2) {
          const float a = acc[mq][m][2 * n2][rr];
          const float gt = acc[mq][m][2 * n2 + 1][rr];
          const float h = a * gt / (1.0f + __expf(-gt));
          Ho[(size_t)row * 5120 + colb + n2 * 16] = f2bf(h);
        }
      }
}

// =============== BK=64 8-phase 256x256 GEMM (final GEMM, split-K 4, bf16 partials) ===============
#define MM1(MQ, M, NN, BF) acc[MQ][M][NN] = __builtin_amdgcn_mfma_f32_16x16x32_bf16(af##M, BF, acc[MQ][M][NN], 0, 0, 0)
#define MFMA16(MQ, KS) \
  MM1(MQ,0,0,bf##KS##0); MM1(MQ,0,1,bf##KS##1); MM1(MQ,0,2,bf##KS##2); MM1(MQ,0,3,bf##KS##3); \
  MM1(MQ,1,0,bf##KS##0); MM1(MQ,1,1,bf##KS##1); MM1(MQ,1,2,bf##KS##2); MM1(MQ,1,3,bf##KS##3); \
  MM1(MQ,2,0,bf##KS##0); MM1(MQ,2,1,bf##KS##1); MM1(MQ,2,2,bf##KS##2); MM1(MQ,2,3,bf##KS##3); \
  MM1(MQ,3,0,bf##KS##0); MM1(MQ,3,1,bf##KS##1); MM1(MQ,3,2,bf##KS##2); MM1(MQ,3,3,bf##KS##3)

#define SG_A(SBUF, H, KT) do { \
    GLDS16(gA[H][0] + ((size_t)(KT) << 6), SBUF + ((H) * 64 + w16o) * 64); \
    GLDS16(gA[H][1] + ((size_t)(KT) << 6), SBUF + ((H) * 64 + w16o + 8) * 64); \
  } while (0)
#define SG_B(SBUF, H, KT) do { \
    GLDS16(gB[H][0] + ((size_t)(KT) << 6), SBUF + ((H) * 128 + w16o2) * 64); \
    GLDS16(gB[H][1] + ((size_t)(KT) << 6), SBUF + ((H) * 128 + w16o2 + 8) * 64); \
  } while (0)

#define DS_B(PB_) do { \
  bf00 = *(const short8*)(PB_ + 0    + cks0); bf01 = *(const short8*)(PB_ + 1024 + cks0); \
  bf02 = *(const short8*)(PB_ + 2048 + cks0); bf03 = *(const short8*)(PB_ + 3072 + cks0); \
  bf10 = *(const short8*)(PB_ + 0    + cks1); bf11 = *(const short8*)(PB_ + 1024 + cks1); \
  bf12 = *(const short8*)(PB_ + 2048 + cks1); bf13 = *(const short8*)(PB_ + 3072 + cks1); \
} while (0)

#define P_CORE(PA_, MQ, KS, STAGE_STMT, PREB_STMT, GATE_STMT) do { \
  af0 = *(const short8*)(PA_ + (MQ) * 4096 + 0    + cks##KS); \
  af1 = *(const short8*)(PA_ + (MQ) * 4096 + 1024 + cks##KS); \
  af2 = *(const short8*)(PA_ + (MQ) * 4096 + 2048 + cks##KS); \
  af3 = *(const short8*)(PA_ + (MQ) * 4096 + 3072 + cks##KS); \
  STAGE_STMT; \
  PREB_STMT; \
  __builtin_amdgcn_s_barrier(); \
  asm volatile("s_waitcnt lgkmcnt(0)" ::: "memory"); \
  __builtin_amdgcn_s_setprio(1); \
  MFMA16(MQ, KS); \
  __builtin_amdgcn_s_setprio(0); \
  GATE_STMT; \
  __builtin_amdgcn_s_barrier(); \
} while (0)

#define GATE6 asm volatile("s_waitcnt vmcnt(6)" ::: "memory")
#define HINT8 asm volatile("s_waitcnt lgkmcnt(8)" ::: "memory")

__global__ __launch_bounds__(512, 2) void gemm64_sk(
    const u16* __restrict__ A, const u16* __restrict__ BT, u16* __restrict__ C,
    int M, int N, int Ktot, int Kslice)
{
  __shared__ u16 sh[2][2][16384]; // 128 KB
  const int nbn = N >> 8;
  const int nwg = gridDim.x;
  const int bid = blockIdx.x;
  const int o = (bid & 7) * (nwg >> 3) + (bid >> 3);
  const int bn = o % nbn, bm = o / nbn;   // A-panels per XCD
  const int kbase = blockIdx.y * Kslice;
  const int NI = Kslice >> 7;

  const int t = threadIdx.x, w = t >> 6, lane = t & 63;
  const int wr = w >> 2, wc = w & 3;
  const int lr = lane & 15, lg = lane >> 4;
  const int r8 = lane >> 3, ch = lane & 7;
  const int clog = ch ^ r8;
  const int w16o  = w * 16 + ((w >= 4) ? 64 : 0);
  const int w16o2 = w * 16;

  const u16* gA[2][2]; const u16* gB[2][2];
  #pragma unroll
  for (int h = 0; h < 2; ++h)
    #pragma unroll
    for (int qq = 0; qq < 2; ++qq) {
      gA[h][qq] = A  + (size_t)(bm * 256 + h * 64  + w16o  + qq * 8 + r8) * Ktot + kbase + clog * 8;
      gB[h][qq] = BT + (size_t)(bn * 256 + h * 128 + w16o2 + qq * 8 + r8) * Ktot + kbase + clog * 8;
    }
  u16* sA0 = &sh[0][0][0]; u16* sA1 = &sh[1][0][0];
  u16* sB0 = &sh[0][1][0]; u16* sB1 = &sh[1][1][0];
  const int cks0 = ((0 + lg) ^ (lr & 7)) * 8;
  const int cks1 = ((4 + lg) ^ (lr & 7)) * 8;
  const u16* pA_b0 = sA0 + (wr * 128 + lr) * 64;
  const u16* pA_b1 = sA1 + (wr * 128 + lr) * 64;
  const u16* pB_b0 = sB0 + (wc * 64 + lr) * 64;
  const u16* pB_b1 = sB1 + (wc * 64 + lr) * 64;

  f32x4 acc[2][4][4];
  const f32x4 z4 = { 0.f, 0.f, 0.f, 0.f };
  #pragma unroll
  for (int a = 0; a < 2; ++a)
    #pragma unroll
    for (int b = 0; b < 4; ++b)
      #pragma unroll
      for (int c = 0; c < 4; ++c) acc[a][b][c] = z4;
  short8 af0, af1, af2, af3;
  short8 bf00, bf01, bf02, bf03, bf10, bf11, bf12, bf13;

  SG_B(sB0, 0, 0); SG_B(sB0, 1, 0); SG_A(sA0, 0, 0); SG_A(sA0, 1, 0);
  SG_B(sB1, 0, 1); SG_B(sB1, 1, 1); SG_A(sA1, 0, 1);
  GATE6;
  __builtin_amdgcn_s_barrier();

  for (int i = 0; i < NI; ++i) {
    const int k2 = 2 * i;
    const bool st = (i < NI - 1);
    DS_B(pB_b0);
    P_CORE(pA_b0, 0, 0, SG_A(sA1, 1, k2 + 1), HINT8, );
    P_CORE(pA_b0, 1, 0, if (st) SG_B(sB0, 0, k2 + 2), , );
    P_CORE(pA_b0, 0, 1, if (st) SG_B(sB0, 1, k2 + 2), , );
    P_CORE(pA_b0, 1, 1, if (st) SG_A(sA0, 0, k2 + 2), ,
           if (st) { GATE6; } else { GATE0; });
    DS_B(pB_b1);
    P_CORE(pA_b1, 0, 0, if (st) SG_A(sA0, 1, k2 + 2), HINT8, );
    P_CORE(pA_b1, 1, 0, if (st) SG_B(sB1, 0, k2 + 3), , );
    P_CORE(pA_b1, 0, 1, if (st) SG_B(sB1, 1, k2 + 3), , );
    P_CORE(pA_b1, 1, 1, if (st) SG_A(sA1, 0, k2 + 3), ,
           if (st) { GATE6; });
  }

  u16* Co = C + (size_t)blockIdx.y * M * N;
  #pragma unroll
  for (int mq = 0; mq < 2; ++mq)
    #pragma unroll
    for (int m = 0; m < 4; ++m)
      #pragma unroll
      for (int n = 0; n < 4; ++n)
        #pragma unroll
        for (int rr = 0; rr < 4; ++rr) {
          const int row = bm * 256 + wr * 128 + mq * 64 + m * 16 + lg * 4 + rr;
          const int col = bn * 256 + wc * 64 + n * 16 + lr;
          Co[(size_t)row * N + col] = f2bf(acc[mq][m][n][rr]);
        }
}

// ---------------- combined q + kv projection (one dispatch, 288 blocks, no split-K) ----------------
// blockIdx.x < 8: q tile (bn = x, K=1024); blockIdx.x == 8: kv tile (bn=0, N=128, full K=1024).
__global__ __launch_bounds__(256) void qkv_proj(
    const u16* __restrict__ xn, const u16* __restrict__ WqT, u16* __restrict__ qbuf,
    const u16* __restrict__ cn, const u16* __restrict__ WkvT, u16* __restrict__ kvbuf)
{
  __shared__ u16 As[128 * 32];
  __shared__ u16 Bs[128 * 32];
  const int bm = blockIdx.y;
  const u16* A; const u16* BT; u16* Cp;
  int N, bn;
  if (blockIdx.x < 8) { A = xn; BT = WqT;  Cp = qbuf;  N = 1024; bn = blockIdx.x; }
  else                { A = cn; BT = WkvT; Cp = kvbuf; N = 128;  bn = 0; }
  const int Ktot = 1024;

  const int t = threadIdx.x;
  const int w = t >> 6, lane = t & 63;
  const int wr = w >> 1, wc = w & 1;
  const int lr = lane & 15, lkc = lane >> 4;

  f32x4 acc[4][4];
  const f32x4 z4 = { 0.f, 0.f, 0.f, 0.f };
  #pragma unroll
  for (int mi = 0; mi < 4; ++mi)
    #pragma unroll
    for (int ni = 0; ni < 4; ++ni) acc[mi][ni] = z4;

  const int i0 = t, i1 = t + 256;
  const int r0 = i0 >> 2, k0 = swz4(r0, i0 & 3) * 8;
  const int r1 = i1 >> 2, k1 = swz4(r1, i1 & 3) * 8;
  const u16* a0 = A + (size_t)(bm * 128 + r0) * Ktot + k0;
  const u16* a1 = A + (size_t)(bm * 128 + r1) * Ktot + k1;
  const u16* b0 = BT + (size_t)(bn * 128 + r0) * Ktot + k0;
  const u16* b1 = BT + (size_t)(bn * 128 + r1) * Ktot + k1;
  u16* As0 = As + (size_t)w * 512;
  u16* As1 = As + (size_t)(w + 4) * 512;
  u16* Bs0 = Bs + (size_t)w * 512;
  u16* Bs1 = Bs + (size_t)(w + 4) * 512;

  for (int kt = 0; kt < 32; ++kt) {
    __syncthreads();
    GLDS16(a0, As0); GLDS16(a1, As1); GLDS16(b0, Bs0); GLDS16(b1, Bs1);
    a0 += 32; a1 += 32; b0 += 32; b1 += 32;
    __syncthreads();
    short8 af[4], bf[4];
    #pragma unroll
    for (int mi = 0; mi < 4; ++mi) {
      int row = wr * 64 + mi * 16 + lr;
      af[mi] = *(const short8*)&As[row * 32 + swz4(row, lkc) * 8];
    }
    #pragma unroll
    for (int ni = 0; ni < 4; ++ni) {
      int row = wc * 64 + ni * 16 + lr;
      bf[ni] = *(const short8*)&Bs[row * 32 + swz4(row, lkc) * 8];
    }
    #pragma unroll
    for (int mi = 0; mi < 4; ++mi)
      #pragma unroll
      for (int ni = 0; ni < 4; ++ni)
        acc[mi][ni] = __builtin_amdgcn_mfma_f32_16x16x32_bf16(af[mi], bf[ni], acc[mi][ni], 0, 0, 0);
  }

  const int row0 = bm * 128 + wr * 64, col0 = bn * 128 + wc * 64;
  const int rsub = (lane >> 4) * 4;
  #pragma unroll
  for (int mi = 0; mi < 4; ++mi)
    #pragma unroll
    for (int ni = 0; ni < 4; ++ni)
      #pragma unroll
      for (int r = 0; r < 4; ++r)
        Cp[(size_t)(row0 + mi * 16 + rsub + r) * N + (col0 + ni * 16 + lr)] = f2bf(acc[mi][ni][r]);
}

// ---------------- out = sum of 4 bf16 partials (4096x1024) -> f32 ----------------
__global__ __launch_bounds__(256) void reduce_out(const u16* __restrict__ part, float* __restrict__ out)
{
  const size_t base = ((size_t)blockIdx.x * 256 + threadIdx.x) * 8;
  float s[8] = { 0.f, 0.f, 0.f, 0.f, 0.f, 0.f, 0.f, 0.f };
  #pragma unroll
  for (int zz = 0; zz < 4; ++zz) {
    const short8 v = *(const short8*)&part[(size_t)zz * 4194304 + base];
    #pragma unroll
    for (int i = 0; i < 8; ++i) s[i] += bf2f((u16)v[i]);
  }
  f32x4 lo = { s[0], s[1], s[2], s[3] };
  f32x4 hi = { s[4], s[5], s[6], s[7] };
  *(f32x4*)&out[base] = lo;
  *(f32x4*)&out[base + 4] = hi;
}

// ---------------- flash cross-attention (multi-query: 1 KV head) ----------------
// 8 waves x 512 threads, 256 blocks. T12 in-register P.
__global__ __launch_bounds__(512, 1) void attn_kernel(
    const u16* __restrict__ q, const u16* __restrict__ kv, u16* __restrict__ o)
{
  __shared__ u16 Ks[128 * 64];
  __shared__ u16 Vt[64 * 128];
  __shared__ u16 Es[8][2048];   // per-wave epilogue scratch
  const int b = blockIdx.z, hb = blockIdx.y, qb = blockIdx.x;
  const int t = threadIdx.x, w = t >> 6, lane = t & 63;
  const int q32 = lane & 31, hl = lane >> 5;
  const int hd = hb * 4 + (w >> 1);
  const int t32 = w & 1;

  const size_t qbase = (size_t)b * 2048 + qb * 64;
  short8 qa[4];
  #pragma unroll
  for (int dq = 0; dq < 4; ++dq)
    qa[dq] = *(const short8*)&q[(qbase + t32 * 32 + q32) * 1024 + hd * 64 + dq * 16 + hl * 8];

  f32x16 oacc[2];
  #pragma unroll
  for (int j = 0; j < 2; ++j)
    #pragma unroll
    for (int r = 0; r < 16; ++r) oacc[j][r] = 0.f;
  float m_ = -1e30f, l_ = 0.f;

  const size_t kvb = (size_t)b * 2048 * 128;
  const int vd0 = (t & 7) * 8;
  const int vodd = (t >> 3) & 1;

  uint4 vhold[2];
  #pragma unroll
  for (int c = 0; c < 2; ++c) {
    const int vj = (c * 512 + t) >> 3;
    vhold[c] = *(const uint4*)&kv[kvb + (size_t)vj * 128 + 64 + vd0];
  }

  for (int jt = 0; jt < 16; ++jt) {
    __syncthreads();
    #pragma unroll
    for (int n = 0; n < 2; ++n) {
      const int cc = n * 512 + w * 64;
      const int ccl = cc + lane;
      const int row = ccl >> 3, lc = (ccl & 7) ^ (row & 7);
      GLDS16(&kv[kvb + (size_t)(jt * 128 + row) * 128 + lc * 8], Ks + (size_t)cc * 8);
    }
    #pragma unroll
    for (int c = 0; c < 2; ++c) {
      const int seg = c * 512 + t;
      const int vj = seg >> 3;
      const int jp = vj >> 1;
      const uint4 vv = vhold[c];
      uint4 pvv;
      pvv.x = __shfl_xor((int)vv.x, 8);
      pvv.y = __shfl_xor((int)vv.y, 8);
      pvv.z = __shfl_xor((int)vv.z, 8);
      pvv.w = __shfl_xor((int)vv.w, 8);
      const unsigned ow[4] = { vv.x, vv.y, vv.z, vv.w };
      const unsigned pw[4] = { pvv.x, pvv.y, pvv.z, pvv.w };
      if (!vodd) {
        #pragma unroll
        for (int u = 0; u < 4; ++u) {
          const int d = vd0 + u;
          const unsigned own = (u & 1) ? (ow[u >> 1] >> 16) : (ow[u >> 1] & 0xffffu);
          const unsigned par = (u & 1) ? (pw[u >> 1] >> 16) : (pw[u >> 1] & 0xffffu);
          const int byteoff = d * 256 + ((4 * jp) ^ (((d & 7) ^ ((d >> 3) & 7)) << 4));
          *(unsigned*)((char*)Vt + byteoff) = own | (par << 16);
        }
      } else {
        #pragma unroll
        for (int u = 0; u < 4; ++u) {
          const int ue = u + 4;
          const int d = vd0 + ue;
          const unsigned own = (ue & 1) ? (ow[ue >> 1] >> 16) : (ow[ue >> 1] & 0xffffu);
          const unsigned par = (ue & 1) ? (pw[ue >> 1] >> 16) : (pw[ue >> 1] & 0xffffu);
          const int byteoff = d * 256 + ((4 * jp) ^ (((d & 7) ^ ((d >> 3) & 7)) << 4));
          *(unsigned*)((char*)Vt + byteoff) = par | (own << 16);
        }
      }
    }
    __builtin_amdgcn_sched_barrier(0);
    if (jt < 15) {
      #pragma unroll
      for (int c = 0; c < 2; ++c) {
        const int vj = (c * 512 + t) >> 3;
        vhold[c] = *(const uint4*)&kv[kvb + (size_t)((jt + 1) * 128 + vj) * 128 + 64 + vd0];
      }
      asm volatile("s_waitcnt vmcnt(2) lgkmcnt(0)" ::: "memory");
    } else {
      asm volatile("s_waitcnt vmcnt(0) lgkmcnt(0)" ::: "memory");
    }
    __builtin_amdgcn_s_barrier();
    __builtin_amdgcn_sched_barrier(0);

    f32x16 s[4];
    #pragma unroll
    for (int j32 = 0; j32 < 4; ++j32)
      #pragma unroll
      for (int r = 0; r < 16; ++r) s[j32][r] = 0.f;
    __builtin_amdgcn_s_setprio(1);
    #pragma unroll
    for (int j32 = 0; j32 < 4; ++j32) {
      const int row = j32 * 32 + q32;
      #pragma unroll
      for (int dq = 0; dq < 4; ++dq) {
        const int slot = (dq * 2 + hl) ^ (row & 7);
        const short8 kf = *(const short8*)&Ks[row * 64 + slot * 8];
        s[j32] = __builtin_amdgcn_mfma_f32_32x32x16_bf16(kf, qa[dq], s[j32], 0, 0, 0);
      }
    }
    __builtin_amdgcn_s_setprio(0);
    float mt = -1e30f;
    #pragma unroll
    for (int j32 = 0; j32 < 4; ++j32)
      #pragma unroll
      for (int r = 0; r < 16; ++r) mt = fmaxf(mt, s[j32][r]);
    mt = fmaxf(mt, __shfl_xor(mt, 32));
    const bool noresc = (bool)__all(mt <= m_ + 8.0f);
    float nm = m_;
    if (!noresc) {
      nm = fmaxf(m_, mt);
      const float alpha = __expf(m_ - nm);
      m_ = nm;
      l_ *= alpha;
      #pragma unroll
      for (int d32 = 0; d32 < 2; ++d32)
        #pragma unroll
        for (int r = 0; r < 16; ++r) oacc[d32][r] *= alpha;
    }
    float lsum = 0.f;
    short8 pfr[8];
    #pragma unroll
    for (int j32 = 0; j32 < 4; ++j32) {
      float p[16];
      #pragma unroll
      for (int r = 0; r < 16; ++r) { p[r] = __expf(s[j32][r] - nm); lsum += p[r]; }
      unsigned c[8], xx[8];
      #pragma unroll
      for (int i = 0; i < 8; ++i) c[i] = cvtpk(p[2 * i], p[2 * i + 1]);
      #pragma unroll
      for (int i = 0; i < 8; ++i) xx[i] = (unsigned)__shfl_xor((int)c[i], 32);
      union { unsigned u[4]; short8 s8; } f0, f1;
      f0.u[0] = hl ? xx[2] : c[0];
      f0.u[1] = hl ? xx[3] : c[1];
      f0.u[2] = hl ? c[2]  : xx[0];
      f0.u[3] = hl ? c[3]  : xx[1];
      f1.u[0] = hl ? xx[6] : c[4];
      f1.u[1] = hl ? xx[7] : c[5];
      f1.u[2] = hl ? c[6]  : xx[4];
      f1.u[3] = hl ? c[7]  : xx[5];
      pfr[2 * j32]     = f0.s8;
      pfr[2 * j32 + 1] = f1.s8;
    }
    lsum += __shfl_xor(lsum, 32);
    l_ += lsum;
    __builtin_amdgcn_s_setprio(1);
    #pragma unroll
    for (int d32 = 0; d32 < 2; ++d32) {
      const int dr = d32 * 32 + q32;
      const int vswz = ((dr & 7) ^ ((dr >> 3) & 7)) << 4;
      #pragma unroll
      for (int kk = 0; kk < 8; ++kk) {
        const int byteoff = dr * 256 + ((kk * 32 + hl * 16) ^ vswz);
        const short8 vf = *(const short8*)((const char*)Vt + byteoff);
        oacc[d32] = __builtin_amdgcn_mfma_f32_32x32x16_bf16(vf, pfr[kk], oacc[d32], 0, 0, 0);
      }
    }
    __builtin_amdgcn_s_setprio(0);
  }

  float* Ot = (float*)&Es[w][0];
  const float inv = 1.0f / l_;
  #pragma unroll
  for (int d32 = 0; d32 < 2; ++d32) {
    #pragma unroll
    for (int r = 0; r < 16; ++r) {
      const int d = (r & 3) + 8 * (r >> 2) + 4 * hl;
      const int byteoff = q32 * 128 + ((4 * d) ^ ((q32 & 7) << 4));
      *(float*)((char*)Ot + byteoff) = oacc[d32][r] * inv;
    }
    const int qr = lane >> 1, dc = (lane & 1) * 16;
    union { u16 s[16]; uint4 v[2]; } ob;
    #pragma unroll
    for (int cch = 0; cch < 4; ++cch) {
      const int byteoff = qr * 128 + ((4 * (dc + 4 * cch)) ^ ((qr & 7) << 4));
      const f32x4 vv = *(const f32x4*)((const char*)Ot + byteoff);
      ob.s[cch * 4 + 0] = f2bf(vv[0]);
      ob.s[cch * 4 + 1] = f2bf(vv[1]);
      ob.s[cch * 4 + 2] = f2bf(vv[2]);
      ob.s[cch * 4 + 3] = f2bf(vv[3]);
    }
    u16* orow = &o[(qbase + t32 * 32 + qr) * 5120 + hd * 64 + d32 * 32 + dc];
    *(uint4*)orow = ob.v[0];
    *(uint4*)(orow + 8) = ob.v[1];
  }
}

extern "C" void kernel_launch(void* const* d_in, const int* in_sizes, int n_in,
                              void* d_out, int out_size, void* d_ws, size_t ws_size,
                              hipStream_t stream)
{
  const float* x    = (const float*)d_in[0];
  const float* ctx  = (const float*)d_in[1];
  const float* ng   = (const float*)d_in[2];
  const float* nb   = (const float*)d_in[3];
  const float* cg   = (const float*)d_in[4];
  const float* cb   = (const float*)d_in[5];
  const float* Wq   = (const float*)d_in[6];
  const float* Wkv  = (const float*)d_in[7];
  const float* Wo   = (const float*)d_in[8];
  const float* Wff1 = (const float*)d_in[9];
  const float* Wff2 = (const float*)d_in[10];

  u16* p = (u16*)d_ws;
  u16* WqT   = p; p += (size_t)1024 * 1024;
  u16* W2T   = p; p += (size_t)8192 * 1024;   // Wff1 interleaved
  u16* WkvT  = p; p += (size_t)128 * 1024;
  u16* WcT   = p; p += (size_t)1024 * 5120;
  u16* kvbuf = p; p += (size_t)4096 * 128;
  u16* aoh   = p; p += (size_t)4096 * 5120;
  u16* xn    = p; p += (size_t)4096 * 1024;
  u16* cn    = p; p += (size_t)4096 * 1024;
  u16* qbuf  = p; p += (size_t)4096 * 1024;
  u16* ffpart = xn;    // 32 MB bf16 over xn|cn|qbuf + tail (dead by final GEMM)
  (void)in_sizes; (void)n_in; (void)out_size; (void)ws_size;

  // merged prep: LN + all weight transposes in one dispatch (11808 blocks)
  prep_kernel<<<11808, 256, 0, stream>>>(x, ctx, ng, nb, cg, cb, xn, cn,
                                         Wff1, W2T, Wq, Wkv, Wo, Wff2, WqT, WkvT, WcT);

  // ff: aoh[:,1024:] = silu(xn @ Wff1), N=8192 -> 512 blocks = exact 2/CU pack
  gemm32_ff<<<dim3(512), 512, 0, stream>>>(xn, W2T, aoh, 4096, 8192, 1024);
  // q + kv projections in one dispatch (288 blocks, kv full-K -> kvbuf directly)
  qkv_proj<<<dim3(9, 32, 1), 256, 0, stream>>>(xn, WqT, qbuf, cn, WkvT, kvbuf);
  // attention -> aoh[:,0:1024]; in-register P (T12)
  attn_kernel<<<dim3(32, 4, 2), 512, 0, stream>>>(qbuf, kvbuf, aoh);
  // out = aoh @ [Wo ; Wff2], split-K 4, bf16 partials
  gemm64_sk<<<dim3(64, 4), 512, 0, stream>>>(aoh, WcT, ffpart, 4096, 1024, 5120, 1280);
  reduce_out<<<2048, 256, 0, stream>>>(ffpart, (float*)d_out);
}